// Round 12
// baseline (1072.929 us; speedup 1.0000x reference)
//
#include <hip/hip_runtime.h>
#include <hip/hip_bf16.h>

// DGCNN_Seg forward. B=2, N=4096, K=20. fp32 in/out.
// Round 12: k_topk v4 — bitonic reg sort (R11) + cur/nxt LDS refill (R10, no
// 15-deep shift-pop) + hi/lo u32 dual min-tree (v_min_u32). 28.7KB LDS.
// Selection bit-identical. Everything else unchanged from R11 (1047us).

#define DEVI static __device__ __forceinline__
typedef __attribute__((ext_vector_type(8))) short bf16x8;   // 8 bf16 = 4 VGPR
typedef __attribute__((ext_vector_type(4))) float f32x4;    // MFMA acc
typedef unsigned long long ull;

DEVI float lrelu(float y) { return y > 0.f ? y : 0.2f * y; }
DEVI unsigned okey(float f) {
  unsigned u = __float_as_uint(f);
  return (f < 0.f) ? ~u : (u | 0x80000000u);
}
DEVI float dekey(unsigned k) {
  return __uint_as_float((k & 0x80000000u) ? (k & 0x7fffffffu) : ~k);
}

// ---------------- weight fp32 -> bf16 pack ----------------
__global__ __launch_bounds__(64) void k_conv(const float* __restrict__ src, int lds, int off,
                                             int sub, int Kc, __hip_bfloat16* __restrict__ dst) {
  int o = blockIdx.x, c = blockIdx.y * 64 + threadIdx.x;
  float v = src[(size_t)o * lds + off + c];
  if (sub) v -= src[(size_t)o * lds + c];
  dst[(size_t)o * Kc + c] = __float2bfloat16(v);
}

// ---------------- row squared-norms: one wave per row ----------------
__global__ __launch_bounds__(256) void k_xx(const float* __restrict__ F, int ldf, int C,
                                            float* __restrict__ xx) {
  int lane = threadIdx.x & 63;
  int row = blockIdx.x * 4 + (threadIdx.x >> 6);
  const float* f = F + (size_t)row * ldf;
  float s = 0.f;
  for (int c = lane; c < C; c += 64) { float v = f[c]; s += v * v; }
#pragma unroll
  for (int off = 32; off; off >>= 1) s += __shfl_xor(s, off, 64);
  if (lane == 0) xx[row] = s;
}

// ---------------- pairwise distances v2: 128x64 tile, 8x4 per thread ----------------
// fmaf order per element identical to v1 (chunks of 16 ascending, kk ascending)
__global__ __launch_bounds__(256) void k_dist(const float* __restrict__ F, int ldf, int C,
                                              const float* __restrict__ xx,
                                              float* __restrict__ D, int b, int ibase) {
  __shared__ __align__(16) float As[16][132];
  __shared__ __align__(16) float Bs[16][68];
  const int tid = threadIdx.x;
  const int tx = tid & 15, ty = tid >> 4;
  const int i0 = ibase + blockIdx.x * 128, j0 = blockIdx.y * 64;
  const float* Fb = F + (size_t)b * 4096 * ldf;
  const int arow = tid >> 1, q8 = (tid & 1) * 8;   // A stage: 128 rows x 16 cols
  const int brow = tid >> 2, q4 = (tid & 3) * 4;   // B stage: 64 rows x 16 cols
  float acc[8][4] = {};
  for (int c0 = 0; c0 < C; c0 += 16) {
    if (C - c0 >= 16) {
      float4 a0 = *(const float4*)(Fb + (size_t)(i0 + arow) * ldf + c0 + q8);
      float4 a1 = *(const float4*)(Fb + (size_t)(i0 + arow) * ldf + c0 + q8 + 4);
      As[q8 + 0][arow] = a0.x; As[q8 + 1][arow] = a0.y; As[q8 + 2][arow] = a0.z; As[q8 + 3][arow] = a0.w;
      As[q8 + 4][arow] = a1.x; As[q8 + 5][arow] = a1.y; As[q8 + 6][arow] = a1.z; As[q8 + 7][arow] = a1.w;
      float4 w = *(const float4*)(Fb + (size_t)(j0 + brow) * ldf + c0 + q4);
      Bs[q4 + 0][brow] = w.x; Bs[q4 + 1][brow] = w.y; Bs[q4 + 2][brow] = w.z; Bs[q4 + 3][brow] = w.w;
    } else {
#pragma unroll
      for (int e = 0; e < 8; ++e) {
        int c = c0 + q8 + e;
        As[q8 + e][arow] = (c < C) ? Fb[(size_t)(i0 + arow) * ldf + c] : 0.f;
      }
#pragma unroll
      for (int e = 0; e < 4; ++e) {
        int c = c0 + q4 + e;
        Bs[q4 + e][brow] = (c < C) ? Fb[(size_t)(j0 + brow) * ldf + c] : 0.f;
      }
    }
    __syncthreads();
#pragma unroll
    for (int kk = 0; kk < 16; ++kk) {
      const float4 a4l = *(const float4*)&As[kk][ty * 8];
      const float4 a4h = *(const float4*)&As[kk][ty * 8 + 4];
      const float4 b4 = *(const float4*)&Bs[kk][tx * 4];
      const float av[8] = {a4l.x, a4l.y, a4l.z, a4l.w, a4h.x, a4h.y, a4h.z, a4h.w};
      const float bv[4] = {b4.x, b4.y, b4.z, b4.w};
#pragma unroll
      for (int ii = 0; ii < 8; ++ii)
#pragma unroll
        for (int jj = 0; jj < 4; ++jj)
          acc[ii][jj] = fmaf(av[ii], bv[jj], acc[ii][jj]);
    }
    __syncthreads();
  }
  const float* xxb = xx + b * 4096;
#pragma unroll
  for (int ii = 0; ii < 8; ++ii) {
    int i = i0 + ty * 8 + ii;
    float xi = xxb[i];
    float4 o;
    o.x = xi + xxb[j0 + tx * 4 + 0] - 2.f * acc[ii][0];
    o.y = xi + xxb[j0 + tx * 4 + 1] - 2.f * acc[ii][1];
    o.z = xi + xxb[j0 + tx * 4 + 2] - 2.f * acc[ii][2];
    o.w = xi + xxb[j0 + tx * 4 + 3] - 2.f * acc[ii][3];
    *(float4*)&D[(size_t)(i - ibase) * 4096 + j0 + tx * 4] = o;
  }
}

// ---------------- top-20 v4: 1 block (4 waves) per row ----------------
// Per lane: 16 keys -> bitonic sort in regs; positions 2..15 spill to LDS.
// Extraction: 20 rounds of hi/lo u32 wave-min (v_min_u32 tree) with cur/nxt
// register window + rare exec-masked LDS refill. Selection order identical.
__global__ __launch_bounds__(256) void k_topk(const float* __restrict__ D,
                                              int* __restrict__ idx, int b, int ibase) {
  __shared__ ull sarr[256 * 14];  // 28672 B: sorted positions 2..15 per thread
  __shared__ ull cand[4][20];
  const int tid = threadIdx.x, lane = tid & 63, wv = tid >> 6;
  const int ir_ = blockIdx.x;
  const float* drow = D + (size_t)ir_ * 4096;
  ull arr[16];
  const int base = wv * 1024 + lane;
#pragma unroll
  for (int it = 0; it < 16; ++it) {
    int j = base + it * 64;
    float d = drow[j];
    arr[it] = ((ull)okey(d) << 32) | (unsigned)j;
  }
  // bitonic sort 16, ascending
#pragma unroll
  for (int k = 2; k <= 16; k <<= 1) {
#pragma unroll
    for (int jj = k >> 1; jj > 0; jj >>= 1) {
#pragma unroll
      for (int i = 0; i < 16; ++i) {
        int l = i ^ jj;
        if (l > i) {
          bool up = ((i & k) == 0);
          bool sw = (arr[i] > arr[l]) == up;
          ull a = arr[i], bb = arr[l];
          arr[i] = sw ? bb : a;
          arr[l] = sw ? a : bb;
        }
      }
    }
  }
  // spill positions 2..15
  ull* myl = &sarr[(size_t)tid * 14];
#pragma unroll
  for (int t = 0; t < 14; ++t) myl[t] = arr[t + 2];
  // extraction: cur/nxt window, hi/lo u32 min trees
  ull cur = arr[0], nxt = arr[1];
  int nidx = 0;
  for (int r = 0; r < 20; ++r) {
    unsigned hi = (unsigned)(cur >> 32), lo = (unsigned)cur;
    unsigned mh = hi;
#pragma unroll
    for (int off = 32; off; off >>= 1) {
      unsigned o = __shfl_xor(mh, off, 64);
      mh = o < mh ? o : mh;
    }
    unsigned lo2 = (hi == mh) ? lo : 0xFFFFFFFFu;
    unsigned ml = lo2;
#pragma unroll
    for (int off = 32; off; off >>= 1) {
      unsigned o = __shfl_xor(ml, off, 64);
      ml = o < ml ? o : ml;
    }
    if (lane == 0) cand[wv][r] = ((ull)mh << 32) | ml;
    bool pop = (hi == mh) && (lo == ml);
    if (pop) {
      cur = nxt;
      nxt = (nidx < 14) ? myl[nidx] : ~0ull;
      ++nidx;
    }
  }
  __syncthreads();
  if (tid == 0) {
    int* op = idx + ((size_t)b * 4096 + ibase + ir_) * 20;
    int p0 = 0, p1 = 0, p2 = 0, p3 = 0;
    for (int r = 0; r < 20; ++r) {
      ull v0 = cand[0][p0], v1 = cand[1][p1], v2 = cand[2][p2], v3 = cand[3][p3];
      ull m01 = v0 < v1 ? v0 : v1;
      ull m23 = v2 < v3 ? v2 : v3;
      ull best = m01 < m23 ? m01 : m23;
      if (best == v0) ++p0; else if (best == v1) ++p1;
      else if (best == v2) ++p2; else ++p3;
      op[r] = (int)(best & 0xffffffffull);
      if (p0 > 19) p0 = 19;
      if (p1 > 19) p1 = 19;
      if (p2 > 19) p2 = 19;
      if (p3 > 19) p3 = 19;
    }
  }
}

// ---------------- EdgeConv layer 1 (fp32, Cin=3): one wave per point ----------------
__global__ __launch_bounds__(256) void k_edge1(const float* __restrict__ xf,
                                               const float* __restrict__ W1,
                                               const float* __restrict__ s1,
                                               const float* __restrict__ b1,
                                               const int* __restrict__ idx,
                                               float* __restrict__ xcat,
                                               __hip_bfloat16* __restrict__ xcatb) {
  const int lane = threadIdx.x & 63;
  const int p = blockIdx.x * 4 + (threadIdx.x >> 6);
  const int bb = p >> 12;
  float wl[3], wr[3];
#pragma unroll
  for (int c = 0; c < 3; ++c) {
    wl[c] = W1[lane * 6 + c];
    wr[c] = W1[lane * 6 + 3 + c];
  }
  const float s = s1[lane], bi = b1[lane];
  const float* xc = xf + (size_t)p * 3;
  const float x0 = xc[0], x1 = xc[1], x2 = xc[2];
  const float t = x0 * (wr[0] - wl[0]) + x1 * (wr[1] - wl[1]) + x2 * (wr[2] - wl[2]);
  const int* ir = idx + (size_t)p * 20;
  float best = -INFINITY;
  for (int k = 0; k < 20; ++k) {
    int j = ir[k];
    const float* xn = xf + ((size_t)(bb << 12) + j) * 3;
    float y = t + xn[0] * wl[0] + xn[1] * wl[1] + xn[2] * wl[2];
    y = lrelu(y * s + bi);
    best = fmaxf(best, y);
  }
  xcat[(size_t)p * 512 + lane] = best;
  xcatb[(size_t)p * 512 + lane] = __float2bfloat16(best);
}

// ---------------- fp32 pointwise GEMM, raw store (T for layers 2-3) ----------------
__global__ __launch_bounds__(256) void k_pwT(const float* __restrict__ A, int lda, int K,
                                             const float* __restrict__ W, int ldw, int wsub,
                                             float* __restrict__ out, int ldo) {
  __shared__ __align__(16) float As[16][68];
  __shared__ __align__(16) float Bs[16][68];
  const int tid = threadIdx.x;
  const int tx = tid & 15, ty = tid >> 4;
  const int i0 = blockIdx.x * 64, o0 = blockIdx.y * 64;
  const int row = tid >> 2, q = (tid & 3) * 4;
  float acc[4][4] = {};
  for (int c0 = 0; c0 < K; c0 += 16) {
    float4 a = *(const float4*)(A + (size_t)(i0 + row) * lda + c0 + q);
    As[q + 0][row] = a.x; As[q + 1][row] = a.y; As[q + 2][row] = a.z; As[q + 3][row] = a.w;
    const float* wp = W + (size_t)(o0 + row) * ldw + c0 + q;
#pragma unroll
    for (int e = 0; e < 4; ++e) Bs[q + e][row] = wp[wsub + e] - wp[e];
    __syncthreads();
#pragma unroll
    for (int kk = 0; kk < 16; ++kk) {
      const float4 a4 = *(const float4*)&As[kk][ty * 4];
      const float4 b4 = *(const float4*)&Bs[kk][tx * 4];
      const float av[4] = {a4.x, a4.y, a4.z, a4.w};
      const float bv[4] = {b4.x, b4.y, b4.z, b4.w};
#pragma unroll
      for (int ii = 0; ii < 4; ++ii)
#pragma unroll
        for (int jj = 0; jj < 4; ++jj)
          acc[ii][jj] = fmaf(av[ii], bv[jj], acc[ii][jj]);
    }
    __syncthreads();
  }
#pragma unroll
  for (int ii = 0; ii < 4; ++ii)
#pragma unroll
    for (int jj = 0; jj < 4; ++jj)
      out[(size_t)(i0 + ty * 4 + ii) * ldo + o0 + tx * 4 + jj] = acc[ii][jj];
}

// ---------------- fp32 EdgeConv GEMM (layers 2-3; feeds kNN, stays exact) ----------------
__global__ __launch_bounds__(256) void k_edge(const float* __restrict__ F, int ldf, int Cin,
                                              const float* __restrict__ W,
                                              const float* __restrict__ sc,
                                              const float* __restrict__ bi,
                                              const int* __restrict__ idx,
                                              const float* __restrict__ T, int ldt,
                                              float* __restrict__ out,
                                              __hip_bfloat16* __restrict__ outb) {
  __shared__ float As[16][81];
  __shared__ __align__(16) float Bs[16][68];
  __shared__ float Ys[80][65];
  const int tid = threadIdx.x;
  const int tx = tid & 15, ty = tid >> 4;
  const int r0 = blockIdx.x * 80;
  const int o0 = blockIdx.y * 64;
  const int ldw = 2 * Cin;
  int grow[5], gcol[5];
#pragma unroll
  for (int l = 0; l < 5; ++l) {
    int e = tid + l * 256;
    int rr = e >> 4;
    gcol[l] = e & 15;
    int gr = r0 + rr;
    int p = gr / 20;
    int j = idx[(size_t)p * 20 + (gr % 20)];
    grow[l] = ((p >> 12) << 12) + j;
  }
  float acc[5][4] = {};
  const int wrow = tid >> 2, wq = (tid & 3) * 4;
  for (int c0 = 0; c0 < Cin; c0 += 16) {
#pragma unroll
    for (int l = 0; l < 5; ++l) {
      int e = tid + l * 256;
      As[gcol[l]][e >> 4] = F[(size_t)grow[l] * ldf + c0 + gcol[l]];
    }
    {
      const float* wp = W + (size_t)(o0 + wrow) * ldw + c0 + wq;
#pragma unroll
      for (int e = 0; e < 4; ++e) Bs[wq + e][wrow] = wp[e];
    }
    __syncthreads();
#pragma unroll
    for (int kk = 0; kk < 16; ++kk) {
      float a[5];
#pragma unroll
      for (int l = 0; l < 5; ++l) a[l] = As[kk][ty + l * 16];
      const float4 b4 = *(const float4*)&Bs[kk][tx * 4];
      const float bv[4] = {b4.x, b4.y, b4.z, b4.w};
#pragma unroll
      for (int l = 0; l < 5; ++l)
#pragma unroll
        for (int jj = 0; jj < 4; ++jj)
          acc[l][jj] = fmaf(a[l], bv[jj], acc[l][jj]);
    }
    __syncthreads();
  }
#pragma unroll
  for (int l = 0; l < 5; ++l) {
    int r = ty + l * 16;
    int p = (r0 + r) / 20;
#pragma unroll
    for (int jj = 0; jj < 4; ++jj) {
      int o = o0 + tx * 4 + jj;
      float y = (acc[l][jj] + T[(size_t)p * ldt + o]) * sc[o] + bi[o];
      Ys[r][tx * 4 + jj] = lrelu(y);
    }
  }
  __syncthreads();
  const int grp = tid >> 6, col = tid & 63;
  float m = -INFINITY;
#pragma unroll
  for (int k = 0; k < 20; ++k) m = fmaxf(m, Ys[grp * 20 + k][col]);
  const int p = blockIdx.x * 4 + grp;
  out[(size_t)p * 512 + o0 + col] = m;
  outb[(size_t)p * 512 + o0 + col] = __float2bfloat16(m);
}

// ---------------- MFMA bf16 GEMM: block 128(M)x64(N), 4 waves x (32x64) ----------------
template <int EPI>
__global__ __launch_bounds__(256) void k_mm(
    const __hip_bfloat16* __restrict__ A, int lda, int K,
    const __hip_bfloat16* __restrict__ B,  // [N][K] bf16
    const float* __restrict__ sc, const float* __restrict__ bi,
    const float* __restrict__ extra, int Ncols,
    float* __restrict__ outf, int ldof,
    __hip_bfloat16* __restrict__ outb, int ldob,
    unsigned* __restrict__ gmax) {
  __shared__ __align__(16) __hip_bfloat16 Al[128 * 40];
  __shared__ __align__(16) __hip_bfloat16 Bl[64 * 40];
  __shared__ float Red[4][64];
  const int tid = threadIdx.x, lane = tid & 63, wv = tid >> 6;
  const int m0 = blockIdx.x * 128, n0 = blockIdx.y * 64;
  const int arow = tid >> 2, akc = (tid & 3) * 8;
  const int fm = lane & 15, fq = lane >> 4;
  f32x4 acc[2][4];
#pragma unroll
  for (int mt = 0; mt < 2; ++mt)
#pragma unroll
    for (int nt = 0; nt < 4; ++nt) acc[mt][nt] = (f32x4){0.f, 0.f, 0.f, 0.f};
  for (int c0 = 0; c0 < K; c0 += 32) {
#pragma unroll
    for (int l = 0; l < 2; ++l) {
      int r = arow + l * 64;
      *(float4*)&Al[r * 40 + akc] = *(const float4*)(A + (size_t)(m0 + r) * lda + c0 + akc);
    }
    *(float4*)&Bl[arow * 40 + akc] = *(const float4*)(B + (size_t)(n0 + arow) * K + c0 + akc);
    __syncthreads();
    bf16x8 af[2], bfr[4];
#pragma unroll
    for (int mt = 0; mt < 2; ++mt)
      af[mt] = *(const bf16x8*)&Al[(wv * 32 + mt * 16 + fm) * 40 + fq * 8];
#pragma unroll
    for (int nt = 0; nt < 4; ++nt)
      bfr[nt] = *(const bf16x8*)&Bl[(nt * 16 + fm) * 40 + fq * 8];
#pragma unroll
    for (int mt = 0; mt < 2; ++mt)
#pragma unroll
      for (int nt = 0; nt < 4; ++nt)
        acc[mt][nt] = __builtin_amdgcn_mfma_f32_16x16x32_bf16(af[mt], bfr[nt], acc[mt][nt], 0, 0, 0);
    __syncthreads();
  }
  const int bidx = m0 >> 12;
  if (EPI == 0) {
#pragma unroll
    for (int mt = 0; mt < 2; ++mt)
#pragma unroll
      for (int nt = 0; nt < 4; ++nt)
#pragma unroll
        for (int r = 0; r < 4; ++r)
          outf[(size_t)(m0 + wv * 32 + mt * 16 + fq * 4 + r) * ldof + n0 + nt * 16 + fm] =
              acc[mt][nt][r];
  } else if (EPI == 1) {
#pragma unroll
    for (int nt = 0; nt < 4; ++nt) {
      int col = n0 + nt * 16 + fm;
      float s = sc[col], bb = bi[col];
      float ex = extra ? extra[bidx * Ncols + col] : 0.f;
#pragma unroll
      for (int mt = 0; mt < 2; ++mt)
#pragma unroll
        for (int r = 0; r < 4; ++r) {
          float v = lrelu((acc[mt][nt][r] + ex) * s + bb);
          size_t rr = (size_t)(m0 + wv * 32 + mt * 16 + fq * 4 + r);
          if (outf) outf[rr * ldof + col] = v;
          if (outb) outb[rr * ldob + col] = __float2bfloat16(v);
        }
    }
  } else {
#pragma unroll
    for (int nt = 0; nt < 4; ++nt) {
      int col = n0 + nt * 16 + fm;
      float s = sc[col], bb = bi[col];
      float m = -INFINITY;
#pragma unroll
      for (int mt = 0; mt < 2; ++mt)
#pragma unroll
        for (int r = 0; r < 4; ++r) m = fmaxf(m, lrelu(acc[mt][nt][r] * s + bb));
      m = fmaxf(m, __shfl_xor(m, 16, 64));
      m = fmaxf(m, __shfl_xor(m, 32, 64));
      if (fq == 0) Red[wv][nt * 16 + fm] = m;
    }
    __syncthreads();
    if (tid < 64) {
      float m = fmaxf(fmaxf(Red[0][tid], Red[1][tid]), fmaxf(Red[2][tid], Red[3][tid]));
      atomicMax(&gmax[bidx * Ncols + n0 + tid], okey(m));
    }
  }
}

// ---------------- MFMA bf16 EdgeConv (layer 4): 320 edges x 64 cols / block ----------------
__global__ __launch_bounds__(256) void k_edgem(
    const __hip_bfloat16* __restrict__ F, int ldf, int coff, int K,
    const __hip_bfloat16* __restrict__ Wl,  // [N][K] bf16
    const float* __restrict__ sc, const float* __restrict__ bi,
    const float* __restrict__ T, int N,
    const int* __restrict__ idx,
    float* __restrict__ outf, __hip_bfloat16* __restrict__ outb) {
  __shared__ __align__(16) char smem[320 * 66 * 2];  // 42240 B, overlaid stage/Ys
  __hip_bfloat16* Al = (__hip_bfloat16*)smem;              // 320*40
  __hip_bfloat16* Bl = (__hip_bfloat16*)(smem + 25600);    // 64*40
  __hip_bfloat16* Ys = (__hip_bfloat16*)smem;              // 320*66 (post-loop)
  const int tid = threadIdx.x, lane = tid & 63, wv = tid >> 6;
  const int blk = blockIdx.x, n0 = blockIdx.y * 64;
  const int arow = tid >> 2, akc = (tid & 3) * 8;
  const int fm = lane & 15, fq = lane >> 4;
  const __hip_bfloat16* ap[5];
#pragma unroll
  for (int l = 0; l < 5; ++l) {
    int row = arow + l * 64;
    int e = blk * 320 + row;
    int p = e / 20;
    int j = idx[(size_t)p * 20 + (e - p * 20)];
    int src = ((p >> 12) << 12) + j;
    ap[l] = F + (size_t)src * ldf + coff + akc;
  }
  f32x4 acc[5][4];
#pragma unroll
  for (int l = 0; l < 5; ++l)
#pragma unroll
    for (int nt = 0; nt < 4; ++nt) acc[l][nt] = (f32x4){0.f, 0.f, 0.f, 0.f};
  for (int c0 = 0; c0 < K; c0 += 32) {
#pragma unroll
    for (int l = 0; l < 5; ++l)
      *(float4*)&Al[(arow + l * 64) * 40 + akc] = *(const float4*)(ap[l] + c0);
    *(float4*)&Bl[arow * 40 + akc] = *(const float4*)(Wl + (size_t)(n0 + arow) * K + c0 + akc);
    __syncthreads();
    bf16x8 af[5], bfr[4];
#pragma unroll
    for (int l = 0; l < 5; ++l)
      af[l] = *(const bf16x8*)&Al[(wv * 80 + l * 16 + fm) * 40 + fq * 8];
#pragma unroll
    for (int nt = 0; nt < 4; ++nt)
      bfr[nt] = *(const bf16x8*)&Bl[(nt * 16 + fm) * 40 + fq * 8];
#pragma unroll
    for (int l = 0; l < 5; ++l)
#pragma unroll
      for (int nt = 0; nt < 4; ++nt)
        acc[l][nt] = __builtin_amdgcn_mfma_f32_16x16x32_bf16(af[l], bfr[nt], acc[l][nt], 0, 0, 0);
    __syncthreads();
  }
#pragma unroll
  for (int l = 0; l < 5; ++l)
#pragma unroll
    for (int nt = 0; nt < 4; ++nt)
#pragma unroll
      for (int r = 0; r < 4; ++r)
        Ys[(wv * 80 + l * 16 + fq * 4 + r) * 66 + nt * 16 + fm] = __float2bfloat16(acc[l][nt][r]);
  __syncthreads();
  const int col = tid & 63;
#pragma unroll
  for (int gi = 0; gi < 4; ++gi) {
    int grp = wv + gi * 4;
    float m = -INFINITY;
#pragma unroll
    for (int k = 0; k < 20; ++k)
      m = fmaxf(m, __bfloat162float(Ys[(grp * 20 + k) * 66 + col]));
    int p = blk * 16 + grp;
    int o = n0 + col;
    float v = lrelu((m + T[(size_t)p * N + o]) * sc[o] + bi[o]);
    outf[(size_t)p * 512 + o] = v;
    outb[(size_t)p * 512 + o] = __float2bfloat16(v);
  }
}

// ---------------- bias2: one wave per (b,o) ----------------
__global__ __launch_bounds__(256) void k_bias2(const unsigned* __restrict__ gk,
                                               const float* __restrict__ Ws1,
                                               float* __restrict__ b2g) {
  const int lane = threadIdx.x & 63;
  const int wid = (blockIdx.x * 256 + threadIdx.x) >> 6;  // 0..1023
  const int b = wid >> 9, o = wid & 511;
  const float* wr = Ws1 + (size_t)o * 1536 + 512;
  const unsigned* g = gk + b * 1024;
  float acc = 0.f;
#pragma unroll
  for (int c = lane; c < 1024; c += 64) acc = fmaf(dekey(g[c]), wr[c], acc);
#pragma unroll
  for (int off = 32; off; off >>= 1) acc += __shfl_xor(acc, off, 64);
  if (lane == 0) b2g[b * 512 + o] = acc;
}

// ---------------- final head: out = H(8192x256) . Ws3^T + bs3 (fp32) ----------------
__global__ __launch_bounds__(256) void k_out(const float* __restrict__ H,
                                             const float* __restrict__ Ws3,
                                             const float* __restrict__ bs3,
                                             float* __restrict__ out) {
  __shared__ float Ws[13][256];
  const int tid = threadIdx.x;
  for (int e = tid; e < 13 * 256; e += 256) Ws[e >> 8][e & 255] = Ws3[e];
  __syncthreads();
  const int rloc = tid >> 4, o = tid & 15;
  const int row = blockIdx.x * 16 + rloc;
  if (o < 13) {
    const float* h = H + (size_t)row * 256;
    float acc = 0.f;
    for (int c = 0; c < 256; ++c) acc = fmaf(h[c], Ws[o][c], acc);
    out[(size_t)row * 13 + o] = acc + bs3[o];
  }
}

extern "C" void kernel_launch(void* const* d_in, const int* in_sizes, int n_in,
                              void* d_out, int out_size, void* d_ws, size_t ws_size,
                              hipStream_t stream) {
  const float* X   = (const float*)d_in[0];
  const float* W1  = (const float*)d_in[1];
  const float* S1  = (const float*)d_in[2];
  const float* B1  = (const float*)d_in[3];
  const float* W2  = (const float*)d_in[4];
  const float* S2  = (const float*)d_in[5];
  const float* B2  = (const float*)d_in[6];
  const float* W3  = (const float*)d_in[7];
  const float* S3  = (const float*)d_in[8];
  const float* B3  = (const float*)d_in[9];
  const float* W4  = (const float*)d_in[10];
  const float* S4  = (const float*)d_in[11];
  const float* B4  = (const float*)d_in[12];
  const float* Wg  = (const float*)d_in[13];
  const float* Sg  = (const float*)d_in[14];
  const float* Bg  = (const float*)d_in[15];
  const float* Ws1 = (const float*)d_in[16];
  const float* Ss1 = (const float*)d_in[17];
  const float* Bs1 = (const float*)d_in[18];
  const float* Ws2 = (const float*)d_in[19];
  const float* Ss2 = (const float*)d_in[20];
  const float* Bs2 = (const float*)d_in[21];
  const float* Ws3 = (const float*)d_in[22];
  const float* Bs3 = (const float*)d_in[23];

  char* ws = (char*)d_ws;
  float*           xxb   = (float*)(ws + 0);            // 32 KB
  int*             idxb  = (int*)(ws + 32768);          // 640 KB
  unsigned*        gk    = (unsigned*)(ws + 688128);    // 8 KB
  float*           b2g   = (float*)(ws + 696320);       // 4 KB
  __hip_bfloat16*  Wgb   = (__hip_bfloat16*)(ws + 1048576);  // 1 MB
  __hip_bfloat16*  Ws1b  = (__hip_bfloat16*)(ws + 2097152);  // 512 KB
  __hip_bfloat16*  Ws2b  = (__hip_bfloat16*)(ws + 2621440);  // 256 KB
  __hip_bfloat16*  Wlb4  = (__hip_bfloat16*)(ws + 2883584);  // 64 KB
  __hip_bfloat16*  Wdb4  = (__hip_bfloat16*)(ws + 2949120);  // 64 KB
  __hip_bfloat16*  xcatb = (__hip_bfloat16*)(ws + 3145728);  // 8 MB
  float*           xcat  = (float*)(ws + 11534336);          // 16 MB
  char*            region = ws + 28311552;                   // dist / Tbuf+h1b
  float*           dist  = (float*)(region);
  float*           Tbuf  = (float*)(region);
  __hip_bfloat16*  h1b   = (__hip_bfloat16*)(region + 8388608);

  // Full-batch dist (64 MB) if workspace allows; else 1024-row chunking.
  const bool big = (ws_size >= (size_t)28311552 + (64u << 20));

  hipMemsetAsync(gk, 0, 2 * 1024 * sizeof(unsigned), stream);

  // weight bf16 packs (L4 + head only; L1-L3 weights stay fp32)
  k_conv<<<dim3(256, 2), dim3(64), 0, stream>>>(W4, 256, 0, 0, 128, Wlb4);
  k_conv<<<dim3(256, 2), dim3(64), 0, stream>>>(W4, 256, 128, 1, 128, Wdb4);
  k_conv<<<dim3(1024, 8), dim3(64), 0, stream>>>(Wg, 512, 0, 0, 512, Wgb);
  k_conv<<<dim3(512, 8), dim3(64), 0, stream>>>(Ws1, 1536, 0, 0, 512, Ws1b);
  k_conv<<<dim3(256, 8), dim3(64), 0, stream>>>(Ws2, 512, 0, 0, 512, Ws2b);

  // kNN for one layer (fills idxb); selection bit-identical in both paths
  auto run_knn = [&](const float* F, int ldf, int C) {
    k_xx<<<dim3(2048), dim3(256), 0, stream>>>(F, ldf, C, xxb);
    if (big) {
      for (int b = 0; b < 2; ++b) {
        k_dist<<<dim3(32, 64), dim3(256), 0, stream>>>(F, ldf, C, xxb, dist, b, 0);
        k_topk<<<dim3(4096), dim3(256), 0, stream>>>(dist, idxb, b, 0);
      }
    } else {
      for (int b = 0; b < 2; ++b)
        for (int c = 0; c < 4; ++c) {
          k_dist<<<dim3(8, 64), dim3(256), 0, stream>>>(F, ldf, C, xxb, dist, b, c * 1024);
          k_topk<<<dim3(1024), dim3(256), 0, stream>>>(dist, idxb, b, c * 1024);
        }
    }
  };

  // ---- Layer 1 (C=3 -> 64, fp32 exact) ----
  run_knn(X, 3, 3);
  k_edge1<<<dim3(2048), dim3(256), 0, stream>>>(X, W1, S1, B1, idxb, xcat, xcatb);

  // ---- Layer 2 (64 -> 64), fp32 (feeds kNN — must stay exact, R9 proved it) ----
  run_knn(xcat, 512, 64);
  k_pwT<<<dim3(128, 1), dim3(256), 0, stream>>>(xcat, 512, 64, W2, 128, 64, Tbuf, 64);
  k_edge<<<dim3(2048, 1), dim3(256), 0, stream>>>(xcat, 512, 64, W2, S2, B2,
      idxb, Tbuf, 64, xcat + 64, xcatb + 64);

  // ---- Layer 3 (64 -> 128), fp32 (feeds kNN) ----
  run_knn(xcat + 64, 512, 64);
  k_pwT<<<dim3(128, 2), dim3(256), 0, stream>>>(xcat + 64, 512, 64, W3, 128, 64, Tbuf, 128);
  k_edge<<<dim3(2048, 2), dim3(256), 0, stream>>>(xcat + 64, 512, 64, W3, S3, B3,
      idxb, Tbuf, 128, xcat + 128, xcatb + 128);

  // ---- Layer 4 (128 -> 256), bf16 MFMA (x4 feeds nothing discrete) ----
  run_knn(xcat + 128, 512, 128);
  k_mm<0><<<dim3(64, 4), dim3(256), 0, stream>>>(xcatb + 128, 512, 128, Wdb4,
      nullptr, nullptr, nullptr, 256, Tbuf, 256, nullptr, 0, nullptr);
  k_edgem<<<dim3(512, 4), dim3(256), 0, stream>>>(xcatb, 512, 128, 128, Wlb4,
      S4, B4, Tbuf, 256, idxb, xcat + 256, xcatb + 256);

  // ---- head (all bf16 MFMA) ----
  k_mm<2><<<dim3(64, 16), dim3(256), 0, stream>>>(xcatb, 512, 512, Wgb,
      Sg, Bg, nullptr, 1024, nullptr, 0, nullptr, 0, gk);
  k_bias2<<<dim3(256), dim3(256), 0, stream>>>(gk, Ws1, b2g);
  k_mm<1><<<dim3(64, 8), dim3(256), 0, stream>>>(xcatb, 512, 512, Ws1b,
      Ss1, Bs1, b2g, 512, nullptr, 0, h1b, 512, nullptr);
  k_mm<1><<<dim3(64, 4), dim3(256), 0, stream>>>(h1b, 512, 512, Ws2b,
      Ss2, Bs2, nullptr, 256, Tbuf, 256, nullptr, 0, nullptr);
  k_out<<<dim3(512), dim3(256), 0, stream>>>(Tbuf, Ws3, Bs3, (float*)d_out);
}

// Round 13
// 998.372 us; speedup vs baseline: 1.0747x; 1.0747x over previous
//
#include <hip/hip_runtime.h>
#include <hip/hip_bf16.h>

// DGCNN_Seg forward. B=2, N=4096, K=20. fp32 in/out.
// Round 13: k_topk v5 — no sort, no shift-pop: per-lane top-3 tournament
// window + dual-u32 min-tree extraction + rare divergent refill. k_dist
// stores okey(d) u32 (monotone -> selection bit-identical). Rest = R11 (best).

#define DEVI static __device__ __forceinline__
typedef __attribute__((ext_vector_type(8))) short bf16x8;   // 8 bf16 = 4 VGPR
typedef __attribute__((ext_vector_type(4))) float f32x4;    // MFMA acc
typedef unsigned long long ull;

DEVI float lrelu(float y) { return y > 0.f ? y : 0.2f * y; }
DEVI unsigned okey(float f) {
  unsigned u = __float_as_uint(f);
  return (f < 0.f) ? ~u : (u | 0x80000000u);
}
DEVI float dekey(unsigned k) {
  return __uint_as_float((k & 0x80000000u) ? (k & 0x7fffffffu) : ~k);
}

// ---------------- weight fp32 -> bf16 pack ----------------
__global__ __launch_bounds__(64) void k_conv(const float* __restrict__ src, int lds, int off,
                                             int sub, int Kc, __hip_bfloat16* __restrict__ dst) {
  int o = blockIdx.x, c = blockIdx.y * 64 + threadIdx.x;
  float v = src[(size_t)o * lds + off + c];
  if (sub) v -= src[(size_t)o * lds + c];
  dst[(size_t)o * Kc + c] = __float2bfloat16(v);
}

// ---------------- row squared-norms: one wave per row ----------------
__global__ __launch_bounds__(256) void k_xx(const float* __restrict__ F, int ldf, int C,
                                            float* __restrict__ xx) {
  int lane = threadIdx.x & 63;
  int row = blockIdx.x * 4 + (threadIdx.x >> 6);
  const float* f = F + (size_t)row * ldf;
  float s = 0.f;
  for (int c = lane; c < C; c += 64) { float v = f[c]; s += v * v; }
#pragma unroll
  for (int off = 32; off; off >>= 1) s += __shfl_xor(s, off, 64);
  if (lane == 0) xx[row] = s;
}

// ---------------- pairwise distances v2: 128x64 tile, 8x4 per thread ----------------
// Stores okey(d) as u32 (order-preserving bijection of the fp32 distance).
// fmaf order per element identical to earlier rounds -> selection bit-identical.
__global__ __launch_bounds__(256) void k_dist(const float* __restrict__ F, int ldf, int C,
                                              const float* __restrict__ xx,
                                              unsigned* __restrict__ D, int b, int ibase) {
  __shared__ __align__(16) float As[16][132];
  __shared__ __align__(16) float Bs[16][68];
  const int tid = threadIdx.x;
  const int tx = tid & 15, ty = tid >> 4;
  const int i0 = ibase + blockIdx.x * 128, j0 = blockIdx.y * 64;
  const float* Fb = F + (size_t)b * 4096 * ldf;
  const int arow = tid >> 1, q8 = (tid & 1) * 8;   // A stage: 128 rows x 16 cols
  const int brow = tid >> 2, q4 = (tid & 3) * 4;   // B stage: 64 rows x 16 cols
  float acc[8][4] = {};
  for (int c0 = 0; c0 < C; c0 += 16) {
    if (C - c0 >= 16) {
      float4 a0 = *(const float4*)(Fb + (size_t)(i0 + arow) * ldf + c0 + q8);
      float4 a1 = *(const float4*)(Fb + (size_t)(i0 + arow) * ldf + c0 + q8 + 4);
      As[q8 + 0][arow] = a0.x; As[q8 + 1][arow] = a0.y; As[q8 + 2][arow] = a0.z; As[q8 + 3][arow] = a0.w;
      As[q8 + 4][arow] = a1.x; As[q8 + 5][arow] = a1.y; As[q8 + 6][arow] = a1.z; As[q8 + 7][arow] = a1.w;
      float4 w = *(const float4*)(Fb + (size_t)(j0 + brow) * ldf + c0 + q4);
      Bs[q4 + 0][brow] = w.x; Bs[q4 + 1][brow] = w.y; Bs[q4 + 2][brow] = w.z; Bs[q4 + 3][brow] = w.w;
    } else {
#pragma unroll
      for (int e = 0; e < 8; ++e) {
        int c = c0 + q8 + e;
        As[q8 + e][arow] = (c < C) ? Fb[(size_t)(i0 + arow) * ldf + c] : 0.f;
      }
#pragma unroll
      for (int e = 0; e < 4; ++e) {
        int c = c0 + q4 + e;
        Bs[q4 + e][brow] = (c < C) ? Fb[(size_t)(j0 + brow) * ldf + c] : 0.f;
      }
    }
    __syncthreads();
#pragma unroll
    for (int kk = 0; kk < 16; ++kk) {
      const float4 a4l = *(const float4*)&As[kk][ty * 8];
      const float4 a4h = *(const float4*)&As[kk][ty * 8 + 4];
      const float4 b4 = *(const float4*)&Bs[kk][tx * 4];
      const float av[8] = {a4l.x, a4l.y, a4l.z, a4l.w, a4h.x, a4h.y, a4h.z, a4h.w};
      const float bv[4] = {b4.x, b4.y, b4.z, b4.w};
#pragma unroll
      for (int ii = 0; ii < 8; ++ii)
#pragma unroll
        for (int jj = 0; jj < 4; ++jj)
          acc[ii][jj] = fmaf(av[ii], bv[jj], acc[ii][jj]);
    }
    __syncthreads();
  }
  const float* xxb = xx + b * 4096;
#pragma unroll
  for (int ii = 0; ii < 8; ++ii) {
    int i = i0 + ty * 8 + ii;
    float xi = xxb[i];
    uint4 o;
    o.x = okey(xi + xxb[j0 + tx * 4 + 0] - 2.f * acc[ii][0]);
    o.y = okey(xi + xxb[j0 + tx * 4 + 1] - 2.f * acc[ii][1]);
    o.z = okey(xi + xxb[j0 + tx * 4 + 2] - 2.f * acc[ii][2]);
    o.w = okey(xi + xxb[j0 + tx * 4 + 3] - 2.f * acc[ii][3]);
    *(uint4*)&D[(size_t)(i - ibase) * 4096 + j0 + tx * 4] = o;
  }
}

// ---------------- top-20 v5: 1 block (4 waves) per row ----------------
// Per lane: keep 16 keys in regs; one-pass top-3 tournament (keys+positions).
// Extraction: 20 rounds of dual u32 wave-min (hi=okey, lo=pos10=lane|it<<6;
// pos10 unique per lane -> exactly one pop), 3-deep register window, rare
// divergent refill via consumed-bitmask scan. Selection order bit-identical
// to the sorted-(okey,j) pop order.
__global__ __launch_bounds__(256) void k_topk(const unsigned* __restrict__ Dk,
                                              int* __restrict__ idx, int b, int ibase) {
  __shared__ ull cand[4][20];
  const int tid = threadIdx.x, lane = tid & 63, wv = tid >> 6;
  const int ir_ = blockIdx.x;
  const unsigned* drow = Dk + (size_t)ir_ * 4096;
  const int base = wv * 1024 + lane;
  unsigned key[16];
#pragma unroll
  for (int it = 0; it < 16; ++it) key[it] = drow[base + it * 64];
  // one-pass top-3 tournament with positions (strict < : earliest it wins ties
  // = smallest j within lane, matching (okey,j) order)
  unsigned m1k = 0xFFFFFFFFu, m2k = 0xFFFFFFFFu, m3k = 0xFFFFFFFFu;
  int m1p = 0, m2p = 0, m3p = 0;
#pragma unroll
  for (int it = 0; it < 16; ++it) {
    unsigned v = key[it];
    bool b1 = v < m1k, b2 = v < m2k, b3 = v < m3k;
    m3k = b2 ? m2k : (b3 ? v : m3k);
    m3p = b2 ? m2p : (b3 ? it : m3p);
    m2k = b1 ? m1k : (b2 ? v : m2k);
    m2p = b1 ? m1p : (b2 ? it : m2p);
    m1k = b1 ? v : m1k;
    m1p = b1 ? it : m1p;
  }
  unsigned consumed = (1u << m1p) | (1u << m2p) | (1u << m3p);
  unsigned ck = m1k, cp = (unsigned)(lane | (m1p << 6));
  unsigned n1k = m2k, n1p = (unsigned)(lane | (m2p << 6));
  unsigned n2k = m3k, n2p = (unsigned)(lane | (m3p << 6));
  for (int r = 0; r < 20; ++r) {
    unsigned mh = ck;
#pragma unroll
    for (int off = 32; off; off >>= 1) {
      unsigned o = __shfl_xor(mh, off, 64);
      mh = o < mh ? o : mh;
    }
    unsigned lo2 = (ck == mh) ? cp : 0xFFFFFFFFu;
    unsigned ml = lo2;
#pragma unroll
    for (int off = 32; off; off >>= 1) {
      unsigned o = __shfl_xor(ml, off, 64);
      ml = o < ml ? o : ml;
    }
    if (lane == 0) cand[wv][r] = ((ull)mh << 32) | (unsigned)(wv * 1024 + ml);
    bool pop = (ck == mh) && (cp == ml);
    ck = pop ? n1k : ck;  cp = pop ? n1p : cp;
    n1k = pop ? n2k : n1k; n1p = pop ? n2p : n1p;
    n2k = pop ? 0xFFFFFFFFu : n2k;
    if (ck == 0xFFFFFFFFu) {  // rare: lane popped >=3 times; refill from regs
      unsigned bk = 0xFFFFFFFFu; int bp = 0;
#pragma unroll
      for (int it2 = 0; it2 < 16; ++it2) {
        bool ok = ((consumed >> it2) & 1u) == 0u;
        unsigned v = ok ? key[it2] : 0xFFFFFFFFu;
        bool t = v < bk;
        bk = t ? v : bk;
        bp = t ? it2 : bp;
      }
      consumed |= (1u << bp);
      ck = bk;
      cp = (unsigned)(lane | (bp << 6));
    }
  }
  __syncthreads();
  if (tid == 0) {
    int* op = idx + ((size_t)b * 4096 + ibase + ir_) * 20;
    int p0 = 0, p1 = 0, p2 = 0, p3 = 0;
    for (int r = 0; r < 20; ++r) {
      ull v0 = cand[0][p0], v1 = cand[1][p1], v2 = cand[2][p2], v3 = cand[3][p3];
      ull m01 = v0 < v1 ? v0 : v1;
      ull m23 = v2 < v3 ? v2 : v3;
      ull best = m01 < m23 ? m01 : m23;
      if (best == v0) ++p0; else if (best == v1) ++p1;
      else if (best == v2) ++p2; else ++p3;
      op[r] = (int)(best & 0xfffull);
      if (p0 > 19) p0 = 19;
      if (p1 > 19) p1 = 19;
      if (p2 > 19) p2 = 19;
      if (p3 > 19) p3 = 19;
    }
  }
}

// ---------------- EdgeConv layer 1 (fp32, Cin=3): one wave per point ----------------
__global__ __launch_bounds__(256) void k_edge1(const float* __restrict__ xf,
                                               const float* __restrict__ W1,
                                               const float* __restrict__ s1,
                                               const float* __restrict__ b1,
                                               const int* __restrict__ idx,
                                               float* __restrict__ xcat,
                                               __hip_bfloat16* __restrict__ xcatb) {
  const int lane = threadIdx.x & 63;
  const int p = blockIdx.x * 4 + (threadIdx.x >> 6);
  const int bb = p >> 12;
  float wl[3], wr[3];
#pragma unroll
  for (int c = 0; c < 3; ++c) {
    wl[c] = W1[lane * 6 + c];
    wr[c] = W1[lane * 6 + 3 + c];
  }
  const float s = s1[lane], bi = b1[lane];
  const float* xc = xf + (size_t)p * 3;
  const float x0 = xc[0], x1 = xc[1], x2 = xc[2];
  const float t = x0 * (wr[0] - wl[0]) + x1 * (wr[1] - wl[1]) + x2 * (wr[2] - wl[2]);
  const int* ir = idx + (size_t)p * 20;
  float best = -INFINITY;
  for (int k = 0; k < 20; ++k) {
    int j = ir[k];
    const float* xn = xf + ((size_t)(bb << 12) + j) * 3;
    float y = t + xn[0] * wl[0] + xn[1] * wl[1] + xn[2] * wl[2];
    y = lrelu(y * s + bi);
    best = fmaxf(best, y);
  }
  xcat[(size_t)p * 512 + lane] = best;
  xcatb[(size_t)p * 512 + lane] = __float2bfloat16(best);
}

// ---------------- fp32 pointwise GEMM, raw store (T for layers 2-3) ----------------
__global__ __launch_bounds__(256) void k_pwT(const float* __restrict__ A, int lda, int K,
                                             const float* __restrict__ W, int ldw, int wsub,
                                             float* __restrict__ out, int ldo) {
  __shared__ __align__(16) float As[16][68];
  __shared__ __align__(16) float Bs[16][68];
  const int tid = threadIdx.x;
  const int tx = tid & 15, ty = tid >> 4;
  const int i0 = blockIdx.x * 64, o0 = blockIdx.y * 64;
  const int row = tid >> 2, q = (tid & 3) * 4;
  float acc[4][4] = {};
  for (int c0 = 0; c0 < K; c0 += 16) {
    float4 a = *(const float4*)(A + (size_t)(i0 + row) * lda + c0 + q);
    As[q + 0][row] = a.x; As[q + 1][row] = a.y; As[q + 2][row] = a.z; As[q + 3][row] = a.w;
    const float* wp = W + (size_t)(o0 + row) * ldw + c0 + q;
#pragma unroll
    for (int e = 0; e < 4; ++e) Bs[q + e][row] = wp[wsub + e] - wp[e];
    __syncthreads();
#pragma unroll
    for (int kk = 0; kk < 16; ++kk) {
      const float4 a4 = *(const float4*)&As[kk][ty * 4];
      const float4 b4 = *(const float4*)&Bs[kk][tx * 4];
      const float av[4] = {a4.x, a4.y, a4.z, a4.w};
      const float bv[4] = {b4.x, b4.y, b4.z, b4.w};
#pragma unroll
      for (int ii = 0; ii < 4; ++ii)
#pragma unroll
        for (int jj = 0; jj < 4; ++jj)
          acc[ii][jj] = fmaf(av[ii], bv[jj], acc[ii][jj]);
    }
    __syncthreads();
  }
#pragma unroll
  for (int ii = 0; ii < 4; ++ii)
#pragma unroll
    for (int jj = 0; jj < 4; ++jj)
      out[(size_t)(i0 + ty * 4 + ii) * ldo + o0 + tx * 4 + jj] = acc[ii][jj];
}

// ---------------- fp32 EdgeConv GEMM (layers 2-3; feeds kNN, stays exact) ----------------
__global__ __launch_bounds__(256) void k_edge(const float* __restrict__ F, int ldf, int Cin,
                                              const float* __restrict__ W,
                                              const float* __restrict__ sc,
                                              const float* __restrict__ bi,
                                              const int* __restrict__ idx,
                                              const float* __restrict__ T, int ldt,
                                              float* __restrict__ out,
                                              __hip_bfloat16* __restrict__ outb) {
  __shared__ float As[16][81];
  __shared__ __align__(16) float Bs[16][68];
  __shared__ float Ys[80][65];
  const int tid = threadIdx.x;
  const int tx = tid & 15, ty = tid >> 4;
  const int r0 = blockIdx.x * 80;
  const int o0 = blockIdx.y * 64;
  const int ldw = 2 * Cin;
  int grow[5], gcol[5];
#pragma unroll
  for (int l = 0; l < 5; ++l) {
    int e = tid + l * 256;
    int rr = e >> 4;
    gcol[l] = e & 15;
    int gr = r0 + rr;
    int p = gr / 20;
    int j = idx[(size_t)p * 20 + (gr % 20)];
    grow[l] = ((p >> 12) << 12) + j;
  }
  float acc[5][4] = {};
  const int wrow = tid >> 2, wq = (tid & 3) * 4;
  for (int c0 = 0; c0 < Cin; c0 += 16) {
#pragma unroll
    for (int l = 0; l < 5; ++l) {
      int e = tid + l * 256;
      As[gcol[l]][e >> 4] = F[(size_t)grow[l] * ldf + c0 + gcol[l]];
    }
    {
      const float* wp = W + (size_t)(o0 + wrow) * ldw + c0 + wq;
#pragma unroll
      for (int e = 0; e < 4; ++e) Bs[wq + e][wrow] = wp[e];
    }
    __syncthreads();
#pragma unroll
    for (int kk = 0; kk < 16; ++kk) {
      float a[5];
#pragma unroll
      for (int l = 0; l < 5; ++l) a[l] = As[kk][ty + l * 16];
      const float4 b4 = *(const float4*)&Bs[kk][tx * 4];
      const float bv[4] = {b4.x, b4.y, b4.z, b4.w};
#pragma unroll
      for (int l = 0; l < 5; ++l)
#pragma unroll
        for (int jj = 0; jj < 4; ++jj)
          acc[l][jj] = fmaf(a[l], bv[jj], acc[l][jj]);
    }
    __syncthreads();
  }
#pragma unroll
  for (int l = 0; l < 5; ++l) {
    int r = ty + l * 16;
    int p = (r0 + r) / 20;
#pragma unroll
    for (int jj = 0; jj < 4; ++jj) {
      int o = o0 + tx * 4 + jj;
      float y = (acc[l][jj] + T[(size_t)p * ldt + o]) * sc[o] + bi[o];
      Ys[r][tx * 4 + jj] = lrelu(y);
    }
  }
  __syncthreads();
  const int grp = tid >> 6, col = tid & 63;
  float m = -INFINITY;
#pragma unroll
  for (int k = 0; k < 20; ++k) m = fmaxf(m, Ys[grp * 20 + k][col]);
  const int p = blockIdx.x * 4 + grp;
  out[(size_t)p * 512 + o0 + col] = m;
  outb[(size_t)p * 512 + o0 + col] = __float2bfloat16(m);
}

// ---------------- MFMA bf16 GEMM: block 128(M)x64(N), 4 waves x (32x64) ----------------
template <int EPI>
__global__ __launch_bounds__(256) void k_mm(
    const __hip_bfloat16* __restrict__ A, int lda, int K,
    const __hip_bfloat16* __restrict__ B,  // [N][K] bf16
    const float* __restrict__ sc, const float* __restrict__ bi,
    const float* __restrict__ extra, int Ncols,
    float* __restrict__ outf, int ldof,
    __hip_bfloat16* __restrict__ outb, int ldob,
    unsigned* __restrict__ gmax) {
  __shared__ __align__(16) __hip_bfloat16 Al[128 * 40];
  __shared__ __align__(16) __hip_bfloat16 Bl[64 * 40];
  __shared__ float Red[4][64];
  const int tid = threadIdx.x, lane = tid & 63, wv = tid >> 6;
  const int m0 = blockIdx.x * 128, n0 = blockIdx.y * 64;
  const int arow = tid >> 2, akc = (tid & 3) * 8;
  const int fm = lane & 15, fq = lane >> 4;
  f32x4 acc[2][4];
#pragma unroll
  for (int mt = 0; mt < 2; ++mt)
#pragma unroll
    for (int nt = 0; nt < 4; ++nt) acc[mt][nt] = (f32x4){0.f, 0.f, 0.f, 0.f};
  for (int c0 = 0; c0 < K; c0 += 32) {
#pragma unroll
    for (int l = 0; l < 2; ++l) {
      int r = arow + l * 64;
      *(float4*)&Al[r * 40 + akc] = *(const float4*)(A + (size_t)(m0 + r) * lda + c0 + akc);
    }
    *(float4*)&Bl[arow * 40 + akc] = *(const float4*)(B + (size_t)(n0 + arow) * K + c0 + akc);
    __syncthreads();
    bf16x8 af[2], bfr[4];
#pragma unroll
    for (int mt = 0; mt < 2; ++mt)
      af[mt] = *(const bf16x8*)&Al[(wv * 32 + mt * 16 + fm) * 40 + fq * 8];
#pragma unroll
    for (int nt = 0; nt < 4; ++nt)
      bfr[nt] = *(const bf16x8*)&Bl[(nt * 16 + fm) * 40 + fq * 8];
#pragma unroll
    for (int mt = 0; mt < 2; ++mt)
#pragma unroll
      for (int nt = 0; nt < 4; ++nt)
        acc[mt][nt] = __builtin_amdgcn_mfma_f32_16x16x32_bf16(af[mt], bfr[nt], acc[mt][nt], 0, 0, 0);
    __syncthreads();
  }
  const int bidx = m0 >> 12;
  if (EPI == 0) {
#pragma unroll
    for (int mt = 0; mt < 2; ++mt)
#pragma unroll
      for (int nt = 0; nt < 4; ++nt)
#pragma unroll
        for (int r = 0; r < 4; ++r)
          outf[(size_t)(m0 + wv * 32 + mt * 16 + fq * 4 + r) * ldof + n0 + nt * 16 + fm] =
              acc[mt][nt][r];
  } else if (EPI == 1) {
#pragma unroll
    for (int nt = 0; nt < 4; ++nt) {
      int col = n0 + nt * 16 + fm;
      float s = sc[col], bb = bi[col];
      float ex = extra ? extra[bidx * Ncols + col] : 0.f;
#pragma unroll
      for (int mt = 0; mt < 2; ++mt)
#pragma unroll
        for (int r = 0; r < 4; ++r) {
          float v = lrelu((acc[mt][nt][r] + ex) * s + bb);
          size_t rr = (size_t)(m0 + wv * 32 + mt * 16 + fq * 4 + r);
          if (outf) outf[rr * ldof + col] = v;
          if (outb) outb[rr * ldob + col] = __float2bfloat16(v);
        }
    }
  } else {
#pragma unroll
    for (int nt = 0; nt < 4; ++nt) {
      int col = n0 + nt * 16 + fm;
      float s = sc[col], bb = bi[col];
      float m = -INFINITY;
#pragma unroll
      for (int mt = 0; mt < 2; ++mt)
#pragma unroll
        for (int r = 0; r < 4; ++r) m = fmaxf(m, lrelu(acc[mt][nt][r] * s + bb));
      m = fmaxf(m, __shfl_xor(m, 16, 64));
      m = fmaxf(m, __shfl_xor(m, 32, 64));
      if (fq == 0) Red[wv][nt * 16 + fm] = m;
    }
    __syncthreads();
    if (tid < 64) {
      float m = fmaxf(fmaxf(Red[0][tid], Red[1][tid]), fmaxf(Red[2][tid], Red[3][tid]));
      atomicMax(&gmax[bidx * Ncols + n0 + tid], okey(m));
    }
  }
}

// ---------------- MFMA bf16 EdgeConv (layer 4): 320 edges x 64 cols / block ----------------
__global__ __launch_bounds__(256) void k_edgem(
    const __hip_bfloat16* __restrict__ F, int ldf, int coff, int K,
    const __hip_bfloat16* __restrict__ Wl,  // [N][K] bf16
    const float* __restrict__ sc, const float* __restrict__ bi,
    const float* __restrict__ T, int N,
    const int* __restrict__ idx,
    float* __restrict__ outf, __hip_bfloat16* __restrict__ outb) {
  __shared__ __align__(16) char smem[320 * 66 * 2];  // 42240 B, overlaid stage/Ys
  __hip_bfloat16* Al = (__hip_bfloat16*)smem;              // 320*40
  __hip_bfloat16* Bl = (__hip_bfloat16*)(smem + 25600);    // 64*40
  __hip_bfloat16* Ys = (__hip_bfloat16*)smem;              // 320*66 (post-loop)
  const int tid = threadIdx.x, lane = tid & 63, wv = tid >> 6;
  const int blk = blockIdx.x, n0 = blockIdx.y * 64;
  const int arow = tid >> 2, akc = (tid & 3) * 8;
  const int fm = lane & 15, fq = lane >> 4;
  const __hip_bfloat16* ap[5];
#pragma unroll
  for (int l = 0; l < 5; ++l) {
    int row = arow + l * 64;
    int e = blk * 320 + row;
    int p = e / 20;
    int j = idx[(size_t)p * 20 + (e - p * 20)];
    int src = ((p >> 12) << 12) + j;
    ap[l] = F + (size_t)src * ldf + coff + akc;
  }
  f32x4 acc[5][4];
#pragma unroll
  for (int l = 0; l < 5; ++l)
#pragma unroll
    for (int nt = 0; nt < 4; ++nt) acc[l][nt] = (f32x4){0.f, 0.f, 0.f, 0.f};
  for (int c0 = 0; c0 < K; c0 += 32) {
#pragma unroll
    for (int l = 0; l < 5; ++l)
      *(float4*)&Al[(arow + l * 64) * 40 + akc] = *(const float4*)(ap[l] + c0);
    *(float4*)&Bl[arow * 40 + akc] = *(const float4*)(Wl + (size_t)(n0 + arow) * K + c0 + akc);
    __syncthreads();
    bf16x8 af[5], bfr[4];
#pragma unroll
    for (int l = 0; l < 5; ++l)
      af[l] = *(const bf16x8*)&Al[(wv * 80 + l * 16 + fm) * 40 + fq * 8];
#pragma unroll
    for (int nt = 0; nt < 4; ++nt)
      bfr[nt] = *(const bf16x8*)&Bl[(nt * 16 + fm) * 40 + fq * 8];
#pragma unroll
    for (int l = 0; l < 5; ++l)
#pragma unroll
      for (int nt = 0; nt < 4; ++nt)
        acc[l][nt] = __builtin_amdgcn_mfma_f32_16x16x32_bf16(af[l], bfr[nt], acc[l][nt], 0, 0, 0);
    __syncthreads();
  }
#pragma unroll
  for (int l = 0; l < 5; ++l)
#pragma unroll
    for (int nt = 0; nt < 4; ++nt)
#pragma unroll
      for (int r = 0; r < 4; ++r)
        Ys[(wv * 80 + l * 16 + fq * 4 + r) * 66 + nt * 16 + fm] = __float2bfloat16(acc[l][nt][r]);
  __syncthreads();
  const int col = tid & 63;
#pragma unroll
  for (int gi = 0; gi < 4; ++gi) {
    int grp = wv + gi * 4;
    float m = -INFINITY;
#pragma unroll
    for (int k = 0; k < 20; ++k)
      m = fmaxf(m, __bfloat162float(Ys[(grp * 20 + k) * 66 + col]));
    int p = blk * 16 + grp;
    int o = n0 + col;
    float v = lrelu((m + T[(size_t)p * N + o]) * sc[o] + bi[o]);
    outf[(size_t)p * 512 + o] = v;
    outb[(size_t)p * 512 + o] = __float2bfloat16(v);
  }
}

// ---------------- bias2: one wave per (b,o) ----------------
__global__ __launch_bounds__(256) void k_bias2(const unsigned* __restrict__ gk,
                                               const float* __restrict__ Ws1,
                                               float* __restrict__ b2g) {
  const int lane = threadIdx.x & 63;
  const int wid = (blockIdx.x * 256 + threadIdx.x) >> 6;  // 0..1023
  const int b = wid >> 9, o = wid & 511;
  const float* wr = Ws1 + (size_t)o * 1536 + 512;
  const unsigned* g = gk + b * 1024;
  float acc = 0.f;
#pragma unroll
  for (int c = lane; c < 1024; c += 64) acc = fmaf(dekey(g[c]), wr[c], acc);
#pragma unroll
  for (int off = 32; off; off >>= 1) acc += __shfl_xor(acc, off, 64);
  if (lane == 0) b2g[b * 512 + o] = acc;
}

// ---------------- final head: out = H(8192x256) . Ws3^T + bs3 (fp32) ----------------
__global__ __launch_bounds__(256) void k_out(const float* __restrict__ H,
                                             const float* __restrict__ Ws3,
                                             const float* __restrict__ bs3,
                                             float* __restrict__ out) {
  __shared__ float Ws[13][256];
  const int tid = threadIdx.x;
  for (int e = tid; e < 13 * 256; e += 256) Ws[e >> 8][e & 255] = Ws3[e];
  __syncthreads();
  const int rloc = tid >> 4, o = tid & 15;
  const int row = blockIdx.x * 16 + rloc;
  if (o < 13) {
    const float* h = H + (size_t)row * 256;
    float acc = 0.f;
    for (int c = 0; c < 256; ++c) acc = fmaf(h[c], Ws[o][c], acc);
    out[(size_t)row * 13 + o] = acc + bs3[o];
  }
}

extern "C" void kernel_launch(void* const* d_in, const int* in_sizes, int n_in,
                              void* d_out, int out_size, void* d_ws, size_t ws_size,
                              hipStream_t stream) {
  const float* X   = (const float*)d_in[0];
  const float* W1  = (const float*)d_in[1];
  const float* S1  = (const float*)d_in[2];
  const float* B1  = (const float*)d_in[3];
  const float* W2  = (const float*)d_in[4];
  const float* S2  = (const float*)d_in[5];
  const float* B2  = (const float*)d_in[6];
  const float* W3  = (const float*)d_in[7];
  const float* S3  = (const float*)d_in[8];
  const float* B3  = (const float*)d_in[9];
  const float* W4  = (const float*)d_in[10];
  const float* S4  = (const float*)d_in[11];
  const float* B4  = (const float*)d_in[12];
  const float* Wg  = (const float*)d_in[13];
  const float* Sg  = (const float*)d_in[14];
  const float* Bg  = (const float*)d_in[15];
  const float* Ws1 = (const float*)d_in[16];
  const float* Ss1 = (const float*)d_in[17];
  const float* Bs1 = (const float*)d_in[18];
  const float* Ws2 = (const float*)d_in[19];
  const float* Ss2 = (const float*)d_in[20];
  const float* Bs2 = (const float*)d_in[21];
  const float* Ws3 = (const float*)d_in[22];
  const float* Bs3 = (const float*)d_in[23];

  char* ws = (char*)d_ws;
  float*           xxb   = (float*)(ws + 0);            // 32 KB
  int*             idxb  = (int*)(ws + 32768);          // 640 KB
  unsigned*        gk    = (unsigned*)(ws + 688128);    // 8 KB
  float*           b2g   = (float*)(ws + 696320);       // 4 KB
  __hip_bfloat16*  Wgb   = (__hip_bfloat16*)(ws + 1048576);  // 1 MB
  __hip_bfloat16*  Ws1b  = (__hip_bfloat16*)(ws + 2097152);  // 512 KB
  __hip_bfloat16*  Ws2b  = (__hip_bfloat16*)(ws + 2621440);  // 256 KB
  __hip_bfloat16*  Wlb4  = (__hip_bfloat16*)(ws + 2883584);  // 64 KB
  __hip_bfloat16*  Wdb4  = (__hip_bfloat16*)(ws + 2949120);  // 64 KB
  __hip_bfloat16*  xcatb = (__hip_bfloat16*)(ws + 3145728);  // 8 MB
  float*           xcat  = (float*)(ws + 11534336);          // 16 MB
  char*            region = ws + 28311552;                   // dist / Tbuf+h1b
  unsigned*        dist  = (unsigned*)(region);
  float*           Tbuf  = (float*)(region);
  __hip_bfloat16*  h1b   = (__hip_bfloat16*)(region + 8388608);

  // Full-batch dist (64 MB) if workspace allows; else 1024-row chunking.
  const bool big = (ws_size >= (size_t)28311552 + (64u << 20));

  hipMemsetAsync(gk, 0, 2 * 1024 * sizeof(unsigned), stream);

  // weight bf16 packs (L4 + head only; L1-L3 weights stay fp32)
  k_conv<<<dim3(256, 2), dim3(64), 0, stream>>>(W4, 256, 0, 0, 128, Wlb4);
  k_conv<<<dim3(256, 2), dim3(64), 0, stream>>>(W4, 256, 128, 1, 128, Wdb4);
  k_conv<<<dim3(1024, 8), dim3(64), 0, stream>>>(Wg, 512, 0, 0, 512, Wgb);
  k_conv<<<dim3(512, 8), dim3(64), 0, stream>>>(Ws1, 1536, 0, 0, 512, Ws1b);
  k_conv<<<dim3(256, 8), dim3(64), 0, stream>>>(Ws2, 512, 0, 0, 512, Ws2b);

  // kNN for one layer (fills idxb); selection bit-identical in both paths
  auto run_knn = [&](const float* F, int ldf, int C) {
    k_xx<<<dim3(2048), dim3(256), 0, stream>>>(F, ldf, C, xxb);
    if (big) {
      for (int b = 0; b < 2; ++b) {
        k_dist<<<dim3(32, 64), dim3(256), 0, stream>>>(F, ldf, C, xxb, dist, b, 0);
        k_topk<<<dim3(4096), dim3(256), 0, stream>>>(dist, idxb, b, 0);
      }
    } else {
      for (int b = 0; b < 2; ++b)
        for (int c = 0; c < 4; ++c) {
          k_dist<<<dim3(8, 64), dim3(256), 0, stream>>>(F, ldf, C, xxb, dist, b, c * 1024);
          k_topk<<<dim3(1024), dim3(256), 0, stream>>>(dist, idxb, b, c * 1024);
        }
    }
  };

  // ---- Layer 1 (C=3 -> 64, fp32 exact) ----
  run_knn(X, 3, 3);
  k_edge1<<<dim3(2048), dim3(256), 0, stream>>>(X, W1, S1, B1, idxb, xcat, xcatb);

  // ---- Layer 2 (64 -> 64), fp32 (feeds kNN — must stay exact, R9 proved it) ----
  run_knn(xcat, 512, 64);
  k_pwT<<<dim3(128, 1), dim3(256), 0, stream>>>(xcat, 512, 64, W2, 128, 64, Tbuf, 64);
  k_edge<<<dim3(2048, 1), dim3(256), 0, stream>>>(xcat, 512, 64, W2, S2, B2,
      idxb, Tbuf, 64, xcat + 64, xcatb + 64);

  // ---- Layer 3 (64 -> 128), fp32 (feeds kNN) ----
  run_knn(xcat + 64, 512, 64);
  k_pwT<<<dim3(128, 2), dim3(256), 0, stream>>>(xcat + 64, 512, 64, W3, 128, 64, Tbuf, 128);
  k_edge<<<dim3(2048, 2), dim3(256), 0, stream>>>(xcat + 64, 512, 64, W3, S3, B3,
      idxb, Tbuf, 128, xcat + 128, xcatb + 128);

  // ---- Layer 4 (128 -> 256), bf16 MFMA (x4 feeds nothing discrete) ----
  run_knn(xcat + 128, 512, 128);
  k_mm<0><<<dim3(64, 4), dim3(256), 0, stream>>>(xcatb + 128, 512, 128, Wdb4,
      nullptr, nullptr, nullptr, 256, Tbuf, 256, nullptr, 0, nullptr);
  k_edgem<<<dim3(512, 4), dim3(256), 0, stream>>>(xcatb, 512, 128, 128, Wlb4,
      S4, B4, Tbuf, 256, idxb, xcat + 256, xcatb + 256);

  // ---- head (all bf16 MFMA) ----
  k_mm<2><<<dim3(64, 16), dim3(256), 0, stream>>>(xcatb, 512, 512, Wgb,
      Sg, Bg, nullptr, 1024, nullptr, 0, nullptr, 0, gk);
  k_bias2<<<dim3(256), dim3(256), 0, stream>>>(gk, Ws1, b2g);
  k_mm<1><<<dim3(64, 8), dim3(256), 0, stream>>>(xcatb, 512, 512, Ws1b,
      Ss1, Bs1, b2g, 512, nullptr, 0, h1b, 512, nullptr);
  k_mm<1><<<dim3(64, 4), dim3(256), 0, stream>>>(h1b, 512, 512, Ws2b,
      Ss2, Bs2, nullptr, 256, Tbuf, 256, nullptr, 0, nullptr);
  k_out<<<dim3(512), dim3(256), 0, stream>>>(Tbuf, Ws3, Bs3, (float*)d_out);
}

// Round 14
// 986.235 us; speedup vs baseline: 1.0879x; 1.0123x over previous
//
#include <hip/hip_runtime.h>
#include <hip/hip_bf16.h>

// DGCNN_Seg forward. B=2, N=4096, K=20. fp32 in/out.
// Round 14: k_dist v3 — 128x128 tile (8x8/thread, 2x FMA per LDS read),
// batch-z merged kNN dispatches (1 dist + 1 topk per layer when ws allows
// 128MB). Distances/selection bit-identical. Rest = R13 (998us).

#define DEVI static __device__ __forceinline__
typedef __attribute__((ext_vector_type(8))) short bf16x8;   // 8 bf16 = 4 VGPR
typedef __attribute__((ext_vector_type(4))) float f32x4;    // MFMA acc
typedef unsigned long long ull;

DEVI float lrelu(float y) { return y > 0.f ? y : 0.2f * y; }
DEVI unsigned okey(float f) {
  unsigned u = __float_as_uint(f);
  return (f < 0.f) ? ~u : (u | 0x80000000u);
}
DEVI float dekey(unsigned k) {
  return __uint_as_float((k & 0x80000000u) ? (k & 0x7fffffffu) : ~k);
}

// ---------------- weight fp32 -> bf16 pack ----------------
__global__ __launch_bounds__(64) void k_conv(const float* __restrict__ src, int lds, int off,
                                             int sub, int Kc, __hip_bfloat16* __restrict__ dst) {
  int o = blockIdx.x, c = blockIdx.y * 64 + threadIdx.x;
  float v = src[(size_t)o * lds + off + c];
  if (sub) v -= src[(size_t)o * lds + c];
  dst[(size_t)o * Kc + c] = __float2bfloat16(v);
}

// ---------------- row squared-norms: one wave per row ----------------
__global__ __launch_bounds__(256) void k_xx(const float* __restrict__ F, int ldf, int C,
                                            float* __restrict__ xx) {
  int lane = threadIdx.x & 63;
  int row = blockIdx.x * 4 + (threadIdx.x >> 6);
  const float* f = F + (size_t)row * ldf;
  float s = 0.f;
  for (int c = lane; c < C; c += 64) { float v = f[c]; s += v * v; }
#pragma unroll
  for (int off = 32; off; off >>= 1) s += __shfl_xor(s, off, 64);
  if (lane == 0) xx[row] = s;
}

// ---------------- pairwise distances v3: 128x128 tile, 8x8 per thread ----------------
// Stores okey(d) u32. Per-element fmaf order identical to v1/v2 (c-chunks of 16
// ascending, kk ascending) -> selection bit-identical.
// bfix < 0: batch from blockIdx.z, D offset b*4096*4096.
__global__ __launch_bounds__(256) void k_dist(const float* __restrict__ F, int ldf, int C,
                                              const float* __restrict__ xx,
                                              unsigned* __restrict__ D, int bfix, int ibase) {
  __shared__ __align__(16) float As[16][132];
  __shared__ __align__(16) float Bs[16][132];
  const int tid = threadIdx.x;
  const int tx = tid & 15, ty = tid >> 4;
  const int b = (bfix < 0) ? (int)blockIdx.z : bfix;
  unsigned* Db = (bfix < 0) ? (D + (size_t)b * 4096 * 4096) : D;
  const int i0 = ibase + blockIdx.x * 128, j0 = blockIdx.y * 128;
  const float* Fb = F + (size_t)b * 4096 * ldf;
  const float* xxb = xx + b * 4096;
  const int srow = tid >> 1, sq = (tid & 1) * 8;  // stage: 128 rows x 16 cols
  float acc[8][8] = {};
  for (int c0 = 0; c0 < C; c0 += 16) {
    if (C - c0 >= 16) {
      float4 a0 = *(const float4*)(Fb + (size_t)(i0 + srow) * ldf + c0 + sq);
      float4 a1 = *(const float4*)(Fb + (size_t)(i0 + srow) * ldf + c0 + sq + 4);
      As[sq + 0][srow] = a0.x; As[sq + 1][srow] = a0.y; As[sq + 2][srow] = a0.z; As[sq + 3][srow] = a0.w;
      As[sq + 4][srow] = a1.x; As[sq + 5][srow] = a1.y; As[sq + 6][srow] = a1.z; As[sq + 7][srow] = a1.w;
      float4 b0 = *(const float4*)(Fb + (size_t)(j0 + srow) * ldf + c0 + sq);
      float4 b1 = *(const float4*)(Fb + (size_t)(j0 + srow) * ldf + c0 + sq + 4);
      Bs[sq + 0][srow] = b0.x; Bs[sq + 1][srow] = b0.y; Bs[sq + 2][srow] = b0.z; Bs[sq + 3][srow] = b0.w;
      Bs[sq + 4][srow] = b1.x; Bs[sq + 5][srow] = b1.y; Bs[sq + 6][srow] = b1.z; Bs[sq + 7][srow] = b1.w;
    } else {
#pragma unroll
      for (int e = 0; e < 8; ++e) {
        int c = c0 + sq + e;
        As[sq + e][srow] = (c < C) ? Fb[(size_t)(i0 + srow) * ldf + c] : 0.f;
        Bs[sq + e][srow] = (c < C) ? Fb[(size_t)(j0 + srow) * ldf + c] : 0.f;
      }
    }
    __syncthreads();
#pragma unroll
    for (int kk = 0; kk < 16; ++kk) {
      const float4 al = *(const float4*)&As[kk][ty * 8];
      const float4 ah = *(const float4*)&As[kk][ty * 8 + 4];
      const float4 bl = *(const float4*)&Bs[kk][tx * 8];
      const float4 bh = *(const float4*)&Bs[kk][tx * 8 + 4];
      const float av[8] = {al.x, al.y, al.z, al.w, ah.x, ah.y, ah.z, ah.w};
      const float bv[8] = {bl.x, bl.y, bl.z, bl.w, bh.x, bh.y, bh.z, bh.w};
#pragma unroll
      for (int ii = 0; ii < 8; ++ii)
#pragma unroll
        for (int jj = 0; jj < 8; ++jj)
          acc[ii][jj] = fmaf(av[ii], bv[jj], acc[ii][jj]);
    }
    __syncthreads();
  }
#pragma unroll
  for (int ii = 0; ii < 8; ++ii) {
    int i = i0 + ty * 8 + ii;
    float xi = xxb[i];
    uint4 o1, o2;
    o1.x = okey(xi + xxb[j0 + tx * 8 + 0] - 2.f * acc[ii][0]);
    o1.y = okey(xi + xxb[j0 + tx * 8 + 1] - 2.f * acc[ii][1]);
    o1.z = okey(xi + xxb[j0 + tx * 8 + 2] - 2.f * acc[ii][2]);
    o1.w = okey(xi + xxb[j0 + tx * 8 + 3] - 2.f * acc[ii][3]);
    o2.x = okey(xi + xxb[j0 + tx * 8 + 4] - 2.f * acc[ii][4]);
    o2.y = okey(xi + xxb[j0 + tx * 8 + 5] - 2.f * acc[ii][5]);
    o2.z = okey(xi + xxb[j0 + tx * 8 + 6] - 2.f * acc[ii][6]);
    o2.w = okey(xi + xxb[j0 + tx * 8 + 7] - 2.f * acc[ii][7]);
    *(uint4*)&Db[(size_t)(i - ibase) * 4096 + j0 + tx * 8] = o1;
    *(uint4*)&Db[(size_t)(i - ibase) * 4096 + j0 + tx * 8 + 4] = o2;
  }
}

// ---------------- top-20 v5: 1 block (4 waves) per row ----------------
// bfix < 0: batch from blockIdx.y, Dk offset b*4096*4096.
__global__ __launch_bounds__(256) void k_topk(const unsigned* __restrict__ Dk,
                                              int* __restrict__ idx, int bfix, int ibase) {
  __shared__ ull cand[4][20];
  const int tid = threadIdx.x, lane = tid & 63, wv = tid >> 6;
  const int ir_ = blockIdx.x;
  const int b = (bfix < 0) ? (int)blockIdx.y : bfix;
  const unsigned* drow = Dk + ((bfix < 0) ? (size_t)b * 4096 * 4096 : 0) + (size_t)ir_ * 4096;
  const int base = wv * 1024 + lane;
  unsigned key[16];
#pragma unroll
  for (int it = 0; it < 16; ++it) key[it] = drow[base + it * 64];
  unsigned m1k = 0xFFFFFFFFu, m2k = 0xFFFFFFFFu, m3k = 0xFFFFFFFFu;
  int m1p = 0, m2p = 0, m3p = 0;
#pragma unroll
  for (int it = 0; it < 16; ++it) {
    unsigned v = key[it];
    bool b1 = v < m1k, b2 = v < m2k, b3 = v < m3k;
    m3k = b2 ? m2k : (b3 ? v : m3k);
    m3p = b2 ? m2p : (b3 ? it : m3p);
    m2k = b1 ? m1k : (b2 ? v : m2k);
    m2p = b1 ? m1p : (b2 ? it : m2p);
    m1k = b1 ? v : m1k;
    m1p = b1 ? it : m1p;
  }
  unsigned consumed = (1u << m1p) | (1u << m2p) | (1u << m3p);
  unsigned ck = m1k, cp = (unsigned)(lane | (m1p << 6));
  unsigned n1k = m2k, n1p = (unsigned)(lane | (m2p << 6));
  unsigned n2k = m3k, n2p = (unsigned)(lane | (m3p << 6));
  for (int r = 0; r < 20; ++r) {
    unsigned mh = ck;
#pragma unroll
    for (int off = 32; off; off >>= 1) {
      unsigned o = __shfl_xor(mh, off, 64);
      mh = o < mh ? o : mh;
    }
    unsigned lo2 = (ck == mh) ? cp : 0xFFFFFFFFu;
    unsigned ml = lo2;
#pragma unroll
    for (int off = 32; off; off >>= 1) {
      unsigned o = __shfl_xor(ml, off, 64);
      ml = o < ml ? o : ml;
    }
    if (lane == 0) cand[wv][r] = ((ull)mh << 32) | (unsigned)(wv * 1024 + ml);
    bool pop = (ck == mh) && (cp == ml);
    ck = pop ? n1k : ck;  cp = pop ? n1p : cp;
    n1k = pop ? n2k : n1k; n1p = pop ? n2p : n1p;
    n2k = pop ? 0xFFFFFFFFu : n2k;
    if (ck == 0xFFFFFFFFu) {  // rare: lane popped >=3 times; refill from regs
      unsigned bk = 0xFFFFFFFFu; int bp = 0;
#pragma unroll
      for (int it2 = 0; it2 < 16; ++it2) {
        bool ok = ((consumed >> it2) & 1u) == 0u;
        unsigned v = ok ? key[it2] : 0xFFFFFFFFu;
        bool t = v < bk;
        bk = t ? v : bk;
        bp = t ? it2 : bp;
      }
      consumed |= (1u << bp);
      ck = bk;
      cp = (unsigned)(lane | (bp << 6));
    }
  }
  __syncthreads();
  if (tid == 0) {
    int* op = idx + ((size_t)b * 4096 + ibase + ir_) * 20;
    int p0 = 0, p1 = 0, p2 = 0, p3 = 0;
    for (int r = 0; r < 20; ++r) {
      ull v0 = cand[0][p0], v1 = cand[1][p1], v2 = cand[2][p2], v3 = cand[3][p3];
      ull m01 = v0 < v1 ? v0 : v1;
      ull m23 = v2 < v3 ? v2 : v3;
      ull best = m01 < m23 ? m01 : m23;
      if (best == v0) ++p0; else if (best == v1) ++p1;
      else if (best == v2) ++p2; else ++p3;
      op[r] = (int)(best & 0xfffull);
      if (p0 > 19) p0 = 19;
      if (p1 > 19) p1 = 19;
      if (p2 > 19) p2 = 19;
      if (p3 > 19) p3 = 19;
    }
  }
}

// ---------------- EdgeConv layer 1 (fp32, Cin=3): one wave per point ----------------
__global__ __launch_bounds__(256) void k_edge1(const float* __restrict__ xf,
                                               const float* __restrict__ W1,
                                               const float* __restrict__ s1,
                                               const float* __restrict__ b1,
                                               const int* __restrict__ idx,
                                               float* __restrict__ xcat,
                                               __hip_bfloat16* __restrict__ xcatb) {
  const int lane = threadIdx.x & 63;
  const int p = blockIdx.x * 4 + (threadIdx.x >> 6);
  const int bb = p >> 12;
  float wl[3], wr[3];
#pragma unroll
  for (int c = 0; c < 3; ++c) {
    wl[c] = W1[lane * 6 + c];
    wr[c] = W1[lane * 6 + 3 + c];
  }
  const float s = s1[lane], bi = b1[lane];
  const float* xc = xf + (size_t)p * 3;
  const float x0 = xc[0], x1 = xc[1], x2 = xc[2];
  const float t = x0 * (wr[0] - wl[0]) + x1 * (wr[1] - wl[1]) + x2 * (wr[2] - wl[2]);
  const int* ir = idx + (size_t)p * 20;
  float best = -INFINITY;
  for (int k = 0; k < 20; ++k) {
    int j = ir[k];
    const float* xn = xf + ((size_t)(bb << 12) + j) * 3;
    float y = t + xn[0] * wl[0] + xn[1] * wl[1] + xn[2] * wl[2];
    y = lrelu(y * s + bi);
    best = fmaxf(best, y);
  }
  xcat[(size_t)p * 512 + lane] = best;
  xcatb[(size_t)p * 512 + lane] = __float2bfloat16(best);
}

// ---------------- fp32 pointwise GEMM, raw store (T for layers 2-3) ----------------
__global__ __launch_bounds__(256) void k_pwT(const float* __restrict__ A, int lda, int K,
                                             const float* __restrict__ W, int ldw, int wsub,
                                             float* __restrict__ out, int ldo) {
  __shared__ __align__(16) float As[16][68];
  __shared__ __align__(16) float Bs[16][68];
  const int tid = threadIdx.x;
  const int tx = tid & 15, ty = tid >> 4;
  const int i0 = blockIdx.x * 64, o0 = blockIdx.y * 64;
  const int row = tid >> 2, q = (tid & 3) * 4;
  float acc[4][4] = {};
  for (int c0 = 0; c0 < K; c0 += 16) {
    float4 a = *(const float4*)(A + (size_t)(i0 + row) * lda + c0 + q);
    As[q + 0][row] = a.x; As[q + 1][row] = a.y; As[q + 2][row] = a.z; As[q + 3][row] = a.w;
    const float* wp = W + (size_t)(o0 + row) * ldw + c0 + q;
#pragma unroll
    for (int e = 0; e < 4; ++e) Bs[q + e][row] = wp[wsub + e] - wp[e];
    __syncthreads();
#pragma unroll
    for (int kk = 0; kk < 16; ++kk) {
      const float4 a4 = *(const float4*)&As[kk][ty * 4];
      const float4 b4 = *(const float4*)&Bs[kk][tx * 4];
      const float av[4] = {a4.x, a4.y, a4.z, a4.w};
      const float bv[4] = {b4.x, b4.y, b4.z, b4.w};
#pragma unroll
      for (int ii = 0; ii < 4; ++ii)
#pragma unroll
        for (int jj = 0; jj < 4; ++jj)
          acc[ii][jj] = fmaf(av[ii], bv[jj], acc[ii][jj]);
    }
    __syncthreads();
  }
#pragma unroll
  for (int ii = 0; ii < 4; ++ii)
#pragma unroll
    for (int jj = 0; jj < 4; ++jj)
      out[(size_t)(i0 + ty * 4 + ii) * ldo + o0 + tx * 4 + jj] = acc[ii][jj];
}

// ---------------- fp32 EdgeConv GEMM (layers 2-3; feeds kNN, stays exact) ----------------
__global__ __launch_bounds__(256) void k_edge(const float* __restrict__ F, int ldf, int Cin,
                                              const float* __restrict__ W,
                                              const float* __restrict__ sc,
                                              const float* __restrict__ bi,
                                              const int* __restrict__ idx,
                                              const float* __restrict__ T, int ldt,
                                              float* __restrict__ out,
                                              __hip_bfloat16* __restrict__ outb) {
  __shared__ float As[16][81];
  __shared__ __align__(16) float Bs[16][68];
  __shared__ float Ys[80][65];
  const int tid = threadIdx.x;
  const int tx = tid & 15, ty = tid >> 4;
  const int r0 = blockIdx.x * 80;
  const int o0 = blockIdx.y * 64;
  const int ldw = 2 * Cin;
  int grow[5], gcol[5];
#pragma unroll
  for (int l = 0; l < 5; ++l) {
    int e = tid + l * 256;
    int rr = e >> 4;
    gcol[l] = e & 15;
    int gr = r0 + rr;
    int p = gr / 20;
    int j = idx[(size_t)p * 20 + (gr % 20)];
    grow[l] = ((p >> 12) << 12) + j;
  }
  float acc[5][4] = {};
  const int wrow = tid >> 2, wq = (tid & 3) * 4;
  for (int c0 = 0; c0 < Cin; c0 += 16) {
#pragma unroll
    for (int l = 0; l < 5; ++l) {
      int e = tid + l * 256;
      As[gcol[l]][e >> 4] = F[(size_t)grow[l] * ldf + c0 + gcol[l]];
    }
    {
      const float* wp = W + (size_t)(o0 + wrow) * ldw + c0 + wq;
#pragma unroll
      for (int e = 0; e < 4; ++e) Bs[wq + e][wrow] = wp[e];
    }
    __syncthreads();
#pragma unroll
    for (int kk = 0; kk < 16; ++kk) {
      float a[5];
#pragma unroll
      for (int l = 0; l < 5; ++l) a[l] = As[kk][ty + l * 16];
      const float4 b4 = *(const float4*)&Bs[kk][tx * 4];
      const float bv[4] = {b4.x, b4.y, b4.z, b4.w};
#pragma unroll
      for (int l = 0; l < 5; ++l)
#pragma unroll
        for (int jj = 0; jj < 4; ++jj)
          acc[l][jj] = fmaf(a[l], bv[jj], acc[l][jj]);
    }
    __syncthreads();
  }
#pragma unroll
  for (int l = 0; l < 5; ++l) {
    int r = ty + l * 16;
    int p = (r0 + r) / 20;
#pragma unroll
    for (int jj = 0; jj < 4; ++jj) {
      int o = o0 + tx * 4 + jj;
      float y = (acc[l][jj] + T[(size_t)p * ldt + o]) * sc[o] + bi[o];
      Ys[r][tx * 4 + jj] = lrelu(y);
    }
  }
  __syncthreads();
  const int grp = tid >> 6, col = tid & 63;
  float m = -INFINITY;
#pragma unroll
  for (int k = 0; k < 20; ++k) m = fmaxf(m, Ys[grp * 20 + k][col]);
  const int p = blockIdx.x * 4 + grp;
  out[(size_t)p * 512 + o0 + col] = m;
  outb[(size_t)p * 512 + o0 + col] = __float2bfloat16(m);
}

// ---------------- MFMA bf16 GEMM: block 128(M)x64(N), 4 waves x (32x64) ----------------
template <int EPI>
__global__ __launch_bounds__(256) void k_mm(
    const __hip_bfloat16* __restrict__ A, int lda, int K,
    const __hip_bfloat16* __restrict__ B,  // [N][K] bf16
    const float* __restrict__ sc, const float* __restrict__ bi,
    const float* __restrict__ extra, int Ncols,
    float* __restrict__ outf, int ldof,
    __hip_bfloat16* __restrict__ outb, int ldob,
    unsigned* __restrict__ gmax) {
  __shared__ __align__(16) __hip_bfloat16 Al[128 * 40];
  __shared__ __align__(16) __hip_bfloat16 Bl[64 * 40];
  __shared__ float Red[4][64];
  const int tid = threadIdx.x, lane = tid & 63, wv = tid >> 6;
  const int m0 = blockIdx.x * 128, n0 = blockIdx.y * 64;
  const int arow = tid >> 2, akc = (tid & 3) * 8;
  const int fm = lane & 15, fq = lane >> 4;
  f32x4 acc[2][4];
#pragma unroll
  for (int mt = 0; mt < 2; ++mt)
#pragma unroll
    for (int nt = 0; nt < 4; ++nt) acc[mt][nt] = (f32x4){0.f, 0.f, 0.f, 0.f};
  for (int c0 = 0; c0 < K; c0 += 32) {
#pragma unroll
    for (int l = 0; l < 2; ++l) {
      int r = arow + l * 64;
      *(float4*)&Al[r * 40 + akc] = *(const float4*)(A + (size_t)(m0 + r) * lda + c0 + akc);
    }
    *(float4*)&Bl[arow * 40 + akc] = *(const float4*)(B + (size_t)(n0 + arow) * K + c0 + akc);
    __syncthreads();
    bf16x8 af[2], bfr[4];
#pragma unroll
    for (int mt = 0; mt < 2; ++mt)
      af[mt] = *(const bf16x8*)&Al[(wv * 32 + mt * 16 + fm) * 40 + fq * 8];
#pragma unroll
    for (int nt = 0; nt < 4; ++nt)
      bfr[nt] = *(const bf16x8*)&Bl[(nt * 16 + fm) * 40 + fq * 8];
#pragma unroll
    for (int mt = 0; mt < 2; ++mt)
#pragma unroll
      for (int nt = 0; nt < 4; ++nt)
        acc[mt][nt] = __builtin_amdgcn_mfma_f32_16x16x32_bf16(af[mt], bfr[nt], acc[mt][nt], 0, 0, 0);
    __syncthreads();
  }
  const int bidx = m0 >> 12;
  if (EPI == 0) {
#pragma unroll
    for (int mt = 0; mt < 2; ++mt)
#pragma unroll
      for (int nt = 0; nt < 4; ++nt)
#pragma unroll
        for (int r = 0; r < 4; ++r)
          outf[(size_t)(m0 + wv * 32 + mt * 16 + fq * 4 + r) * ldof + n0 + nt * 16 + fm] =
              acc[mt][nt][r];
  } else if (EPI == 1) {
#pragma unroll
    for (int nt = 0; nt < 4; ++nt) {
      int col = n0 + nt * 16 + fm;
      float s = sc[col], bb = bi[col];
      float ex = extra ? extra[bidx * Ncols + col] : 0.f;
#pragma unroll
      for (int mt = 0; mt < 2; ++mt)
#pragma unroll
        for (int r = 0; r < 4; ++r) {
          float v = lrelu((acc[mt][nt][r] + ex) * s + bb);
          size_t rr = (size_t)(m0 + wv * 32 + mt * 16 + fq * 4 + r);
          if (outf) outf[rr * ldof + col] = v;
          if (outb) outb[rr * ldob + col] = __float2bfloat16(v);
        }
    }
  } else {
#pragma unroll
    for (int nt = 0; nt < 4; ++nt) {
      int col = n0 + nt * 16 + fm;
      float s = sc[col], bb = bi[col];
      float m = -INFINITY;
#pragma unroll
      for (int mt = 0; mt < 2; ++mt)
#pragma unroll
        for (int r = 0; r < 4; ++r) m = fmaxf(m, lrelu(acc[mt][nt][r] * s + bb));
      m = fmaxf(m, __shfl_xor(m, 16, 64));
      m = fmaxf(m, __shfl_xor(m, 32, 64));
      if (fq == 0) Red[wv][nt * 16 + fm] = m;
    }
    __syncthreads();
    if (tid < 64) {
      float m = fmaxf(fmaxf(Red[0][tid], Red[1][tid]), fmaxf(Red[2][tid], Red[3][tid]));
      atomicMax(&gmax[bidx * Ncols + n0 + tid], okey(m));
    }
  }
}

// ---------------- MFMA bf16 EdgeConv (layer 4): 320 edges x 64 cols / block ----------------
__global__ __launch_bounds__(256) void k_edgem(
    const __hip_bfloat16* __restrict__ F, int ldf, int coff, int K,
    const __hip_bfloat16* __restrict__ Wl,  // [N][K] bf16
    const float* __restrict__ sc, const float* __restrict__ bi,
    const float* __restrict__ T, int N,
    const int* __restrict__ idx,
    float* __restrict__ outf, __hip_bfloat16* __restrict__ outb) {
  __shared__ __align__(16) char smem[320 * 66 * 2];  // 42240 B, overlaid stage/Ys
  __hip_bfloat16* Al = (__hip_bfloat16*)smem;              // 320*40
  __hip_bfloat16* Bl = (__hip_bfloat16*)(smem + 25600);    // 64*40
  __hip_bfloat16* Ys = (__hip_bfloat16*)smem;              // 320*66 (post-loop)
  const int tid = threadIdx.x, lane = tid & 63, wv = tid >> 6;
  const int blk = blockIdx.x, n0 = blockIdx.y * 64;
  const int arow = tid >> 2, akc = (tid & 3) * 8;
  const int fm = lane & 15, fq = lane >> 4;
  const __hip_bfloat16* ap[5];
#pragma unroll
  for (int l = 0; l < 5; ++l) {
    int row = arow + l * 64;
    int e = blk * 320 + row;
    int p = e / 20;
    int j = idx[(size_t)p * 20 + (e - p * 20)];
    int src = ((p >> 12) << 12) + j;
    ap[l] = F + (size_t)src * ldf + coff + akc;
  }
  f32x4 acc[5][4];
#pragma unroll
  for (int l = 0; l < 5; ++l)
#pragma unroll
    for (int nt = 0; nt < 4; ++nt) acc[l][nt] = (f32x4){0.f, 0.f, 0.f, 0.f};
  for (int c0 = 0; c0 < K; c0 += 32) {
#pragma unroll
    for (int l = 0; l < 5; ++l)
      *(float4*)&Al[(arow + l * 64) * 40 + akc] = *(const float4*)(ap[l] + c0);
    *(float4*)&Bl[arow * 40 + akc] = *(const float4*)(Wl + (size_t)(n0 + arow) * K + c0 + akc);
    __syncthreads();
    bf16x8 af[5], bfr[4];
#pragma unroll
    for (int l = 0; l < 5; ++l)
      af[l] = *(const bf16x8*)&Al[(wv * 80 + l * 16 + fm) * 40 + fq * 8];
#pragma unroll
    for (int nt = 0; nt < 4; ++nt)
      bfr[nt] = *(const bf16x8*)&Bl[(nt * 16 + fm) * 40 + fq * 8];
#pragma unroll
    for (int l = 0; l < 5; ++l)
#pragma unroll
      for (int nt = 0; nt < 4; ++nt)
        acc[l][nt] = __builtin_amdgcn_mfma_f32_16x16x32_bf16(af[l], bfr[nt], acc[l][nt], 0, 0, 0);
    __syncthreads();
  }
#pragma unroll
  for (int l = 0; l < 5; ++l)
#pragma unroll
    for (int nt = 0; nt < 4; ++nt)
#pragma unroll
      for (int r = 0; r < 4; ++r)
        Ys[(wv * 80 + l * 16 + fq * 4 + r) * 66 + nt * 16 + fm] = __float2bfloat16(acc[l][nt][r]);
  __syncthreads();
  const int col = tid & 63;
#pragma unroll
  for (int gi = 0; gi < 4; ++gi) {
    int grp = wv + gi * 4;
    float m = -INFINITY;
#pragma unroll
    for (int k = 0; k < 20; ++k)
      m = fmaxf(m, __bfloat162float(Ys[(grp * 20 + k) * 66 + col]));
    int p = blk * 16 + grp;
    int o = n0 + col;
    float v = lrelu((m + T[(size_t)p * N + o]) * sc[o] + bi[o]);
    outf[(size_t)p * 512 + o] = v;
    outb[(size_t)p * 512 + o] = __float2bfloat16(v);
  }
}

// ---------------- bias2: one wave per (b,o) ----------------
__global__ __launch_bounds__(256) void k_bias2(const unsigned* __restrict__ gk,
                                               const float* __restrict__ Ws1,
                                               float* __restrict__ b2g) {
  const int lane = threadIdx.x & 63;
  const int wid = (blockIdx.x * 256 + threadIdx.x) >> 6;  // 0..1023
  const int b = wid >> 9, o = wid & 511;
  const float* wr = Ws1 + (size_t)o * 1536 + 512;
  const unsigned* g = gk + b * 1024;
  float acc = 0.f;
#pragma unroll
  for (int c = lane; c < 1024; c += 64) acc = fmaf(dekey(g[c]), wr[c], acc);
#pragma unroll
  for (int off = 32; off; off >>= 1) acc += __shfl_xor(acc, off, 64);
  if (lane == 0) b2g[b * 512 + o] = acc;
}

// ---------------- final head: out = H(8192x256) . Ws3^T + bs3 (fp32) ----------------
__global__ __launch_bounds__(256) void k_out(const float* __restrict__ H,
                                             const float* __restrict__ Ws3,
                                             const float* __restrict__ bs3,
                                             float* __restrict__ out) {
  __shared__ float Ws[13][256];
  const int tid = threadIdx.x;
  for (int e = tid; e < 13 * 256; e += 256) Ws[e >> 8][e & 255] = Ws3[e];
  __syncthreads();
  const int rloc = tid >> 4, o = tid & 15;
  const int row = blockIdx.x * 16 + rloc;
  if (o < 13) {
    const float* h = H + (size_t)row * 256;
    float acc = 0.f;
    for (int c = 0; c < 256; ++c) acc = fmaf(h[c], Ws[o][c], acc);
    out[(size_t)row * 13 + o] = acc + bs3[o];
  }
}

extern "C" void kernel_launch(void* const* d_in, const int* in_sizes, int n_in,
                              void* d_out, int out_size, void* d_ws, size_t ws_size,
                              hipStream_t stream) {
  const float* X   = (const float*)d_in[0];
  const float* W1  = (const float*)d_in[1];
  const float* S1  = (const float*)d_in[2];
  const float* B1  = (const float*)d_in[3];
  const float* W2  = (const float*)d_in[4];
  const float* S2  = (const float*)d_in[5];
  const float* B2  = (const float*)d_in[6];
  const float* W3  = (const float*)d_in[7];
  const float* S3  = (const float*)d_in[8];
  const float* B3  = (const float*)d_in[9];
  const float* W4  = (const float*)d_in[10];
  const float* S4  = (const float*)d_in[11];
  const float* B4  = (const float*)d_in[12];
  const float* Wg  = (const float*)d_in[13];
  const float* Sg  = (const float*)d_in[14];
  const float* Bg  = (const float*)d_in[15];
  const float* Ws1 = (const float*)d_in[16];
  const float* Ss1 = (const float*)d_in[17];
  const float* Bs1 = (const float*)d_in[18];
  const float* Ws2 = (const float*)d_in[19];
  const float* Ss2 = (const float*)d_in[20];
  const float* Bs2 = (const float*)d_in[21];
  const float* Ws3 = (const float*)d_in[22];
  const float* Bs3 = (const float*)d_in[23];

  char* ws = (char*)d_ws;
  float*           xxb   = (float*)(ws + 0);            // 32 KB
  int*             idxb  = (int*)(ws + 32768);          // 640 KB
  unsigned*        gk    = (unsigned*)(ws + 688128);    // 8 KB
  float*           b2g   = (float*)(ws + 696320);       // 4 KB
  __hip_bfloat16*  Wgb   = (__hip_bfloat16*)(ws + 1048576);  // 1 MB
  __hip_bfloat16*  Ws1b  = (__hip_bfloat16*)(ws + 2097152);  // 512 KB
  __hip_bfloat16*  Ws2b  = (__hip_bfloat16*)(ws + 2621440);  // 256 KB
  __hip_bfloat16*  Wlb4  = (__hip_bfloat16*)(ws + 2883584);  // 64 KB
  __hip_bfloat16*  Wdb4  = (__hip_bfloat16*)(ws + 2949120);  // 64 KB
  __hip_bfloat16*  xcatb = (__hip_bfloat16*)(ws + 3145728);  // 8 MB
  float*           xcat  = (float*)(ws + 11534336);          // 16 MB
  char*            region = ws + 28311552;                   // dist / Tbuf+h1b
  unsigned*        dist  = (unsigned*)(region);
  float*           Tbuf  = (float*)(region);
  __hip_bfloat16*  h1b   = (__hip_bfloat16*)(region + 8388608);

  // dist buffer variants: both batches (128MB) > one batch (64MB) > chunked (16MB)
  const bool big2 = (ws_size >= (size_t)28311552 + (128u << 20));
  const bool big1 = (ws_size >= (size_t)28311552 + (64u << 20));

  hipMemsetAsync(gk, 0, 2 * 1024 * sizeof(unsigned), stream);

  // weight bf16 packs (L4 + head only; L1-L3 weights stay fp32)
  k_conv<<<dim3(256, 2), dim3(64), 0, stream>>>(W4, 256, 0, 0, 128, Wlb4);
  k_conv<<<dim3(256, 2), dim3(64), 0, stream>>>(W4, 256, 128, 1, 128, Wdb4);
  k_conv<<<dim3(1024, 8), dim3(64), 0, stream>>>(Wg, 512, 0, 0, 512, Wgb);
  k_conv<<<dim3(512, 8), dim3(64), 0, stream>>>(Ws1, 1536, 0, 0, 512, Ws1b);
  k_conv<<<dim3(256, 8), dim3(64), 0, stream>>>(Ws2, 512, 0, 0, 512, Ws2b);

  // kNN for one layer (fills idxb); selection bit-identical in all paths
  auto run_knn = [&](const float* F, int ldf, int C) {
    k_xx<<<dim3(2048), dim3(256), 0, stream>>>(F, ldf, C, xxb);
    if (big2) {
      k_dist<<<dim3(32, 32, 2), dim3(256), 0, stream>>>(F, ldf, C, xxb, dist, -1, 0);
      k_topk<<<dim3(4096, 2), dim3(256), 0, stream>>>(dist, idxb, -1, 0);
    } else if (big1) {
      for (int b = 0; b < 2; ++b) {
        k_dist<<<dim3(32, 32), dim3(256), 0, stream>>>(F, ldf, C, xxb, dist, b, 0);
        k_topk<<<dim3(4096), dim3(256), 0, stream>>>(dist, idxb, b, 0);
      }
    } else {
      for (int b = 0; b < 2; ++b)
        for (int c = 0; c < 4; ++c) {
          k_dist<<<dim3(8, 32), dim3(256), 0, stream>>>(F, ldf, C, xxb, dist, b, c * 1024);
          k_topk<<<dim3(1024), dim3(256), 0, stream>>>(dist, idxb, b, c * 1024);
        }
    }
  };

  // ---- Layer 1 (C=3 -> 64, fp32 exact) ----
  run_knn(X, 3, 3);
  k_edge1<<<dim3(2048), dim3(256), 0, stream>>>(X, W1, S1, B1, idxb, xcat, xcatb);

  // ---- Layer 2 (64 -> 64), fp32 (feeds kNN — must stay exact, R9 proved it) ----
  run_knn(xcat, 512, 64);
  k_pwT<<<dim3(128, 1), dim3(256), 0, stream>>>(xcat, 512, 64, W2, 128, 64, Tbuf, 64);
  k_edge<<<dim3(2048, 1), dim3(256), 0, stream>>>(xcat, 512, 64, W2, S2, B2,
      idxb, Tbuf, 64, xcat + 64, xcatb + 64);

  // ---- Layer 3 (64 -> 128), fp32 (feeds kNN) ----
  run_knn(xcat + 64, 512, 64);
  k_pwT<<<dim3(128, 2), dim3(256), 0, stream>>>(xcat + 64, 512, 64, W3, 128, 64, Tbuf, 128);
  k_edge<<<dim3(2048, 2), dim3(256), 0, stream>>>(xcat + 64, 512, 64, W3, S3, B3,
      idxb, Tbuf, 128, xcat + 128, xcatb + 128);

  // ---- Layer 4 (128 -> 256), bf16 MFMA (x4 feeds nothing discrete) ----
  run_knn(xcat + 128, 512, 128);
  k_mm<0><<<dim3(64, 4), dim3(256), 0, stream>>>(xcatb + 128, 512, 128, Wdb4,
      nullptr, nullptr, nullptr, 256, Tbuf, 256, nullptr, 0, nullptr);
  k_edgem<<<dim3(512, 4), dim3(256), 0, stream>>>(xcatb, 512, 128, 128, Wlb4,
      S4, B4, Tbuf, 256, idxb, xcat + 256, xcatb + 256);

  // ---- head (all bf16 MFMA) ----
  k_mm<2><<<dim3(64, 16), dim3(256), 0, stream>>>(xcatb, 512, 512, Wgb,
      Sg, Bg, nullptr, 1024, nullptr, 0, nullptr, 0, gk);
  k_bias2<<<dim3(256), dim3(256), 0, stream>>>(gk, Ws1, b2g);
  k_mm<1><<<dim3(64, 8), dim3(256), 0, stream>>>(xcatb, 512, 512, Ws1b,
      Ss1, Bs1, b2g, 512, nullptr, 0, h1b, 512, nullptr);
  k_mm<1><<<dim3(64, 4), dim3(256), 0, stream>>>(h1b, 512, 512, Ws2b,
      Ss2, Bs2, nullptr, 256, Tbuf, 256, nullptr, 0, nullptr);
  k_out<<<dim3(512), dim3(256), 0, stream>>>(Tbuf, Ws3, Bs3, (float*)d_out);
}

// Round 15
// 977.188 us; speedup vs baseline: 1.0980x; 1.0093x over previous
//
#include <hip/hip_runtime.h>
#include <hip/hip_bf16.h>

// DGCNN_Seg forward. B=2, N=4096, K=20. fp32 in/out.
// Round 15: symmetric k_dist — d(i,j)=d(j,i) bit-exactly (commutative fp32
// mul/add, same summation order), so compute upper-triangle tiles only
// (528 vs 1024) and mirror via LDS strip-transpose. Halves dist GEMM FLOPs.
// Rest = R14 (986us, absmax 0.01171875).

#define DEVI static __device__ __forceinline__
typedef __attribute__((ext_vector_type(8))) short bf16x8;   // 8 bf16 = 4 VGPR
typedef __attribute__((ext_vector_type(4))) float f32x4;    // MFMA acc
typedef unsigned long long ull;

DEVI float lrelu(float y) { return y > 0.f ? y : 0.2f * y; }
DEVI unsigned okey(float f) {
  unsigned u = __float_as_uint(f);
  return (f < 0.f) ? ~u : (u | 0x80000000u);
}
DEVI float dekey(unsigned k) {
  return __uint_as_float((k & 0x80000000u) ? (k & 0x7fffffffu) : ~k);
}

// ---------------- weight fp32 -> bf16 pack ----------------
__global__ __launch_bounds__(64) void k_conv(const float* __restrict__ src, int lds, int off,
                                             int sub, int Kc, __hip_bfloat16* __restrict__ dst) {
  int o = blockIdx.x, c = blockIdx.y * 64 + threadIdx.x;
  float v = src[(size_t)o * lds + off + c];
  if (sub) v -= src[(size_t)o * lds + c];
  dst[(size_t)o * Kc + c] = __float2bfloat16(v);
}

// ---------------- row squared-norms: one wave per row ----------------
__global__ __launch_bounds__(256) void k_xx(const float* __restrict__ F, int ldf, int C,
                                            float* __restrict__ xx) {
  int lane = threadIdx.x & 63;
  int row = blockIdx.x * 4 + (threadIdx.x >> 6);
  const float* f = F + (size_t)row * ldf;
  float s = 0.f;
  for (int c = lane; c < C; c += 64) { float v = f[c]; s += v * v; }
#pragma unroll
  for (int off = 32; off; off >>= 1) s += __shfl_xor(s, off, 64);
  if (lane == 0) xx[row] = s;
}

// ---------------- pairwise distances v4: 128x128 tile, 8x8/thread ----------------
// sym=1 (big2 path): triangular tile decode from blockIdx.x, batch=blockIdx.z;
// off-diagonal tiles also write the mirrored block via LDS strip-transpose.
// Stores okey(d) u32. Per-element fmaf order identical -> bit-identical.
__global__ __launch_bounds__(256) void k_dist(const float* __restrict__ F, int ldf, int C,
                                              const float* __restrict__ xx,
                                              unsigned* __restrict__ D, int bfix, int ibase,
                                              int sym) {
  __shared__ __align__(16) char smem[16896];
  float (*As)[132] = (float(*)[132])smem;            // 16x132x4 = 8448 B
  float (*Bs)[132] = (float(*)[132])(smem + 8448);   // 8448 B
  unsigned (*Ls)[132] = (unsigned(*)[132])smem;      // 32x132x4 = 16896 B (post-loop overlay)
  const int tid = threadIdx.x;
  const int tx = tid & 15, ty = tid >> 4;
  int bi, bj;
  if (sym) {
    int t = blockIdx.x, r = 32;
    bi = 0;
    while (t >= r) { t -= r; ++bi; r = 32 - bi; }
    bj = bi + t;
  } else {
    bi = blockIdx.x;
    bj = blockIdx.y;
  }
  const int b = (bfix < 0) ? (int)blockIdx.z : bfix;
  unsigned* Db = (bfix < 0) ? (D + (size_t)b * 4096 * 4096) : D;
  const int i0 = ibase + bi * 128, j0 = bj * 128;
  const float* Fb = F + (size_t)b * 4096 * ldf;
  const float* xxb = xx + b * 4096;
  const int srow = tid >> 1, sq = (tid & 1) * 8;  // stage: 128 rows x 16 cols
  float acc[8][8] = {};
  for (int c0 = 0; c0 < C; c0 += 16) {
    if (C - c0 >= 16) {
      float4 a0 = *(const float4*)(Fb + (size_t)(i0 + srow) * ldf + c0 + sq);
      float4 a1 = *(const float4*)(Fb + (size_t)(i0 + srow) * ldf + c0 + sq + 4);
      As[sq + 0][srow] = a0.x; As[sq + 1][srow] = a0.y; As[sq + 2][srow] = a0.z; As[sq + 3][srow] = a0.w;
      As[sq + 4][srow] = a1.x; As[sq + 5][srow] = a1.y; As[sq + 6][srow] = a1.z; As[sq + 7][srow] = a1.w;
      float4 b0 = *(const float4*)(Fb + (size_t)(j0 + srow) * ldf + c0 + sq);
      float4 b1 = *(const float4*)(Fb + (size_t)(j0 + srow) * ldf + c0 + sq + 4);
      Bs[sq + 0][srow] = b0.x; Bs[sq + 1][srow] = b0.y; Bs[sq + 2][srow] = b0.z; Bs[sq + 3][srow] = b0.w;
      Bs[sq + 4][srow] = b1.x; Bs[sq + 5][srow] = b1.y; Bs[sq + 6][srow] = b1.z; Bs[sq + 7][srow] = b1.w;
    } else {
#pragma unroll
      for (int e = 0; e < 8; ++e) {
        int c = c0 + sq + e;
        As[sq + e][srow] = (c < C) ? Fb[(size_t)(i0 + srow) * ldf + c] : 0.f;
        Bs[sq + e][srow] = (c < C) ? Fb[(size_t)(j0 + srow) * ldf + c] : 0.f;
      }
    }
    __syncthreads();
#pragma unroll
    for (int kk = 0; kk < 16; ++kk) {
      const float4 al = *(const float4*)&As[kk][ty * 8];
      const float4 ah = *(const float4*)&As[kk][ty * 8 + 4];
      const float4 bl = *(const float4*)&Bs[kk][tx * 8];
      const float4 bh = *(const float4*)&Bs[kk][tx * 8 + 4];
      const float av[8] = {al.x, al.y, al.z, al.w, ah.x, ah.y, ah.z, ah.w};
      const float bv[8] = {bl.x, bl.y, bl.z, bl.w, bh.x, bh.y, bh.z, bh.w};
#pragma unroll
      for (int ii = 0; ii < 8; ++ii)
#pragma unroll
        for (int jj = 0; jj < 8; ++jj)
          acc[ii][jj] = fmaf(av[ii], bv[jj], acc[ii][jj]);
    }
    __syncthreads();
  }
  // normal block store
#pragma unroll
  for (int ii = 0; ii < 8; ++ii) {
    int i = i0 + ty * 8 + ii;
    float xi = xxb[i];
    uint4 o1, o2;
    o1.x = okey(xi + xxb[j0 + tx * 8 + 0] - 2.f * acc[ii][0]);
    o1.y = okey(xi + xxb[j0 + tx * 8 + 1] - 2.f * acc[ii][1]);
    o1.z = okey(xi + xxb[j0 + tx * 8 + 2] - 2.f * acc[ii][2]);
    o1.w = okey(xi + xxb[j0 + tx * 8 + 3] - 2.f * acc[ii][3]);
    o2.x = okey(xi + xxb[j0 + tx * 8 + 4] - 2.f * acc[ii][4]);
    o2.y = okey(xi + xxb[j0 + tx * 8 + 5] - 2.f * acc[ii][5]);
    o2.z = okey(xi + xxb[j0 + tx * 8 + 6] - 2.f * acc[ii][6]);
    o2.w = okey(xi + xxb[j0 + tx * 8 + 7] - 2.f * acc[ii][7]);
    *(uint4*)&Db[(size_t)(i - ibase) * 4096 + j0 + tx * 8] = o1;
    *(uint4*)&Db[(size_t)(i - ibase) * 4096 + j0 + tx * 8 + 4] = o2;
  }
  // mirror block store (sym, off-diagonal): strip-transpose through LDS.
  // fp32 + and * are commutative -> mirror value bit-identical to direct compute.
  if (sym && bi < bj) {
    for (int s = 0; s < 4; ++s) {
      __syncthreads();  // Ls overlays As/Bs; also guards strip reuse
      if ((tx >> 2) == s) {
        const int ltx = tx & 3;
        float xi_[8];
#pragma unroll
        for (int jj = 0; jj < 8; ++jj) xi_[jj] = xxb[j0 + tx * 8 + jj];
#pragma unroll
        for (int ii = 0; ii < 8; ++ii) {
          float xr = xxb[i0 + ty * 8 + ii];
#pragma unroll
          for (int jj = 0; jj < 8; ++jj)
            Ls[ltx * 8 + jj][ty * 8 + ii] = okey(xr + xi_[jj] - 2.f * acc[ii][jj]);
        }
      }
      __syncthreads();
      // copy out: 32 mirror rows x 128 cols; thread tid -> row tid>>3, col seg (tid&7)*16
      {
        const int mr = tid >> 3, cs = (tid & 7) * 16;
        unsigned* dst = &Db[(size_t)(j0 + s * 32 + mr) * 4096 + i0 + cs];
        const unsigned* srcp = &Ls[mr][cs];
        *(uint4*)(dst + 0) = *(const uint4*)(srcp + 0);
        *(uint4*)(dst + 4) = *(const uint4*)(srcp + 4);
        *(uint4*)(dst + 8) = *(const uint4*)(srcp + 8);
        *(uint4*)(dst + 12) = *(const uint4*)(srcp + 12);
      }
    }
  }
}

// ---------------- top-20 v5: 1 block (4 waves) per row ----------------
__global__ __launch_bounds__(256) void k_topk(const unsigned* __restrict__ Dk,
                                              int* __restrict__ idx, int bfix, int ibase) {
  __shared__ ull cand[4][20];
  const int tid = threadIdx.x, lane = tid & 63, wv = tid >> 6;
  const int ir_ = blockIdx.x;
  const int b = (bfix < 0) ? (int)blockIdx.y : bfix;
  const unsigned* drow = Dk + ((bfix < 0) ? (size_t)b * 4096 * 4096 : 0) + (size_t)ir_ * 4096;
  const int base = wv * 1024 + lane;
  unsigned key[16];
#pragma unroll
  for (int it = 0; it < 16; ++it) key[it] = drow[base + it * 64];
  unsigned m1k = 0xFFFFFFFFu, m2k = 0xFFFFFFFFu, m3k = 0xFFFFFFFFu;
  int m1p = 0, m2p = 0, m3p = 0;
#pragma unroll
  for (int it = 0; it < 16; ++it) {
    unsigned v = key[it];
    bool b1 = v < m1k, b2 = v < m2k, b3 = v < m3k;
    m3k = b2 ? m2k : (b3 ? v : m3k);
    m3p = b2 ? m2p : (b3 ? it : m3p);
    m2k = b1 ? m1k : (b2 ? v : m2k);
    m2p = b1 ? m1p : (b2 ? it : m2p);
    m1k = b1 ? v : m1k;
    m1p = b1 ? it : m1p;
  }
  unsigned consumed = (1u << m1p) | (1u << m2p) | (1u << m3p);
  unsigned ck = m1k, cp = (unsigned)(lane | (m1p << 6));
  unsigned n1k = m2k, n1p = (unsigned)(lane | (m2p << 6));
  unsigned n2k = m3k, n2p = (unsigned)(lane | (m3p << 6));
  for (int r = 0; r < 20; ++r) {
    unsigned mh = ck;
#pragma unroll
    for (int off = 32; off; off >>= 1) {
      unsigned o = __shfl_xor(mh, off, 64);
      mh = o < mh ? o : mh;
    }
    unsigned lo2 = (ck == mh) ? cp : 0xFFFFFFFFu;
    unsigned ml = lo2;
#pragma unroll
    for (int off = 32; off; off >>= 1) {
      unsigned o = __shfl_xor(ml, off, 64);
      ml = o < ml ? o : ml;
    }
    if (lane == 0) cand[wv][r] = ((ull)mh << 32) | (unsigned)(wv * 1024 + ml);
    bool pop = (ck == mh) && (cp == ml);
    ck = pop ? n1k : ck;  cp = pop ? n1p : cp;
    n1k = pop ? n2k : n1k; n1p = pop ? n2p : n1p;
    n2k = pop ? 0xFFFFFFFFu : n2k;
    if (ck == 0xFFFFFFFFu) {  // rare: lane popped >=3 times; refill from regs
      unsigned bk = 0xFFFFFFFFu; int bp = 0;
#pragma unroll
      for (int it2 = 0; it2 < 16; ++it2) {
        bool ok = ((consumed >> it2) & 1u) == 0u;
        unsigned v = ok ? key[it2] : 0xFFFFFFFFu;
        bool t = v < bk;
        bk = t ? v : bk;
        bp = t ? it2 : bp;
      }
      consumed |= (1u << bp);
      ck = bk;
      cp = (unsigned)(lane | (bp << 6));
    }
  }
  __syncthreads();
  if (tid == 0) {
    int* op = idx + ((size_t)b * 4096 + ibase + ir_) * 20;
    int p0 = 0, p1 = 0, p2 = 0, p3 = 0;
    for (int r = 0; r < 20; ++r) {
      ull v0 = cand[0][p0], v1 = cand[1][p1], v2 = cand[2][p2], v3 = cand[3][p3];
      ull m01 = v0 < v1 ? v0 : v1;
      ull m23 = v2 < v3 ? v2 : v3;
      ull best = m01 < m23 ? m01 : m23;
      if (best == v0) ++p0; else if (best == v1) ++p1;
      else if (best == v2) ++p2; else ++p3;
      op[r] = (int)(best & 0xfffull);
      if (p0 > 19) p0 = 19;
      if (p1 > 19) p1 = 19;
      if (p2 > 19) p2 = 19;
      if (p3 > 19) p3 = 19;
    }
  }
}

// ---------------- EdgeConv layer 1 (fp32, Cin=3): one wave per point ----------------
__global__ __launch_bounds__(256) void k_edge1(const float* __restrict__ xf,
                                               const float* __restrict__ W1,
                                               const float* __restrict__ s1,
                                               const float* __restrict__ b1,
                                               const int* __restrict__ idx,
                                               float* __restrict__ xcat,
                                               __hip_bfloat16* __restrict__ xcatb) {
  const int lane = threadIdx.x & 63;
  const int p = blockIdx.x * 4 + (threadIdx.x >> 6);
  const int bb = p >> 12;
  float wl[3], wr[3];
#pragma unroll
  for (int c = 0; c < 3; ++c) {
    wl[c] = W1[lane * 6 + c];
    wr[c] = W1[lane * 6 + 3 + c];
  }
  const float s = s1[lane], bi = b1[lane];
  const float* xc = xf + (size_t)p * 3;
  const float x0 = xc[0], x1 = xc[1], x2 = xc[2];
  const float t = x0 * (wr[0] - wl[0]) + x1 * (wr[1] - wl[1]) + x2 * (wr[2] - wl[2]);
  const int* ir = idx + (size_t)p * 20;
  float best = -INFINITY;
  for (int k = 0; k < 20; ++k) {
    int j = ir[k];
    const float* xn = xf + ((size_t)(bb << 12) + j) * 3;
    float y = t + xn[0] * wl[0] + xn[1] * wl[1] + xn[2] * wl[2];
    y = lrelu(y * s + bi);
    best = fmaxf(best, y);
  }
  xcat[(size_t)p * 512 + lane] = best;
  xcatb[(size_t)p * 512 + lane] = __float2bfloat16(best);
}

// ---------------- fp32 pointwise GEMM, raw store (T for layers 2-3) ----------------
__global__ __launch_bounds__(256) void k_pwT(const float* __restrict__ A, int lda, int K,
                                             const float* __restrict__ W, int ldw, int wsub,
                                             float* __restrict__ out, int ldo) {
  __shared__ __align__(16) float As[16][68];
  __shared__ __align__(16) float Bs[16][68];
  const int tid = threadIdx.x;
  const int tx = tid & 15, ty = tid >> 4;
  const int i0 = blockIdx.x * 64, o0 = blockIdx.y * 64;
  const int row = tid >> 2, q = (tid & 3) * 4;
  float acc[4][4] = {};
  for (int c0 = 0; c0 < K; c0 += 16) {
    float4 a = *(const float4*)(A + (size_t)(i0 + row) * lda + c0 + q);
    As[q + 0][row] = a.x; As[q + 1][row] = a.y; As[q + 2][row] = a.z; As[q + 3][row] = a.w;
    const float* wp = W + (size_t)(o0 + row) * ldw + c0 + q;
#pragma unroll
    for (int e = 0; e < 4; ++e) Bs[q + e][row] = wp[wsub + e] - wp[e];
    __syncthreads();
#pragma unroll
    for (int kk = 0; kk < 16; ++kk) {
      const float4 a4 = *(const float4*)&As[kk][ty * 4];
      const float4 b4 = *(const float4*)&Bs[kk][tx * 4];
      const float av[4] = {a4.x, a4.y, a4.z, a4.w};
      const float bv[4] = {b4.x, b4.y, b4.z, b4.w};
#pragma unroll
      for (int ii = 0; ii < 4; ++ii)
#pragma unroll
        for (int jj = 0; jj < 4; ++jj)
          acc[ii][jj] = fmaf(av[ii], bv[jj], acc[ii][jj]);
    }
    __syncthreads();
  }
#pragma unroll
  for (int ii = 0; ii < 4; ++ii)
#pragma unroll
    for (int jj = 0; jj < 4; ++jj)
      out[(size_t)(i0 + ty * 4 + ii) * ldo + o0 + tx * 4 + jj] = acc[ii][jj];
}

// ---------------- fp32 EdgeConv GEMM (layers 2-3; feeds kNN, stays exact) ----------------
__global__ __launch_bounds__(256) void k_edge(const float* __restrict__ F, int ldf, int Cin,
                                              const float* __restrict__ W,
                                              const float* __restrict__ sc,
                                              const float* __restrict__ bi,
                                              const int* __restrict__ idx,
                                              const float* __restrict__ T, int ldt,
                                              float* __restrict__ out,
                                              __hip_bfloat16* __restrict__ outb) {
  __shared__ float As[16][81];
  __shared__ __align__(16) float Bs[16][68];
  __shared__ float Ys[80][65];
  const int tid = threadIdx.x;
  const int tx = tid & 15, ty = tid >> 4;
  const int r0 = blockIdx.x * 80;
  const int o0 = blockIdx.y * 64;
  const int ldw = 2 * Cin;
  int grow[5], gcol[5];
#pragma unroll
  for (int l = 0; l < 5; ++l) {
    int e = tid + l * 256;
    int rr = e >> 4;
    gcol[l] = e & 15;
    int gr = r0 + rr;
    int p = gr / 20;
    int j = idx[(size_t)p * 20 + (gr % 20)];
    grow[l] = ((p >> 12) << 12) + j;
  }
  float acc[5][4] = {};
  const int wrow = tid >> 2, wq = (tid & 3) * 4;
  for (int c0 = 0; c0 < Cin; c0 += 16) {
#pragma unroll
    for (int l = 0; l < 5; ++l) {
      int e = tid + l * 256;
      As[gcol[l]][e >> 4] = F[(size_t)grow[l] * ldf + c0 + gcol[l]];
    }
    {
      const float* wp = W + (size_t)(o0 + wrow) * ldw + c0 + wq;
#pragma unroll
      for (int e = 0; e < 4; ++e) Bs[wq + e][wrow] = wp[e];
    }
    __syncthreads();
#pragma unroll
    for (int kk = 0; kk < 16; ++kk) {
      float a[5];
#pragma unroll
      for (int l = 0; l < 5; ++l) a[l] = As[kk][ty + l * 16];
      const float4 b4 = *(const float4*)&Bs[kk][tx * 4];
      const float bv[4] = {b4.x, b4.y, b4.z, b4.w};
#pragma unroll
      for (int l = 0; l < 5; ++l)
#pragma unroll
        for (int jj = 0; jj < 4; ++jj)
          acc[l][jj] = fmaf(a[l], bv[jj], acc[l][jj]);
    }
    __syncthreads();
  }
#pragma unroll
  for (int l = 0; l < 5; ++l) {
    int r = ty + l * 16;
    int p = (r0 + r) / 20;
#pragma unroll
    for (int jj = 0; jj < 4; ++jj) {
      int o = o0 + tx * 4 + jj;
      float y = (acc[l][jj] + T[(size_t)p * ldt + o]) * sc[o] + bi[o];
      Ys[r][tx * 4 + jj] = lrelu(y);
    }
  }
  __syncthreads();
  const int grp = tid >> 6, col = tid & 63;
  float m = -INFINITY;
#pragma unroll
  for (int k = 0; k < 20; ++k) m = fmaxf(m, Ys[grp * 20 + k][col]);
  const int p = blockIdx.x * 4 + grp;
  out[(size_t)p * 512 + o0 + col] = m;
  outb[(size_t)p * 512 + o0 + col] = __float2bfloat16(m);
}

// ---------------- MFMA bf16 GEMM: block 128(M)x64(N), 4 waves x (32x64) ----------------
template <int EPI>
__global__ __launch_bounds__(256) void k_mm(
    const __hip_bfloat16* __restrict__ A, int lda, int K,
    const __hip_bfloat16* __restrict__ B,  // [N][K] bf16
    const float* __restrict__ sc, const float* __restrict__ bi,
    const float* __restrict__ extra, int Ncols,
    float* __restrict__ outf, int ldof,
    __hip_bfloat16* __restrict__ outb, int ldob,
    unsigned* __restrict__ gmax) {
  __shared__ __align__(16) __hip_bfloat16 Al[128 * 40];
  __shared__ __align__(16) __hip_bfloat16 Bl[64 * 40];
  __shared__ float Red[4][64];
  const int tid = threadIdx.x, lane = tid & 63, wv = tid >> 6;
  const int m0 = blockIdx.x * 128, n0 = blockIdx.y * 64;
  const int arow = tid >> 2, akc = (tid & 3) * 8;
  const int fm = lane & 15, fq = lane >> 4;
  f32x4 acc[2][4];
#pragma unroll
  for (int mt = 0; mt < 2; ++mt)
#pragma unroll
    for (int nt = 0; nt < 4; ++nt) acc[mt][nt] = (f32x4){0.f, 0.f, 0.f, 0.f};
  for (int c0 = 0; c0 < K; c0 += 32) {
#pragma unroll
    for (int l = 0; l < 2; ++l) {
      int r = arow + l * 64;
      *(float4*)&Al[r * 40 + akc] = *(const float4*)(A + (size_t)(m0 + r) * lda + c0 + akc);
    }
    *(float4*)&Bl[arow * 40 + akc] = *(const float4*)(B + (size_t)(n0 + arow) * K + c0 + akc);
    __syncthreads();
    bf16x8 af[2], bfr[4];
#pragma unroll
    for (int mt = 0; mt < 2; ++mt)
      af[mt] = *(const bf16x8*)&Al[(wv * 32 + mt * 16 + fm) * 40 + fq * 8];
#pragma unroll
    for (int nt = 0; nt < 4; ++nt)
      bfr[nt] = *(const bf16x8*)&Bl[(nt * 16 + fm) * 40 + fq * 8];
#pragma unroll
    for (int mt = 0; mt < 2; ++mt)
#pragma unroll
      for (int nt = 0; nt < 4; ++nt)
        acc[mt][nt] = __builtin_amdgcn_mfma_f32_16x16x32_bf16(af[mt], bfr[nt], acc[mt][nt], 0, 0, 0);
    __syncthreads();
  }
  const int bidx = m0 >> 12;
  if (EPI == 0) {
#pragma unroll
    for (int mt = 0; mt < 2; ++mt)
#pragma unroll
      for (int nt = 0; nt < 4; ++nt)
#pragma unroll
        for (int r = 0; r < 4; ++r)
          outf[(size_t)(m0 + wv * 32 + mt * 16 + fq * 4 + r) * ldof + n0 + nt * 16 + fm] =
              acc[mt][nt][r];
  } else if (EPI == 1) {
#pragma unroll
    for (int nt = 0; nt < 4; ++nt) {
      int col = n0 + nt * 16 + fm;
      float s = sc[col], bb = bi[col];
      float ex = extra ? extra[bidx * Ncols + col] : 0.f;
#pragma unroll
      for (int mt = 0; mt < 2; ++mt)
#pragma unroll
        for (int r = 0; r < 4; ++r) {
          float v = lrelu((acc[mt][nt][r] + ex) * s + bb);
          size_t rr = (size_t)(m0 + wv * 32 + mt * 16 + fq * 4 + r);
          if (outf) outf[rr * ldof + col] = v;
          if (outb) outb[rr * ldob + col] = __float2bfloat16(v);
        }
    }
  } else {
#pragma unroll
    for (int nt = 0; nt < 4; ++nt) {
      int col = n0 + nt * 16 + fm;
      float s = sc[col], bb = bi[col];
      float m = -INFINITY;
#pragma unroll
      for (int mt = 0; mt < 2; ++mt)
#pragma unroll
        for (int r = 0; r < 4; ++r) m = fmaxf(m, lrelu(acc[mt][nt][r] * s + bb));
      m = fmaxf(m, __shfl_xor(m, 16, 64));
      m = fmaxf(m, __shfl_xor(m, 32, 64));
      if (fq == 0) Red[wv][nt * 16 + fm] = m;
    }
    __syncthreads();
    if (tid < 64) {
      float m = fmaxf(fmaxf(Red[0][tid], Red[1][tid]), fmaxf(Red[2][tid], Red[3][tid]));
      atomicMax(&gmax[bidx * Ncols + n0 + tid], okey(m));
    }
  }
}

// ---------------- MFMA bf16 EdgeConv (layer 4): 320 edges x 64 cols / block ----------------
__global__ __launch_bounds__(256) void k_edgem(
    const __hip_bfloat16* __restrict__ F, int ldf, int coff, int K,
    const __hip_bfloat16* __restrict__ Wl,  // [N][K] bf16
    const float* __restrict__ sc, const float* __restrict__ bi,
    const float* __restrict__ T, int N,
    const int* __restrict__ idx,
    float* __restrict__ outf, __hip_bfloat16* __restrict__ outb) {
  __shared__ __align__(16) char smem[320 * 66 * 2];  // 42240 B, overlaid stage/Ys
  __hip_bfloat16* Al = (__hip_bfloat16*)smem;              // 320*40
  __hip_bfloat16* Bl = (__hip_bfloat16*)(smem + 25600);    // 64*40
  __hip_bfloat16* Ys = (__hip_bfloat16*)smem;              // 320*66 (post-loop)
  const int tid = threadIdx.x, lane = tid & 63, wv = tid >> 6;
  const int blk = blockIdx.x, n0 = blockIdx.y * 64;
  const int arow = tid >> 2, akc = (tid & 3) * 8;
  const int fm = lane & 15, fq = lane >> 4;
  const __hip_bfloat16* ap[5];
#pragma unroll
  for (int l = 0; l < 5; ++l) {
    int row = arow + l * 64;
    int e = blk * 320 + row;
    int p = e / 20;
    int j = idx[(size_t)p * 20 + (e - p * 20)];
    int src = ((p >> 12) << 12) + j;
    ap[l] = F + (size_t)src * ldf + coff + akc;
  }
  f32x4 acc[5][4];
#pragma unroll
  for (int l = 0; l < 5; ++l)
#pragma unroll
    for (int nt = 0; nt < 4; ++nt) acc[l][nt] = (f32x4){0.f, 0.f, 0.f, 0.f};
  for (int c0 = 0; c0 < K; c0 += 32) {
#pragma unroll
    for (int l = 0; l < 5; ++l)
      *(float4*)&Al[(arow + l * 64) * 40 + akc] = *(const float4*)(ap[l] + c0);
    *(float4*)&Bl[arow * 40 + akc] = *(const float4*)(Wl + (size_t)(n0 + arow) * K + c0 + akc);
    __syncthreads();
    bf16x8 af[5], bfr[4];
#pragma unroll
    for (int l = 0; l < 5; ++l)
      af[l] = *(const bf16x8*)&Al[(wv * 80 + l * 16 + fm) * 40 + fq * 8];
#pragma unroll
    for (int nt = 0; nt < 4; ++nt)
      bfr[nt] = *(const bf16x8*)&Bl[(nt * 16 + fm) * 40 + fq * 8];
#pragma unroll
    for (int l = 0; l < 5; ++l)
#pragma unroll
      for (int nt = 0; nt < 4; ++nt)
        acc[l][nt] = __builtin_amdgcn_mfma_f32_16x16x32_bf16(af[l], bfr[nt], acc[l][nt], 0, 0, 0);
    __syncthreads();
  }
#pragma unroll
  for (int l = 0; l < 5; ++l)
#pragma unroll
    for (int nt = 0; nt < 4; ++nt)
#pragma unroll
      for (int r = 0; r < 4; ++r)
        Ys[(wv * 80 + l * 16 + fq * 4 + r) * 66 + nt * 16 + fm] = __float2bfloat16(acc[l][nt][r]);
  __syncthreads();
  const int col = tid & 63;
#pragma unroll
  for (int gi = 0; gi < 4; ++gi) {
    int grp = wv + gi * 4;
    float m = -INFINITY;
#pragma unroll
    for (int k = 0; k < 20; ++k)
      m = fmaxf(m, __bfloat162float(Ys[(grp * 20 + k) * 66 + col]));
    int p = blk * 16 + grp;
    int o = n0 + col;
    float v = lrelu((m + T[(size_t)p * N + o]) * sc[o] + bi[o]);
    outf[(size_t)p * 512 + o] = v;
    outb[(size_t)p * 512 + o] = __float2bfloat16(v);
  }
}

// ---------------- bias2: one wave per (b,o) ----------------
__global__ __launch_bounds__(256) void k_bias2(const unsigned* __restrict__ gk,
                                               const float* __restrict__ Ws1,
                                               float* __restrict__ b2g) {
  const int lane = threadIdx.x & 63;
  const int wid = (blockIdx.x * 256 + threadIdx.x) >> 6;  // 0..1023
  const int b = wid >> 9, o = wid & 511;
  const float* wr = Ws1 + (size_t)o * 1536 + 512;
  const unsigned* g = gk + b * 1024;
  float acc = 0.f;
#pragma unroll
  for (int c = lane; c < 1024; c += 64) acc = fmaf(dekey(g[c]), wr[c], acc);
#pragma unroll
  for (int off = 32; off; off >>= 1) acc += __shfl_xor(acc, off, 64);
  if (lane == 0) b2g[b * 512 + o] = acc;
}

// ---------------- final head: out = H(8192x256) . Ws3^T + bs3 (fp32) ----------------
__global__ __launch_bounds__(256) void k_out(const float* __restrict__ H,
                                             const float* __restrict__ Ws3,
                                             const float* __restrict__ bs3,
                                             float* __restrict__ out) {
  __shared__ float Ws[13][256];
  const int tid = threadIdx.x;
  for (int e = tid; e < 13 * 256; e += 256) Ws[e >> 8][e & 255] = Ws3[e];
  __syncthreads();
  const int rloc = tid >> 4, o = tid & 15;
  const int row = blockIdx.x * 16 + rloc;
  if (o < 13) {
    const float* h = H + (size_t)row * 256;
    float acc = 0.f;
    for (int c = 0; c < 256; ++c) acc = fmaf(h[c], Ws[o][c], acc);
    out[(size_t)row * 13 + o] = acc + bs3[o];
  }
}

extern "C" void kernel_launch(void* const* d_in, const int* in_sizes, int n_in,
                              void* d_out, int out_size, void* d_ws, size_t ws_size,
                              hipStream_t stream) {
  const float* X   = (const float*)d_in[0];
  const float* W1  = (const float*)d_in[1];
  const float* S1  = (const float*)d_in[2];
  const float* B1  = (const float*)d_in[3];
  const float* W2  = (const float*)d_in[4];
  const float* S2  = (const float*)d_in[5];
  const float* B2  = (const float*)d_in[6];
  const float* W3  = (const float*)d_in[7];
  const float* S3  = (const float*)d_in[8];
  const float* B3  = (const float*)d_in[9];
  const float* W4  = (const float*)d_in[10];
  const float* S4  = (const float*)d_in[11];
  const float* B4  = (const float*)d_in[12];
  const float* Wg  = (const float*)d_in[13];
  const float* Sg  = (const float*)d_in[14];
  const float* Bg  = (const float*)d_in[15];
  const float* Ws1 = (const float*)d_in[16];
  const float* Ss1 = (const float*)d_in[17];
  const float* Bs1 = (const float*)d_in[18];
  const float* Ws2 = (const float*)d_in[19];
  const float* Ss2 = (const float*)d_in[20];
  const float* Bs2 = (const float*)d_in[21];
  const float* Ws3 = (const float*)d_in[22];
  const float* Bs3 = (const float*)d_in[23];

  char* ws = (char*)d_ws;
  float*           xxb   = (float*)(ws + 0);            // 32 KB
  int*             idxb  = (int*)(ws + 32768);          // 640 KB
  unsigned*        gk    = (unsigned*)(ws + 688128);    // 8 KB
  float*           b2g   = (float*)(ws + 696320);       // 4 KB
  __hip_bfloat16*  Wgb   = (__hip_bfloat16*)(ws + 1048576);  // 1 MB
  __hip_bfloat16*  Ws1b  = (__hip_bfloat16*)(ws + 2097152);  // 512 KB
  __hip_bfloat16*  Ws2b  = (__hip_bfloat16*)(ws + 2621440);  // 256 KB
  __hip_bfloat16*  Wlb4  = (__hip_bfloat16*)(ws + 2883584);  // 64 KB
  __hip_bfloat16*  Wdb4  = (__hip_bfloat16*)(ws + 2949120);  // 64 KB
  __hip_bfloat16*  xcatb = (__hip_bfloat16*)(ws + 3145728);  // 8 MB
  float*           xcat  = (float*)(ws + 11534336);          // 16 MB
  char*            region = ws + 28311552;                   // dist / Tbuf+h1b
  unsigned*        dist  = (unsigned*)(region);
  float*           Tbuf  = (float*)(region);
  __hip_bfloat16*  h1b   = (__hip_bfloat16*)(region + 8388608);

  // dist buffer variants: both batches (128MB) > one batch (64MB) > chunked (16MB)
  const bool big2 = (ws_size >= (size_t)28311552 + (128u << 20));
  const bool big1 = (ws_size >= (size_t)28311552 + (64u << 20));

  hipMemsetAsync(gk, 0, 2 * 1024 * sizeof(unsigned), stream);

  // weight bf16 packs (L4 + head only; L1-L3 weights stay fp32)
  k_conv<<<dim3(256, 2), dim3(64), 0, stream>>>(W4, 256, 0, 0, 128, Wlb4);
  k_conv<<<dim3(256, 2), dim3(64), 0, stream>>>(W4, 256, 128, 1, 128, Wdb4);
  k_conv<<<dim3(1024, 8), dim3(64), 0, stream>>>(Wg, 512, 0, 0, 512, Wgb);
  k_conv<<<dim3(512, 8), dim3(64), 0, stream>>>(Ws1, 1536, 0, 0, 512, Ws1b);
  k_conv<<<dim3(256, 8), dim3(64), 0, stream>>>(Ws2, 512, 0, 0, 512, Ws2b);

  // kNN for one layer (fills idxb); selection bit-identical in all paths
  auto run_knn = [&](const float* F, int ldf, int C) {
    k_xx<<<dim3(2048), dim3(256), 0, stream>>>(F, ldf, C, xxb);
    if (big2) {
      k_dist<<<dim3(528, 1, 2), dim3(256), 0, stream>>>(F, ldf, C, xxb, dist, -1, 0, 1);
      k_topk<<<dim3(4096, 2), dim3(256), 0, stream>>>(dist, idxb, -1, 0);
    } else if (big1) {
      for (int b = 0; b < 2; ++b) {
        k_dist<<<dim3(32, 32), dim3(256), 0, stream>>>(F, ldf, C, xxb, dist, b, 0, 0);
        k_topk<<<dim3(4096), dim3(256), 0, stream>>>(dist, idxb, b, 0);
      }
    } else {
      for (int b = 0; b < 2; ++b)
        for (int c = 0; c < 4; ++c) {
          k_dist<<<dim3(8, 32), dim3(256), 0, stream>>>(F, ldf, C, xxb, dist, b, c * 1024, 0);
          k_topk<<<dim3(1024), dim3(256), 0, stream>>>(dist, idxb, b, c * 1024);
        }
    }
  };

  // ---- Layer 1 (C=3 -> 64, fp32 exact) ----
  run_knn(X, 3, 3);
  k_edge1<<<dim3(2048), dim3(256), 0, stream>>>(X, W1, S1, B1, idxb, xcat, xcatb);

  // ---- Layer 2 (64 -> 64), fp32 (feeds kNN — must stay exact, R9 proved it) ----
  run_knn(xcat, 512, 64);
  k_pwT<<<dim3(128, 1), dim3(256), 0, stream>>>(xcat, 512, 64, W2, 128, 64, Tbuf, 64);
  k_edge<<<dim3(2048, 1), dim3(256), 0, stream>>>(xcat, 512, 64, W2, S2, B2,
      idxb, Tbuf, 64, xcat + 64, xcatb + 64);

  // ---- Layer 3 (64 -> 128), fp32 (feeds kNN) ----
  run_knn(xcat + 64, 512, 64);
  k_pwT<<<dim3(128, 2), dim3(256), 0, stream>>>(xcat + 64, 512, 64, W3, 128, 64, Tbuf, 128);
  k_edge<<<dim3(2048, 2), dim3(256), 0, stream>>>(xcat + 64, 512, 64, W3, S3, B3,
      idxb, Tbuf, 128, xcat + 128, xcatb + 128);

  // ---- Layer 4 (128 -> 256), bf16 MFMA (x4 feeds nothing discrete) ----
  run_knn(xcat + 128, 512, 128);
  k_mm<0><<<dim3(64, 4), dim3(256), 0, stream>>>(xcatb + 128, 512, 128, Wdb4,
      nullptr, nullptr, nullptr, 256, Tbuf, 256, nullptr, 0, nullptr);
  k_edgem<<<dim3(512, 4), dim3(256), 0, stream>>>(xcatb, 512, 128, 128, Wlb4,
      S4, B4, Tbuf, 256, idxb, xcat + 256, xcatb + 256);

  // ---- head (all bf16 MFMA) ----
  k_mm<2><<<dim3(64, 16), dim3(256), 0, stream>>>(xcatb, 512, 512, Wgb,
      Sg, Bg, nullptr, 1024, nullptr, 0, nullptr, 0, gk);
  k_bias2<<<dim3(256), dim3(256), 0, stream>>>(gk, Ws1, b2g);
  k_mm<1><<<dim3(64, 8), dim3(256), 0, stream>>>(xcatb, 512, 512, Ws1b,
      Ss1, Bs1, b2g, 512, nullptr, 0, h1b, 512, nullptr);
  k_mm<1><<<dim3(64, 4), dim3(256), 0, stream>>>(h1b, 512, 512, Ws2b,
      Ss2, Bs2, nullptr, 256, Tbuf, 256, nullptr, 0, nullptr);
  k_out<<<dim3(512), dim3(256), 0, stream>>>(Tbuf, Ws3, Bs3, (float*)d_out);
}

// Round 16
// 913.136 us; speedup vs baseline: 1.1750x; 1.0701x over previous
//
#include <hip/hip_runtime.h>
#include <hip/hip_bf16.h>

// DGCNN_Seg forward. B=2, N=4096, K=20. fp32 in/out.
// Round 16: symmetric k_dist with BARRIER-FREE mirror (direct register->global
// transposed stores; R15's LDS strip-transpose cost 8 barriers + 28 VGPRs and
// killed occupancy 35%->15%). Values bit-identical (commutative operands).
// Rest = R15 (977us, absmax 0.01171875).

#define DEVI static __device__ __forceinline__
typedef __attribute__((ext_vector_type(8))) short bf16x8;   // 8 bf16 = 4 VGPR
typedef __attribute__((ext_vector_type(4))) float f32x4;    // MFMA acc
typedef unsigned long long ull;

DEVI float lrelu(float y) { return y > 0.f ? y : 0.2f * y; }
DEVI unsigned okey(float f) {
  unsigned u = __float_as_uint(f);
  return (f < 0.f) ? ~u : (u | 0x80000000u);
}
DEVI float dekey(unsigned k) {
  return __uint_as_float((k & 0x80000000u) ? (k & 0x7fffffffu) : ~k);
}

// ---------------- weight fp32 -> bf16 pack ----------------
__global__ __launch_bounds__(64) void k_conv(const float* __restrict__ src, int lds, int off,
                                             int sub, int Kc, __hip_bfloat16* __restrict__ dst) {
  int o = blockIdx.x, c = blockIdx.y * 64 + threadIdx.x;
  float v = src[(size_t)o * lds + off + c];
  if (sub) v -= src[(size_t)o * lds + c];
  dst[(size_t)o * Kc + c] = __float2bfloat16(v);
}

// ---------------- row squared-norms: one wave per row ----------------
__global__ __launch_bounds__(256) void k_xx(const float* __restrict__ F, int ldf, int C,
                                            float* __restrict__ xx) {
  int lane = threadIdx.x & 63;
  int row = blockIdx.x * 4 + (threadIdx.x >> 6);
  const float* f = F + (size_t)row * ldf;
  float s = 0.f;
  for (int c = lane; c < C; c += 64) { float v = f[c]; s += v * v; }
#pragma unroll
  for (int off = 32; off; off >>= 1) s += __shfl_xor(s, off, 64);
  if (lane == 0) xx[row] = s;
}

// ---------------- pairwise distances v5: 128x128 tile, 8x8/thread ----------------
// sym=1 (big2): triangular tile decode, batch=blockIdx.z; off-diagonal tiles
// write the mirrored block directly from registers (no LDS, no barriers).
// Stores okey(d) u32. Per-element fmaf order identical -> bit-identical.
__global__ __launch_bounds__(256) void k_dist(const float* __restrict__ F, int ldf, int C,
                                              const float* __restrict__ xx,
                                              unsigned* __restrict__ D, int bfix, int ibase,
                                              int sym) {
  __shared__ __align__(16) float As[16][132];
  __shared__ __align__(16) float Bs[16][132];
  const int tid = threadIdx.x;
  const int tx = tid & 15, ty = tid >> 4;
  int bi, bj;
  if (sym) {
    int t = blockIdx.x, r = 32;
    bi = 0;
    while (t >= r) { t -= r; ++bi; r = 32 - bi; }
    bj = bi + t;
  } else {
    bi = blockIdx.x;
    bj = blockIdx.y;
  }
  const int b = (bfix < 0) ? (int)blockIdx.z : bfix;
  unsigned* Db = (bfix < 0) ? (D + (size_t)b * 4096 * 4096) : D;
  const int i0 = ibase + bi * 128, j0 = bj * 128;
  const float* Fb = F + (size_t)b * 4096 * ldf;
  const float* xxb = xx + b * 4096;
  const int srow = tid >> 1, sq = (tid & 1) * 8;  // stage: 128 rows x 16 cols
  float acc[8][8] = {};
  for (int c0 = 0; c0 < C; c0 += 16) {
    if (C - c0 >= 16) {
      float4 a0 = *(const float4*)(Fb + (size_t)(i0 + srow) * ldf + c0 + sq);
      float4 a1 = *(const float4*)(Fb + (size_t)(i0 + srow) * ldf + c0 + sq + 4);
      As[sq + 0][srow] = a0.x; As[sq + 1][srow] = a0.y; As[sq + 2][srow] = a0.z; As[sq + 3][srow] = a0.w;
      As[sq + 4][srow] = a1.x; As[sq + 5][srow] = a1.y; As[sq + 6][srow] = a1.z; As[sq + 7][srow] = a1.w;
      float4 b0 = *(const float4*)(Fb + (size_t)(j0 + srow) * ldf + c0 + sq);
      float4 b1 = *(const float4*)(Fb + (size_t)(j0 + srow) * ldf + c0 + sq + 4);
      Bs[sq + 0][srow] = b0.x; Bs[sq + 1][srow] = b0.y; Bs[sq + 2][srow] = b0.z; Bs[sq + 3][srow] = b0.w;
      Bs[sq + 4][srow] = b1.x; Bs[sq + 5][srow] = b1.y; Bs[sq + 6][srow] = b1.z; Bs[sq + 7][srow] = b1.w;
    } else {
#pragma unroll
      for (int e = 0; e < 8; ++e) {
        int c = c0 + sq + e;
        As[sq + e][srow] = (c < C) ? Fb[(size_t)(i0 + srow) * ldf + c] : 0.f;
        Bs[sq + e][srow] = (c < C) ? Fb[(size_t)(j0 + srow) * ldf + c] : 0.f;
      }
    }
    __syncthreads();
#pragma unroll
    for (int kk = 0; kk < 16; ++kk) {
      const float4 al = *(const float4*)&As[kk][ty * 8];
      const float4 ah = *(const float4*)&As[kk][ty * 8 + 4];
      const float4 bl = *(const float4*)&Bs[kk][tx * 8];
      const float4 bh = *(const float4*)&Bs[kk][tx * 8 + 4];
      const float av[8] = {al.x, al.y, al.z, al.w, ah.x, ah.y, ah.z, ah.w};
      const float bv[8] = {bl.x, bl.y, bl.z, bl.w, bh.x, bh.y, bh.z, bh.w};
#pragma unroll
      for (int ii = 0; ii < 8; ++ii)
#pragma unroll
        for (int jj = 0; jj < 8; ++jj)
          acc[ii][jj] = fmaf(av[ii], bv[jj], acc[ii][jj]);
    }
    __syncthreads();
  }
  // normal block store
#pragma unroll
  for (int ii = 0; ii < 8; ++ii) {
    int i = i0 + ty * 8 + ii;
    float xi = xxb[i];
    uint4 o1, o2;
    o1.x = okey(xi + xxb[j0 + tx * 8 + 0] - 2.f * acc[ii][0]);
    o1.y = okey(xi + xxb[j0 + tx * 8 + 1] - 2.f * acc[ii][1]);
    o1.z = okey(xi + xxb[j0 + tx * 8 + 2] - 2.f * acc[ii][2]);
    o1.w = okey(xi + xxb[j0 + tx * 8 + 3] - 2.f * acc[ii][3]);
    o2.x = okey(xi + xxb[j0 + tx * 8 + 4] - 2.f * acc[ii][4]);
    o2.y = okey(xi + xxb[j0 + tx * 8 + 5] - 2.f * acc[ii][5]);
    o2.z = okey(xi + xxb[j0 + tx * 8 + 6] - 2.f * acc[ii][6]);
    o2.w = okey(xi + xxb[j0 + tx * 8 + 7] - 2.f * acc[ii][7]);
    *(uint4*)&Db[(size_t)(i - ibase) * 4096 + j0 + tx * 8] = o1;
    *(uint4*)&Db[(size_t)(i - ibase) * 4096 + j0 + tx * 8 + 4] = o2;
  }
  // mirror block store (sym, off-diagonal): direct register->global transposed.
  // Value = xxb[col] + xxb[row] - 2*acc (commutative ops -> bit-identical to
  // what a direct compute of that entry would produce).
  if (sym && bi < bj) {
#pragma unroll
    for (int jj = 0; jj < 8; ++jj) {
      const float xj = xxb[j0 + tx * 8 + jj];
      uint4 m1, m2;
      m1.x = okey(xxb[i0 + ty * 8 + 0] + xj - 2.f * acc[0][jj]);
      m1.y = okey(xxb[i0 + ty * 8 + 1] + xj - 2.f * acc[1][jj]);
      m1.z = okey(xxb[i0 + ty * 8 + 2] + xj - 2.f * acc[2][jj]);
      m1.w = okey(xxb[i0 + ty * 8 + 3] + xj - 2.f * acc[3][jj]);
      m2.x = okey(xxb[i0 + ty * 8 + 4] + xj - 2.f * acc[4][jj]);
      m2.y = okey(xxb[i0 + ty * 8 + 5] + xj - 2.f * acc[5][jj]);
      m2.z = okey(xxb[i0 + ty * 8 + 6] + xj - 2.f * acc[6][jj]);
      m2.w = okey(xxb[i0 + ty * 8 + 7] + xj - 2.f * acc[7][jj]);
      unsigned* dst = &Db[(size_t)(j0 + tx * 8 + jj) * 4096 + i0 + ty * 8];
      *(uint4*)(dst + 0) = m1;
      *(uint4*)(dst + 4) = m2;
    }
  }
}

// ---------------- top-20 v5: 1 block (4 waves) per row ----------------
__global__ __launch_bounds__(256) void k_topk(const unsigned* __restrict__ Dk,
                                              int* __restrict__ idx, int bfix, int ibase) {
  __shared__ ull cand[4][20];
  const int tid = threadIdx.x, lane = tid & 63, wv = tid >> 6;
  const int ir_ = blockIdx.x;
  const int b = (bfix < 0) ? (int)blockIdx.y : bfix;
  const unsigned* drow = Dk + ((bfix < 0) ? (size_t)b * 4096 * 4096 : 0) + (size_t)ir_ * 4096;
  const int base = wv * 1024 + lane;
  unsigned key[16];
#pragma unroll
  for (int it = 0; it < 16; ++it) key[it] = drow[base + it * 64];
  unsigned m1k = 0xFFFFFFFFu, m2k = 0xFFFFFFFFu, m3k = 0xFFFFFFFFu;
  int m1p = 0, m2p = 0, m3p = 0;
#pragma unroll
  for (int it = 0; it < 16; ++it) {
    unsigned v = key[it];
    bool b1 = v < m1k, b2 = v < m2k, b3 = v < m3k;
    m3k = b2 ? m2k : (b3 ? v : m3k);
    m3p = b2 ? m2p : (b3 ? it : m3p);
    m2k = b1 ? m1k : (b2 ? v : m2k);
    m2p = b1 ? m1p : (b2 ? it : m2p);
    m1k = b1 ? v : m1k;
    m1p = b1 ? it : m1p;
  }
  unsigned consumed = (1u << m1p) | (1u << m2p) | (1u << m3p);
  unsigned ck = m1k, cp = (unsigned)(lane | (m1p << 6));
  unsigned n1k = m2k, n1p = (unsigned)(lane | (m2p << 6));
  unsigned n2k = m3k, n2p = (unsigned)(lane | (m3p << 6));
  for (int r = 0; r < 20; ++r) {
    unsigned mh = ck;
#pragma unroll
    for (int off = 32; off; off >>= 1) {
      unsigned o = __shfl_xor(mh, off, 64);
      mh = o < mh ? o : mh;
    }
    unsigned lo2 = (ck == mh) ? cp : 0xFFFFFFFFu;
    unsigned ml = lo2;
#pragma unroll
    for (int off = 32; off; off >>= 1) {
      unsigned o = __shfl_xor(ml, off, 64);
      ml = o < ml ? o : ml;
    }
    if (lane == 0) cand[wv][r] = ((ull)mh << 32) | (unsigned)(wv * 1024 + ml);
    bool pop = (ck == mh) && (cp == ml);
    ck = pop ? n1k : ck;  cp = pop ? n1p : cp;
    n1k = pop ? n2k : n1k; n1p = pop ? n2p : n1p;
    n2k = pop ? 0xFFFFFFFFu : n2k;
    if (ck == 0xFFFFFFFFu) {  // rare: lane popped >=3 times; refill from regs
      unsigned bk = 0xFFFFFFFFu; int bp = 0;
#pragma unroll
      for (int it2 = 0; it2 < 16; ++it2) {
        bool ok = ((consumed >> it2) & 1u) == 0u;
        unsigned v = ok ? key[it2] : 0xFFFFFFFFu;
        bool t = v < bk;
        bk = t ? v : bk;
        bp = t ? it2 : bp;
      }
      consumed |= (1u << bp);
      ck = bk;
      cp = (unsigned)(lane | (bp << 6));
    }
  }
  __syncthreads();
  if (tid == 0) {
    int* op = idx + ((size_t)b * 4096 + ibase + ir_) * 20;
    int p0 = 0, p1 = 0, p2 = 0, p3 = 0;
    for (int r = 0; r < 20; ++r) {
      ull v0 = cand[0][p0], v1 = cand[1][p1], v2 = cand[2][p2], v3 = cand[3][p3];
      ull m01 = v0 < v1 ? v0 : v1;
      ull m23 = v2 < v3 ? v2 : v3;
      ull best = m01 < m23 ? m01 : m23;
      if (best == v0) ++p0; else if (best == v1) ++p1;
      else if (best == v2) ++p2; else ++p3;
      op[r] = (int)(best & 0xfffull);
      if (p0 > 19) p0 = 19;
      if (p1 > 19) p1 = 19;
      if (p2 > 19) p2 = 19;
      if (p3 > 19) p3 = 19;
    }
  }
}

// ---------------- EdgeConv layer 1 (fp32, Cin=3): one wave per point ----------------
__global__ __launch_bounds__(256) void k_edge1(const float* __restrict__ xf,
                                               const float* __restrict__ W1,
                                               const float* __restrict__ s1,
                                               const float* __restrict__ b1,
                                               const int* __restrict__ idx,
                                               float* __restrict__ xcat,
                                               __hip_bfloat16* __restrict__ xcatb) {
  const int lane = threadIdx.x & 63;
  const int p = blockIdx.x * 4 + (threadIdx.x >> 6);
  const int bb = p >> 12;
  float wl[3], wr[3];
#pragma unroll
  for (int c = 0; c < 3; ++c) {
    wl[c] = W1[lane * 6 + c];
    wr[c] = W1[lane * 6 + 3 + c];
  }
  const float s = s1[lane], bi = b1[lane];
  const float* xc = xf + (size_t)p * 3;
  const float x0 = xc[0], x1 = xc[1], x2 = xc[2];
  const float t = x0 * (wr[0] - wl[0]) + x1 * (wr[1] - wl[1]) + x2 * (wr[2] - wl[2]);
  const int* ir = idx + (size_t)p * 20;
  float best = -INFINITY;
  for (int k = 0; k < 20; ++k) {
    int j = ir[k];
    const float* xn = xf + ((size_t)(bb << 12) + j) * 3;
    float y = t + xn[0] * wl[0] + xn[1] * wl[1] + xn[2] * wl[2];
    y = lrelu(y * s + bi);
    best = fmaxf(best, y);
  }
  xcat[(size_t)p * 512 + lane] = best;
  xcatb[(size_t)p * 512 + lane] = __float2bfloat16(best);
}

// ---------------- fp32 pointwise GEMM, raw store (T for layers 2-3) ----------------
__global__ __launch_bounds__(256) void k_pwT(const float* __restrict__ A, int lda, int K,
                                             const float* __restrict__ W, int ldw, int wsub,
                                             float* __restrict__ out, int ldo) {
  __shared__ __align__(16) float As[16][68];
  __shared__ __align__(16) float Bs[16][68];
  const int tid = threadIdx.x;
  const int tx = tid & 15, ty = tid >> 4;
  const int i0 = blockIdx.x * 64, o0 = blockIdx.y * 64;
  const int row = tid >> 2, q = (tid & 3) * 4;
  float acc[4][4] = {};
  for (int c0 = 0; c0 < K; c0 += 16) {
    float4 a = *(const float4*)(A + (size_t)(i0 + row) * lda + c0 + q);
    As[q + 0][row] = a.x; As[q + 1][row] = a.y; As[q + 2][row] = a.z; As[q + 3][row] = a.w;
    const float* wp = W + (size_t)(o0 + row) * ldw + c0 + q;
#pragma unroll
    for (int e = 0; e < 4; ++e) Bs[q + e][row] = wp[wsub + e] - wp[e];
    __syncthreads();
#pragma unroll
    for (int kk = 0; kk < 16; ++kk) {
      const float4 a4 = *(const float4*)&As[kk][ty * 4];
      const float4 b4 = *(const float4*)&Bs[kk][tx * 4];
      const float av[4] = {a4.x, a4.y, a4.z, a4.w};
      const float bv[4] = {b4.x, b4.y, b4.z, b4.w};
#pragma unroll
      for (int ii = 0; ii < 4; ++ii)
#pragma unroll
        for (int jj = 0; jj < 4; ++jj)
          acc[ii][jj] = fmaf(av[ii], bv[jj], acc[ii][jj]);
    }
    __syncthreads();
  }
#pragma unroll
  for (int ii = 0; ii < 4; ++ii)
#pragma unroll
    for (int jj = 0; jj < 4; ++jj)
      out[(size_t)(i0 + ty * 4 + ii) * ldo + o0 + tx * 4 + jj] = acc[ii][jj];
}

// ---------------- fp32 EdgeConv GEMM (layers 2-3; feeds kNN, stays exact) ----------------
__global__ __launch_bounds__(256) void k_edge(const float* __restrict__ F, int ldf, int Cin,
                                              const float* __restrict__ W,
                                              const float* __restrict__ sc,
                                              const float* __restrict__ bi,
                                              const int* __restrict__ idx,
                                              const float* __restrict__ T, int ldt,
                                              float* __restrict__ out,
                                              __hip_bfloat16* __restrict__ outb) {
  __shared__ float As[16][81];
  __shared__ __align__(16) float Bs[16][68];
  __shared__ float Ys[80][65];
  const int tid = threadIdx.x;
  const int tx = tid & 15, ty = tid >> 4;
  const int r0 = blockIdx.x * 80;
  const int o0 = blockIdx.y * 64;
  const int ldw = 2 * Cin;
  int grow[5], gcol[5];
#pragma unroll
  for (int l = 0; l < 5; ++l) {
    int e = tid + l * 256;
    int rr = e >> 4;
    gcol[l] = e & 15;
    int gr = r0 + rr;
    int p = gr / 20;
    int j = idx[(size_t)p * 20 + (gr % 20)];
    grow[l] = ((p >> 12) << 12) + j;
  }
  float acc[5][4] = {};
  const int wrow = tid >> 2, wq = (tid & 3) * 4;
  for (int c0 = 0; c0 < Cin; c0 += 16) {
#pragma unroll
    for (int l = 0; l < 5; ++l) {
      int e = tid + l * 256;
      As[gcol[l]][e >> 4] = F[(size_t)grow[l] * ldf + c0 + gcol[l]];
    }
    {
      const float* wp = W + (size_t)(o0 + wrow) * ldw + c0 + wq;
#pragma unroll
      for (int e = 0; e < 4; ++e) Bs[wq + e][wrow] = wp[e];
    }
    __syncthreads();
#pragma unroll
    for (int kk = 0; kk < 16; ++kk) {
      float a[5];
#pragma unroll
      for (int l = 0; l < 5; ++l) a[l] = As[kk][ty + l * 16];
      const float4 b4 = *(const float4*)&Bs[kk][tx * 4];
      const float bv[4] = {b4.x, b4.y, b4.z, b4.w};
#pragma unroll
      for (int l = 0; l < 5; ++l)
#pragma unroll
        for (int jj = 0; jj < 4; ++jj)
          acc[l][jj] = fmaf(a[l], bv[jj], acc[l][jj]);
    }
    __syncthreads();
  }
#pragma unroll
  for (int l = 0; l < 5; ++l) {
    int r = ty + l * 16;
    int p = (r0 + r) / 20;
#pragma unroll
    for (int jj = 0; jj < 4; ++jj) {
      int o = o0 + tx * 4 + jj;
      float y = (acc[l][jj] + T[(size_t)p * ldt + o]) * sc[o] + bi[o];
      Ys[r][tx * 4 + jj] = lrelu(y);
    }
  }
  __syncthreads();
  const int grp = tid >> 6, col = tid & 63;
  float m = -INFINITY;
#pragma unroll
  for (int k = 0; k < 20; ++k) m = fmaxf(m, Ys[grp * 20 + k][col]);
  const int p = blockIdx.x * 4 + grp;
  out[(size_t)p * 512 + o0 + col] = m;
  outb[(size_t)p * 512 + o0 + col] = __float2bfloat16(m);
}

// ---------------- MFMA bf16 GEMM: block 128(M)x64(N), 4 waves x (32x64) ----------------
template <int EPI>
__global__ __launch_bounds__(256) void k_mm(
    const __hip_bfloat16* __restrict__ A, int lda, int K,
    const __hip_bfloat16* __restrict__ B,  // [N][K] bf16
    const float* __restrict__ sc, const float* __restrict__ bi,
    const float* __restrict__ extra, int Ncols,
    float* __restrict__ outf, int ldof,
    __hip_bfloat16* __restrict__ outb, int ldob,
    unsigned* __restrict__ gmax) {
  __shared__ __align__(16) __hip_bfloat16 Al[128 * 40];
  __shared__ __align__(16) __hip_bfloat16 Bl[64 * 40];
  __shared__ float Red[4][64];
  const int tid = threadIdx.x, lane = tid & 63, wv = tid >> 6;
  const int m0 = blockIdx.x * 128, n0 = blockIdx.y * 64;
  const int arow = tid >> 2, akc = (tid & 3) * 8;
  const int fm = lane & 15, fq = lane >> 4;
  f32x4 acc[2][4];
#pragma unroll
  for (int mt = 0; mt < 2; ++mt)
#pragma unroll
    for (int nt = 0; nt < 4; ++nt) acc[mt][nt] = (f32x4){0.f, 0.f, 0.f, 0.f};
  for (int c0 = 0; c0 < K; c0 += 32) {
#pragma unroll
    for (int l = 0; l < 2; ++l) {
      int r = arow + l * 64;
      *(float4*)&Al[r * 40 + akc] = *(const float4*)(A + (size_t)(m0 + r) * lda + c0 + akc);
    }
    *(float4*)&Bl[arow * 40 + akc] = *(const float4*)(B + (size_t)(n0 + arow) * K + c0 + akc);
    __syncthreads();
    bf16x8 af[2], bfr[4];
#pragma unroll
    for (int mt = 0; mt < 2; ++mt)
      af[mt] = *(const bf16x8*)&Al[(wv * 32 + mt * 16 + fm) * 40 + fq * 8];
#pragma unroll
    for (int nt = 0; nt < 4; ++nt)
      bfr[nt] = *(const bf16x8*)&Bl[(nt * 16 + fm) * 40 + fq * 8];
#pragma unroll
    for (int mt = 0; mt < 2; ++mt)
#pragma unroll
      for (int nt = 0; nt < 4; ++nt)
        acc[mt][nt] = __builtin_amdgcn_mfma_f32_16x16x32_bf16(af[mt], bfr[nt], acc[mt][nt], 0, 0, 0);
    __syncthreads();
  }
  const int bidx = m0 >> 12;
  if (EPI == 0) {
#pragma unroll
    for (int mt = 0; mt < 2; ++mt)
#pragma unroll
      for (int nt = 0; nt < 4; ++nt)
#pragma unroll
        for (int r = 0; r < 4; ++r)
          outf[(size_t)(m0 + wv * 32 + mt * 16 + fq * 4 + r) * ldof + n0 + nt * 16 + fm] =
              acc[mt][nt][r];
  } else if (EPI == 1) {
#pragma unroll
    for (int nt = 0; nt < 4; ++nt) {
      int col = n0 + nt * 16 + fm;
      float s = sc[col], bb = bi[col];
      float ex = extra ? extra[bidx * Ncols + col] : 0.f;
#pragma unroll
      for (int mt = 0; mt < 2; ++mt)
#pragma unroll
        for (int r = 0; r < 4; ++r) {
          float v = lrelu((acc[mt][nt][r] + ex) * s + bb);
          size_t rr = (size_t)(m0 + wv * 32 + mt * 16 + fq * 4 + r);
          if (outf) outf[rr * ldof + col] = v;
          if (outb) outb[rr * ldob + col] = __float2bfloat16(v);
        }
    }
  } else {
#pragma unroll
    for (int nt = 0; nt < 4; ++nt) {
      int col = n0 + nt * 16 + fm;
      float s = sc[col], bb = bi[col];
      float m = -INFINITY;
#pragma unroll
      for (int mt = 0; mt < 2; ++mt)
#pragma unroll
        for (int r = 0; r < 4; ++r) m = fmaxf(m, lrelu(acc[mt][nt][r] * s + bb));
      m = fmaxf(m, __shfl_xor(m, 16, 64));
      m = fmaxf(m, __shfl_xor(m, 32, 64));
      if (fq == 0) Red[wv][nt * 16 + fm] = m;
    }
    __syncthreads();
    if (tid < 64) {
      float m = fmaxf(fmaxf(Red[0][tid], Red[1][tid]), fmaxf(Red[2][tid], Red[3][tid]));
      atomicMax(&gmax[bidx * Ncols + n0 + tid], okey(m));
    }
  }
}

// ---------------- MFMA bf16 EdgeConv (layer 4): 320 edges x 64 cols / block ----------------
__global__ __launch_bounds__(256) void k_edgem(
    const __hip_bfloat16* __restrict__ F, int ldf, int coff, int K,
    const __hip_bfloat16* __restrict__ Wl,  // [N][K] bf16
    const float* __restrict__ sc, const float* __restrict__ bi,
    const float* __restrict__ T, int N,
    const int* __restrict__ idx,
    float* __restrict__ outf, __hip_bfloat16* __restrict__ outb) {
  __shared__ __align__(16) char smem[320 * 66 * 2];  // 42240 B, overlaid stage/Ys
  __hip_bfloat16* Al = (__hip_bfloat16*)smem;              // 320*40
  __hip_bfloat16* Bl = (__hip_bfloat16*)(smem + 25600);    // 64*40
  __hip_bfloat16* Ys = (__hip_bfloat16*)smem;              // 320*66 (post-loop)
  const int tid = threadIdx.x, lane = tid & 63, wv = tid >> 6;
  const int blk = blockIdx.x, n0 = blockIdx.y * 64;
  const int arow = tid >> 2, akc = (tid & 3) * 8;
  const int fm = lane & 15, fq = lane >> 4;
  const __hip_bfloat16* ap[5];
#pragma unroll
  for (int l = 0; l < 5; ++l) {
    int row = arow + l * 64;
    int e = blk * 320 + row;
    int p = e / 20;
    int j = idx[(size_t)p * 20 + (e - p * 20)];
    int src = ((p >> 12) << 12) + j;
    ap[l] = F + (size_t)src * ldf + coff + akc;
  }
  f32x4 acc[5][4];
#pragma unroll
  for (int l = 0; l < 5; ++l)
#pragma unroll
    for (int nt = 0; nt < 4; ++nt) acc[l][nt] = (f32x4){0.f, 0.f, 0.f, 0.f};
  for (int c0 = 0; c0 < K; c0 += 32) {
#pragma unroll
    for (int l = 0; l < 5; ++l)
      *(float4*)&Al[(arow + l * 64) * 40 + akc] = *(const float4*)(ap[l] + c0);
    *(float4*)&Bl[arow * 40 + akc] = *(const float4*)(Wl + (size_t)(n0 + arow) * K + c0 + akc);
    __syncthreads();
    bf16x8 af[5], bfr[4];
#pragma unroll
    for (int l = 0; l < 5; ++l)
      af[l] = *(const bf16x8*)&Al[(wv * 80 + l * 16 + fm) * 40 + fq * 8];
#pragma unroll
    for (int nt = 0; nt < 4; ++nt)
      bfr[nt] = *(const bf16x8*)&Bl[(nt * 16 + fm) * 40 + fq * 8];
#pragma unroll
    for (int l = 0; l < 5; ++l)
#pragma unroll
      for (int nt = 0; nt < 4; ++nt)
        acc[l][nt] = __builtin_amdgcn_mfma_f32_16x16x32_bf16(af[l], bfr[nt], acc[l][nt], 0, 0, 0);
    __syncthreads();
  }
#pragma unroll
  for (int l = 0; l < 5; ++l)
#pragma unroll
    for (int nt = 0; nt < 4; ++nt)
#pragma unroll
      for (int r = 0; r < 4; ++r)
        Ys[(wv * 80 + l * 16 + fq * 4 + r) * 66 + nt * 16 + fm] = __float2bfloat16(acc[l][nt][r]);
  __syncthreads();
  const int col = tid & 63;
#pragma unroll
  for (int gi = 0; gi < 4; ++gi) {
    int grp = wv + gi * 4;
    float m = -INFINITY;
#pragma unroll
    for (int k = 0; k < 20; ++k)
      m = fmaxf(m, __bfloat162float(Ys[(grp * 20 + k) * 66 + col]));
    int p = blk * 16 + grp;
    int o = n0 + col;
    float v = lrelu((m + T[(size_t)p * N + o]) * sc[o] + bi[o]);
    outf[(size_t)p * 512 + o] = v;
    outb[(size_t)p * 512 + o] = __float2bfloat16(v);
  }
}

// ---------------- bias2: one wave per (b,o) ----------------
__global__ __launch_bounds__(256) void k_bias2(const unsigned* __restrict__ gk,
                                               const float* __restrict__ Ws1,
                                               float* __restrict__ b2g) {
  const int lane = threadIdx.x & 63;
  const int wid = (blockIdx.x * 256 + threadIdx.x) >> 6;  // 0..1023
  const int b = wid >> 9, o = wid & 511;
  const float* wr = Ws1 + (size_t)o * 1536 + 512;
  const unsigned* g = gk + b * 1024;
  float acc = 0.f;
#pragma unroll
  for (int c = lane; c < 1024; c += 64) acc = fmaf(dekey(g[c]), wr[c], acc);
#pragma unroll
  for (int off = 32; off; off >>= 1) acc += __shfl_xor(acc, off, 64);
  if (lane == 0) b2g[b * 512 + o] = acc;
}

// ---------------- final head: out = H(8192x256) . Ws3^T + bs3 (fp32) ----------------
__global__ __launch_bounds__(256) void k_out(const float* __restrict__ H,
                                             const float* __restrict__ Ws3,
                                             const float* __restrict__ bs3,
                                             float* __restrict__ out) {
  __shared__ float Ws[13][256];
  const int tid = threadIdx.x;
  for (int e = tid; e < 13 * 256; e += 256) Ws[e >> 8][e & 255] = Ws3[e];
  __syncthreads();
  const int rloc = tid >> 4, o = tid & 15;
  const int row = blockIdx.x * 16 + rloc;
  if (o < 13) {
    const float* h = H + (size_t)row * 256;
    float acc = 0.f;
    for (int c = 0; c < 256; ++c) acc = fmaf(h[c], Ws[o][c], acc);
    out[(size_t)row * 13 + o] = acc + bs3[o];
  }
}

extern "C" void kernel_launch(void* const* d_in, const int* in_sizes, int n_in,
                              void* d_out, int out_size, void* d_ws, size_t ws_size,
                              hipStream_t stream) {
  const float* X   = (const float*)d_in[0];
  const float* W1  = (const float*)d_in[1];
  const float* S1  = (const float*)d_in[2];
  const float* B1  = (const float*)d_in[3];
  const float* W2  = (const float*)d_in[4];
  const float* S2  = (const float*)d_in[5];
  const float* B2  = (const float*)d_in[6];
  const float* W3  = (const float*)d_in[7];
  const float* S3  = (const float*)d_in[8];
  const float* B3  = (const float*)d_in[9];
  const float* W4  = (const float*)d_in[10];
  const float* S4  = (const float*)d_in[11];
  const float* B4  = (const float*)d_in[12];
  const float* Wg  = (const float*)d_in[13];
  const float* Sg  = (const float*)d_in[14];
  const float* Bg  = (const float*)d_in[15];
  const float* Ws1 = (const float*)d_in[16];
  const float* Ss1 = (const float*)d_in[17];
  const float* Bs1 = (const float*)d_in[18];
  const float* Ws2 = (const float*)d_in[19];
  const float* Ss2 = (const float*)d_in[20];
  const float* Bs2 = (const float*)d_in[21];
  const float* Ws3 = (const float*)d_in[22];
  const float* Bs3 = (const float*)d_in[23];

  char* ws = (char*)d_ws;
  float*           xxb   = (float*)(ws + 0);            // 32 KB
  int*             idxb  = (int*)(ws + 32768);          // 640 KB
  unsigned*        gk    = (unsigned*)(ws + 688128);    // 8 KB
  float*           b2g   = (float*)(ws + 696320);       // 4 KB
  __hip_bfloat16*  Wgb   = (__hip_bfloat16*)(ws + 1048576);  // 1 MB
  __hip_bfloat16*  Ws1b  = (__hip_bfloat16*)(ws + 2097152);  // 512 KB
  __hip_bfloat16*  Ws2b  = (__hip_bfloat16*)(ws + 2621440);  // 256 KB
  __hip_bfloat16*  Wlb4  = (__hip_bfloat16*)(ws + 2883584);  // 64 KB
  __hip_bfloat16*  Wdb4  = (__hip_bfloat16*)(ws + 2949120);  // 64 KB
  __hip_bfloat16*  xcatb = (__hip_bfloat16*)(ws + 3145728);  // 8 MB
  float*           xcat  = (float*)(ws + 11534336);          // 16 MB
  char*            region = ws + 28311552;                   // dist / Tbuf+h1b
  unsigned*        dist  = (unsigned*)(region);
  float*           Tbuf  = (float*)(region);
  __hip_bfloat16*  h1b   = (__hip_bfloat16*)(region + 8388608);

  // dist buffer variants: both batches (128MB) > one batch (64MB) > chunked (16MB)
  const bool big2 = (ws_size >= (size_t)28311552 + (128u << 20));
  const bool big1 = (ws_size >= (size_t)28311552 + (64u << 20));

  hipMemsetAsync(gk, 0, 2 * 1024 * sizeof(unsigned), stream);

  // weight bf16 packs (L4 + head only; L1-L3 weights stay fp32)
  k_conv<<<dim3(256, 2), dim3(64), 0, stream>>>(W4, 256, 0, 0, 128, Wlb4);
  k_conv<<<dim3(256, 2), dim3(64), 0, stream>>>(W4, 256, 128, 1, 128, Wdb4);
  k_conv<<<dim3(1024, 8), dim3(64), 0, stream>>>(Wg, 512, 0, 0, 512, Wgb);
  k_conv<<<dim3(512, 8), dim3(64), 0, stream>>>(Ws1, 1536, 0, 0, 512, Ws1b);
  k_conv<<<dim3(256, 8), dim3(64), 0, stream>>>(Ws2, 512, 0, 0, 512, Ws2b);

  // kNN for one layer (fills idxb); selection bit-identical in all paths
  auto run_knn = [&](const float* F, int ldf, int C) {
    k_xx<<<dim3(2048), dim3(256), 0, stream>>>(F, ldf, C, xxb);
    if (big2) {
      k_dist<<<dim3(528, 1, 2), dim3(256), 0, stream>>>(F, ldf, C, xxb, dist, -1, 0, 1);
      k_topk<<<dim3(4096, 2), dim3(256), 0, stream>>>(dist, idxb, -1, 0);
    } else if (big1) {
      for (int b = 0; b < 2; ++b) {
        k_dist<<<dim3(32, 32), dim3(256), 0, stream>>>(F, ldf, C, xxb, dist, b, 0, 0);
        k_topk<<<dim3(4096), dim3(256), 0, stream>>>(dist, idxb, b, 0);
      }
    } else {
      for (int b = 0; b < 2; ++b)
        for (int c = 0; c < 4; ++c) {
          k_dist<<<dim3(8, 32), dim3(256), 0, stream>>>(F, ldf, C, xxb, dist, b, c * 1024, 0);
          k_topk<<<dim3(1024), dim3(256), 0, stream>>>(dist, idxb, b, c * 1024);
        }
    }
  };

  // ---- Layer 1 (C=3 -> 64, fp32 exact) ----
  run_knn(X, 3, 3);
  k_edge1<<<dim3(2048), dim3(256), 0, stream>>>(X, W1, S1, B1, idxb, xcat, xcatb);

  // ---- Layer 2 (64 -> 64), fp32 (feeds kNN — must stay exact, R9 proved it) ----
  run_knn(xcat, 512, 64);
  k_pwT<<<dim3(128, 1), dim3(256), 0, stream>>>(xcat, 512, 64, W2, 128, 64, Tbuf, 64);
  k_edge<<<dim3(2048, 1), dim3(256), 0, stream>>>(xcat, 512, 64, W2, S2, B2,
      idxb, Tbuf, 64, xcat + 64, xcatb + 64);

  // ---- Layer 3 (64 -> 128), fp32 (feeds kNN) ----
  run_knn(xcat + 64, 512, 64);
  k_pwT<<<dim3(128, 2), dim3(256), 0, stream>>>(xcat + 64, 512, 64, W3, 128, 64, Tbuf, 128);
  k_edge<<<dim3(2048, 2), dim3(256), 0, stream>>>(xcat + 64, 512, 64, W3, S3, B3,
      idxb, Tbuf, 128, xcat + 128, xcatb + 128);

  // ---- Layer 4 (128 -> 256), bf16 MFMA (x4 feeds nothing discrete) ----
  run_knn(xcat + 128, 512, 128);
  k_mm<0><<<dim3(64, 4), dim3(256), 0, stream>>>(xcatb + 128, 512, 128, Wdb4,
      nullptr, nullptr, nullptr, 256, Tbuf, 256, nullptr, 0, nullptr);
  k_edgem<<<dim3(512, 4), dim3(256), 0, stream>>>(xcatb, 512, 128, 128, Wlb4,
      S4, B4, Tbuf, 256, idxb, xcat + 256, xcatb + 256);

  // ---- head (all bf16 MFMA) ----
  k_mm<2><<<dim3(64, 16), dim3(256), 0, stream>>>(xcatb, 512, 512, Wgb,
      Sg, Bg, nullptr, 1024, nullptr, 0, nullptr, 0, gk);
  k_bias2<<<dim3(256), dim3(256), 0, stream>>>(gk, Ws1, b2g);
  k_mm<1><<<dim3(64, 8), dim3(256), 0, stream>>>(xcatb, 512, 512, Ws1b,
      Ss1, Bs1, b2g, 512, nullptr, 0, h1b, 512, nullptr);
  k_mm<1><<<dim3(64, 4), dim3(256), 0, stream>>>(h1b, 512, 512, Ws2b,
      Ss2, Bs2, nullptr, 256, Tbuf, 256, nullptr, 0, nullptr);
  k_out<<<dim3(512), dim3(256), 0, stream>>>(Tbuf, Ws3, Bs3, (float*)d_out);
}

// Round 17
// 902.146 us; speedup vs baseline: 1.1893x; 1.0122x over previous
//
#include <hip/hip_runtime.h>
#include <hip/hip_bf16.h>

// DGCNN_Seg forward. B=2, N=4096, K=20. fp32 in/out.
// Round 17: k_topk v6 — contiguous per-lane candidates loaded as 4x uint4
// (16B/lane vs 4B scalar; 1KB/wave per load instr). Selection bit-identical:
// pop order is (okey, j) lexicographic; pos10 = lane*16+it IS the j-offset.
// Rest = R16 (913us, absmax 0.01171875).

#define DEVI static __device__ __forceinline__
typedef __attribute__((ext_vector_type(8))) short bf16x8;   // 8 bf16 = 4 VGPR
typedef __attribute__((ext_vector_type(4))) float f32x4;    // MFMA acc
typedef unsigned long long ull;

DEVI float lrelu(float y) { return y > 0.f ? y : 0.2f * y; }
DEVI unsigned okey(float f) {
  unsigned u = __float_as_uint(f);
  return (f < 0.f) ? ~u : (u | 0x80000000u);
}
DEVI float dekey(unsigned k) {
  return __uint_as_float((k & 0x80000000u) ? (k & 0x7fffffffu) : ~k);
}

// ---------------- weight fp32 -> bf16 pack ----------------
__global__ __launch_bounds__(64) void k_conv(const float* __restrict__ src, int lds, int off,
                                             int sub, int Kc, __hip_bfloat16* __restrict__ dst) {
  int o = blockIdx.x, c = blockIdx.y * 64 + threadIdx.x;
  float v = src[(size_t)o * lds + off + c];
  if (sub) v -= src[(size_t)o * lds + c];
  dst[(size_t)o * Kc + c] = __float2bfloat16(v);
}

// ---------------- row squared-norms: one wave per row ----------------
__global__ __launch_bounds__(256) void k_xx(const float* __restrict__ F, int ldf, int C,
                                            float* __restrict__ xx) {
  int lane = threadIdx.x & 63;
  int row = blockIdx.x * 4 + (threadIdx.x >> 6);
  const float* f = F + (size_t)row * ldf;
  float s = 0.f;
  for (int c = lane; c < C; c += 64) { float v = f[c]; s += v * v; }
#pragma unroll
  for (int off = 32; off; off >>= 1) s += __shfl_xor(s, off, 64);
  if (lane == 0) xx[row] = s;
}

// ---------------- pairwise distances v5: 128x128 tile, 8x8/thread ----------------
// sym=1 (big2): triangular tile decode, batch=blockIdx.z; off-diagonal tiles
// write the mirrored block directly from registers (no LDS, no barriers).
// Stores okey(d) u32. Per-element fmaf order identical -> bit-identical.
__global__ __launch_bounds__(256) void k_dist(const float* __restrict__ F, int ldf, int C,
                                              const float* __restrict__ xx,
                                              unsigned* __restrict__ D, int bfix, int ibase,
                                              int sym) {
  __shared__ __align__(16) float As[16][132];
  __shared__ __align__(16) float Bs[16][132];
  const int tid = threadIdx.x;
  const int tx = tid & 15, ty = tid >> 4;
  int bi, bj;
  if (sym) {
    int t = blockIdx.x, r = 32;
    bi = 0;
    while (t >= r) { t -= r; ++bi; r = 32 - bi; }
    bj = bi + t;
  } else {
    bi = blockIdx.x;
    bj = blockIdx.y;
  }
  const int b = (bfix < 0) ? (int)blockIdx.z : bfix;
  unsigned* Db = (bfix < 0) ? (D + (size_t)b * 4096 * 4096) : D;
  const int i0 = ibase + bi * 128, j0 = bj * 128;
  const float* Fb = F + (size_t)b * 4096 * ldf;
  const float* xxb = xx + b * 4096;
  const int srow = tid >> 1, sq = (tid & 1) * 8;  // stage: 128 rows x 16 cols
  float acc[8][8] = {};
  for (int c0 = 0; c0 < C; c0 += 16) {
    if (C - c0 >= 16) {
      float4 a0 = *(const float4*)(Fb + (size_t)(i0 + srow) * ldf + c0 + sq);
      float4 a1 = *(const float4*)(Fb + (size_t)(i0 + srow) * ldf + c0 + sq + 4);
      As[sq + 0][srow] = a0.x; As[sq + 1][srow] = a0.y; As[sq + 2][srow] = a0.z; As[sq + 3][srow] = a0.w;
      As[sq + 4][srow] = a1.x; As[sq + 5][srow] = a1.y; As[sq + 6][srow] = a1.z; As[sq + 7][srow] = a1.w;
      float4 b0 = *(const float4*)(Fb + (size_t)(j0 + srow) * ldf + c0 + sq);
      float4 b1 = *(const float4*)(Fb + (size_t)(j0 + srow) * ldf + c0 + sq + 4);
      Bs[sq + 0][srow] = b0.x; Bs[sq + 1][srow] = b0.y; Bs[sq + 2][srow] = b0.z; Bs[sq + 3][srow] = b0.w;
      Bs[sq + 4][srow] = b1.x; Bs[sq + 5][srow] = b1.y; Bs[sq + 6][srow] = b1.z; Bs[sq + 7][srow] = b1.w;
    } else {
#pragma unroll
      for (int e = 0; e < 8; ++e) {
        int c = c0 + sq + e;
        As[sq + e][srow] = (c < C) ? Fb[(size_t)(i0 + srow) * ldf + c] : 0.f;
        Bs[sq + e][srow] = (c < C) ? Fb[(size_t)(j0 + srow) * ldf + c] : 0.f;
      }
    }
    __syncthreads();
#pragma unroll
    for (int kk = 0; kk < 16; ++kk) {
      const float4 al = *(const float4*)&As[kk][ty * 8];
      const float4 ah = *(const float4*)&As[kk][ty * 8 + 4];
      const float4 bl = *(const float4*)&Bs[kk][tx * 8];
      const float4 bh = *(const float4*)&Bs[kk][tx * 8 + 4];
      const float av[8] = {al.x, al.y, al.z, al.w, ah.x, ah.y, ah.z, ah.w};
      const float bv[8] = {bl.x, bl.y, bl.z, bl.w, bh.x, bh.y, bh.z, bh.w};
#pragma unroll
      for (int ii = 0; ii < 8; ++ii)
#pragma unroll
        for (int jj = 0; jj < 8; ++jj)
          acc[ii][jj] = fmaf(av[ii], bv[jj], acc[ii][jj]);
    }
    __syncthreads();
  }
  // normal block store
#pragma unroll
  for (int ii = 0; ii < 8; ++ii) {
    int i = i0 + ty * 8 + ii;
    float xi = xxb[i];
    uint4 o1, o2;
    o1.x = okey(xi + xxb[j0 + tx * 8 + 0] - 2.f * acc[ii][0]);
    o1.y = okey(xi + xxb[j0 + tx * 8 + 1] - 2.f * acc[ii][1]);
    o1.z = okey(xi + xxb[j0 + tx * 8 + 2] - 2.f * acc[ii][2]);
    o1.w = okey(xi + xxb[j0 + tx * 8 + 3] - 2.f * acc[ii][3]);
    o2.x = okey(xi + xxb[j0 + tx * 8 + 4] - 2.f * acc[ii][4]);
    o2.y = okey(xi + xxb[j0 + tx * 8 + 5] - 2.f * acc[ii][5]);
    o2.z = okey(xi + xxb[j0 + tx * 8 + 6] - 2.f * acc[ii][6]);
    o2.w = okey(xi + xxb[j0 + tx * 8 + 7] - 2.f * acc[ii][7]);
    *(uint4*)&Db[(size_t)(i - ibase) * 4096 + j0 + tx * 8] = o1;
    *(uint4*)&Db[(size_t)(i - ibase) * 4096 + j0 + tx * 8 + 4] = o2;
  }
  // mirror block store (sym, off-diagonal): direct register->global transposed.
  if (sym && bi < bj) {
#pragma unroll
    for (int jj = 0; jj < 8; ++jj) {
      const float xj = xxb[j0 + tx * 8 + jj];
      uint4 m1, m2;
      m1.x = okey(xxb[i0 + ty * 8 + 0] + xj - 2.f * acc[0][jj]);
      m1.y = okey(xxb[i0 + ty * 8 + 1] + xj - 2.f * acc[1][jj]);
      m1.z = okey(xxb[i0 + ty * 8 + 2] + xj - 2.f * acc[2][jj]);
      m1.w = okey(xxb[i0 + ty * 8 + 3] + xj - 2.f * acc[3][jj]);
      m2.x = okey(xxb[i0 + ty * 8 + 4] + xj - 2.f * acc[4][jj]);
      m2.y = okey(xxb[i0 + ty * 8 + 5] + xj - 2.f * acc[5][jj]);
      m2.z = okey(xxb[i0 + ty * 8 + 6] + xj - 2.f * acc[6][jj]);
      m2.w = okey(xxb[i0 + ty * 8 + 7] + xj - 2.f * acc[7][jj]);
      unsigned* dst = &Db[(size_t)(j0 + tx * 8 + jj) * 4096 + i0 + ty * 8];
      *(uint4*)(dst + 0) = m1;
      *(uint4*)(dst + 4) = m2;
    }
  }
}

// ---------------- top-20 v6: 1 block (4 waves) per row ----------------
// Per lane: 16 CONTIGUOUS candidates (4x uint4 loads, 1KB/wave-instr);
// top-3 tournament; dual u32 min-tree extraction with pos10 = j-offset
// (lane*16+it). Pop order = (okey, j) lexicographic -> bit-identical.
__global__ __launch_bounds__(256) void k_topk(const unsigned* __restrict__ Dk,
                                              int* __restrict__ idx, int bfix, int ibase) {
  __shared__ ull cand[4][20];
  const int tid = threadIdx.x, lane = tid & 63, wv = tid >> 6;
  const int ir_ = blockIdx.x;
  const int b = (bfix < 0) ? (int)blockIdx.y : bfix;
  const unsigned* drow = Dk + ((bfix < 0) ? (size_t)b * 4096 * 4096 : 0) + (size_t)ir_ * 4096;
  const int base = wv * 1024 + lane * 16;
  unsigned key[16];
  {
    uint4 k0 = *(const uint4*)&drow[base + 0];
    uint4 k1 = *(const uint4*)&drow[base + 4];
    uint4 k2 = *(const uint4*)&drow[base + 8];
    uint4 k3 = *(const uint4*)&drow[base + 12];
    key[0] = k0.x; key[1] = k0.y; key[2] = k0.z; key[3] = k0.w;
    key[4] = k1.x; key[5] = k1.y; key[6] = k1.z; key[7] = k1.w;
    key[8] = k2.x; key[9] = k2.y; key[10] = k2.z; key[11] = k2.w;
    key[12] = k3.x; key[13] = k3.y; key[14] = k3.z; key[15] = k3.w;
  }
  unsigned m1k = 0xFFFFFFFFu, m2k = 0xFFFFFFFFu, m3k = 0xFFFFFFFFu;
  int m1p = 0, m2p = 0, m3p = 0;
#pragma unroll
  for (int it = 0; it < 16; ++it) {
    unsigned v = key[it];
    bool b1 = v < m1k, b2 = v < m2k, b3 = v < m3k;
    m3k = b2 ? m2k : (b3 ? v : m3k);
    m3p = b2 ? m2p : (b3 ? it : m3p);
    m2k = b1 ? m1k : (b2 ? v : m2k);
    m2p = b1 ? m1p : (b2 ? it : m2p);
    m1k = b1 ? v : m1k;
    m1p = b1 ? it : m1p;
  }
  unsigned consumed = (1u << m1p) | (1u << m2p) | (1u << m3p);
  unsigned ck = m1k, cp = (unsigned)(lane * 16 + m1p);
  unsigned n1k = m2k, n1p = (unsigned)(lane * 16 + m2p);
  unsigned n2k = m3k, n2p = (unsigned)(lane * 16 + m3p);
  for (int r = 0; r < 20; ++r) {
    unsigned mh = ck;
#pragma unroll
    for (int off = 32; off; off >>= 1) {
      unsigned o = __shfl_xor(mh, off, 64);
      mh = o < mh ? o : mh;
    }
    unsigned lo2 = (ck == mh) ? cp : 0xFFFFFFFFu;
    unsigned ml = lo2;
#pragma unroll
    for (int off = 32; off; off >>= 1) {
      unsigned o = __shfl_xor(ml, off, 64);
      ml = o < ml ? o : ml;
    }
    if (lane == 0) cand[wv][r] = ((ull)mh << 32) | (unsigned)(wv * 1024 + ml);
    bool pop = (ck == mh) && (cp == ml);
    ck = pop ? n1k : ck;  cp = pop ? n1p : cp;
    n1k = pop ? n2k : n1k; n1p = pop ? n2p : n1p;
    n2k = pop ? 0xFFFFFFFFu : n2k;
    if (ck == 0xFFFFFFFFu) {  // rare: lane popped >=3 times; refill from regs
      unsigned bk = 0xFFFFFFFFu; int bp = 0;
#pragma unroll
      for (int it2 = 0; it2 < 16; ++it2) {
        bool ok = ((consumed >> it2) & 1u) == 0u;
        unsigned v = ok ? key[it2] : 0xFFFFFFFFu;
        bool t = v < bk;
        bk = t ? v : bk;
        bp = t ? it2 : bp;
      }
      consumed |= (1u << bp);
      ck = bk;
      cp = (unsigned)(lane * 16 + bp);
    }
  }
  __syncthreads();
  if (tid == 0) {
    int* op = idx + ((size_t)b * 4096 + ibase + ir_) * 20;
    int p0 = 0, p1 = 0, p2 = 0, p3 = 0;
    for (int r = 0; r < 20; ++r) {
      ull v0 = cand[0][p0], v1 = cand[1][p1], v2 = cand[2][p2], v3 = cand[3][p3];
      ull m01 = v0 < v1 ? v0 : v1;
      ull m23 = v2 < v3 ? v2 : v3;
      ull best = m01 < m23 ? m01 : m23;
      if (best == v0) ++p0; else if (best == v1) ++p1;
      else if (best == v2) ++p2; else ++p3;
      op[r] = (int)(best & 0xfffull);
      if (p0 > 19) p0 = 19;
      if (p1 > 19) p1 = 19;
      if (p2 > 19) p2 = 19;
      if (p3 > 19) p3 = 19;
    }
  }
}

// ---------------- EdgeConv layer 1 (fp32, Cin=3): one wave per point ----------------
__global__ __launch_bounds__(256) void k_edge1(const float* __restrict__ xf,
                                               const float* __restrict__ W1,
                                               const float* __restrict__ s1,
                                               const float* __restrict__ b1,
                                               const int* __restrict__ idx,
                                               float* __restrict__ xcat,
                                               __hip_bfloat16* __restrict__ xcatb) {
  const int lane = threadIdx.x & 63;
  const int p = blockIdx.x * 4 + (threadIdx.x >> 6);
  const int bb = p >> 12;
  float wl[3], wr[3];
#pragma unroll
  for (int c = 0; c < 3; ++c) {
    wl[c] = W1[lane * 6 + c];
    wr[c] = W1[lane * 6 + 3 + c];
  }
  const float s = s1[lane], bi = b1[lane];
  const float* xc = xf + (size_t)p * 3;
  const float x0 = xc[0], x1 = xc[1], x2 = xc[2];
  const float t = x0 * (wr[0] - wl[0]) + x1 * (wr[1] - wl[1]) + x2 * (wr[2] - wl[2]);
  const int* ir = idx + (size_t)p * 20;
  float best = -INFINITY;
  for (int k = 0; k < 20; ++k) {
    int j = ir[k];
    const float* xn = xf + ((size_t)(bb << 12) + j) * 3;
    float y = t + xn[0] * wl[0] + xn[1] * wl[1] + xn[2] * wl[2];
    y = lrelu(y * s + bi);
    best = fmaxf(best, y);
  }
  xcat[(size_t)p * 512 + lane] = best;
  xcatb[(size_t)p * 512 + lane] = __float2bfloat16(best);
}

// ---------------- fp32 pointwise GEMM, raw store (T for layers 2-3) ----------------
__global__ __launch_bounds__(256) void k_pwT(const float* __restrict__ A, int lda, int K,
                                             const float* __restrict__ W, int ldw, int wsub,
                                             float* __restrict__ out, int ldo) {
  __shared__ __align__(16) float As[16][68];
  __shared__ __align__(16) float Bs[16][68];
  const int tid = threadIdx.x;
  const int tx = tid & 15, ty = tid >> 4;
  const int i0 = blockIdx.x * 64, o0 = blockIdx.y * 64;
  const int row = tid >> 2, q = (tid & 3) * 4;
  float acc[4][4] = {};
  for (int c0 = 0; c0 < K; c0 += 16) {
    float4 a = *(const float4*)(A + (size_t)(i0 + row) * lda + c0 + q);
    As[q + 0][row] = a.x; As[q + 1][row] = a.y; As[q + 2][row] = a.z; As[q + 3][row] = a.w;
    const float* wp = W + (size_t)(o0 + row) * ldw + c0 + q;
#pragma unroll
    for (int e = 0; e < 4; ++e) Bs[q + e][row] = wp[wsub + e] - wp[e];
    __syncthreads();
#pragma unroll
    for (int kk = 0; kk < 16; ++kk) {
      const float4 a4 = *(const float4*)&As[kk][ty * 4];
      const float4 b4 = *(const float4*)&Bs[kk][tx * 4];
      const float av[4] = {a4.x, a4.y, a4.z, a4.w};
      const float bv[4] = {b4.x, b4.y, b4.z, b4.w};
#pragma unroll
      for (int ii = 0; ii < 4; ++ii)
#pragma unroll
        for (int jj = 0; jj < 4; ++jj)
          acc[ii][jj] = fmaf(av[ii], bv[jj], acc[ii][jj]);
    }
    __syncthreads();
  }
#pragma unroll
  for (int ii = 0; ii < 4; ++ii)
#pragma unroll
    for (int jj = 0; jj < 4; ++jj)
      out[(size_t)(i0 + ty * 4 + ii) * ldo + o0 + tx * 4 + jj] = acc[ii][jj];
}

// ---------------- fp32 EdgeConv GEMM (layers 2-3; feeds kNN, stays exact) ----------------
__global__ __launch_bounds__(256) void k_edge(const float* __restrict__ F, int ldf, int Cin,
                                              const float* __restrict__ W,
                                              const float* __restrict__ sc,
                                              const float* __restrict__ bi,
                                              const int* __restrict__ idx,
                                              const float* __restrict__ T, int ldt,
                                              float* __restrict__ out,
                                              __hip_bfloat16* __restrict__ outb) {
  __shared__ float As[16][81];
  __shared__ __align__(16) float Bs[16][68];
  __shared__ float Ys[80][65];
  const int tid = threadIdx.x;
  const int tx = tid & 15, ty = tid >> 4;
  const int r0 = blockIdx.x * 80;
  const int o0 = blockIdx.y * 64;
  const int ldw = 2 * Cin;
  int grow[5], gcol[5];
#pragma unroll
  for (int l = 0; l < 5; ++l) {
    int e = tid + l * 256;
    int rr = e >> 4;
    gcol[l] = e & 15;
    int gr = r0 + rr;
    int p = gr / 20;
    int j = idx[(size_t)p * 20 + (gr % 20)];
    grow[l] = ((p >> 12) << 12) + j;
  }
  float acc[5][4] = {};
  const int wrow = tid >> 2, wq = (tid & 3) * 4;
  for (int c0 = 0; c0 < Cin; c0 += 16) {
#pragma unroll
    for (int l = 0; l < 5; ++l) {
      int e = tid + l * 256;
      As[gcol[l]][e >> 4] = F[(size_t)grow[l] * ldf + c0 + gcol[l]];
    }
    {
      const float* wp = W + (size_t)(o0 + wrow) * ldw + c0 + wq;
#pragma unroll
      for (int e = 0; e < 4; ++e) Bs[wq + e][wrow] = wp[e];
    }
    __syncthreads();
#pragma unroll
    for (int kk = 0; kk < 16; ++kk) {
      float a[5];
#pragma unroll
      for (int l = 0; l < 5; ++l) a[l] = As[kk][ty + l * 16];
      const float4 b4 = *(const float4*)&Bs[kk][tx * 4];
      const float bv[4] = {b4.x, b4.y, b4.z, b4.w};
#pragma unroll
      for (int l = 0; l < 5; ++l)
#pragma unroll
        for (int jj = 0; jj < 4; ++jj)
          acc[l][jj] = fmaf(a[l], bv[jj], acc[l][jj]);
    }
    __syncthreads();
  }
#pragma unroll
  for (int l = 0; l < 5; ++l) {
    int r = ty + l * 16;
    int p = (r0 + r) / 20;
#pragma unroll
    for (int jj = 0; jj < 4; ++jj) {
      int o = o0 + tx * 4 + jj;
      float y = (acc[l][jj] + T[(size_t)p * ldt + o]) * sc[o] + bi[o];
      Ys[r][tx * 4 + jj] = lrelu(y);
    }
  }
  __syncthreads();
  const int grp = tid >> 6, col = tid & 63;
  float m = -INFINITY;
#pragma unroll
  for (int k = 0; k < 20; ++k) m = fmaxf(m, Ys[grp * 20 + k][col]);
  const int p = blockIdx.x * 4 + grp;
  out[(size_t)p * 512 + o0 + col] = m;
  outb[(size_t)p * 512 + o0 + col] = __float2bfloat16(m);
}

// ---------------- MFMA bf16 GEMM: block 128(M)x64(N), 4 waves x (32x64) ----------------
template <int EPI>
__global__ __launch_bounds__(256) void k_mm(
    const __hip_bfloat16* __restrict__ A, int lda, int K,
    const __hip_bfloat16* __restrict__ B,  // [N][K] bf16
    const float* __restrict__ sc, const float* __restrict__ bi,
    const float* __restrict__ extra, int Ncols,
    float* __restrict__ outf, int ldof,
    __hip_bfloat16* __restrict__ outb, int ldob,
    unsigned* __restrict__ gmax) {
  __shared__ __align__(16) __hip_bfloat16 Al[128 * 40];
  __shared__ __align__(16) __hip_bfloat16 Bl[64 * 40];
  __shared__ float Red[4][64];
  const int tid = threadIdx.x, lane = tid & 63, wv = tid >> 6;
  const int m0 = blockIdx.x * 128, n0 = blockIdx.y * 64;
  const int arow = tid >> 2, akc = (tid & 3) * 8;
  const int fm = lane & 15, fq = lane >> 4;
  f32x4 acc[2][4];
#pragma unroll
  for (int mt = 0; mt < 2; ++mt)
#pragma unroll
    for (int nt = 0; nt < 4; ++nt) acc[mt][nt] = (f32x4){0.f, 0.f, 0.f, 0.f};
  for (int c0 = 0; c0 < K; c0 += 32) {
#pragma unroll
    for (int l = 0; l < 2; ++l) {
      int r = arow + l * 64;
      *(float4*)&Al[r * 40 + akc] = *(const float4*)(A + (size_t)(m0 + r) * lda + c0 + akc);
    }
    *(float4*)&Bl[arow * 40 + akc] = *(const float4*)(B + (size_t)(n0 + arow) * K + c0 + akc);
    __syncthreads();
    bf16x8 af[2], bfr[4];
#pragma unroll
    for (int mt = 0; mt < 2; ++mt)
      af[mt] = *(const bf16x8*)&Al[(wv * 32 + mt * 16 + fm) * 40 + fq * 8];
#pragma unroll
    for (int nt = 0; nt < 4; ++nt)
      bfr[nt] = *(const bf16x8*)&Bl[(nt * 16 + fm) * 40 + fq * 8];
#pragma unroll
    for (int mt = 0; mt < 2; ++mt)
#pragma unroll
      for (int nt = 0; nt < 4; ++nt)
        acc[mt][nt] = __builtin_amdgcn_mfma_f32_16x16x32_bf16(af[mt], bfr[nt], acc[mt][nt], 0, 0, 0);
    __syncthreads();
  }
  const int bidx = m0 >> 12;
  if (EPI == 0) {
#pragma unroll
    for (int mt = 0; mt < 2; ++mt)
#pragma unroll
      for (int nt = 0; nt < 4; ++nt)
#pragma unroll
        for (int r = 0; r < 4; ++r)
          outf[(size_t)(m0 + wv * 32 + mt * 16 + fq * 4 + r) * ldof + n0 + nt * 16 + fm] =
              acc[mt][nt][r];
  } else if (EPI == 1) {
#pragma unroll
    for (int nt = 0; nt < 4; ++nt) {
      int col = n0 + nt * 16 + fm;
      float s = sc[col], bb = bi[col];
      float ex = extra ? extra[bidx * Ncols + col] : 0.f;
#pragma unroll
      for (int mt = 0; mt < 2; ++mt)
#pragma unroll
        for (int r = 0; r < 4; ++r) {
          float v = lrelu((acc[mt][nt][r] + ex) * s + bb);
          size_t rr = (size_t)(m0 + wv * 32 + mt * 16 + fq * 4 + r);
          if (outf) outf[rr * ldof + col] = v;
          if (outb) outb[rr * ldob + col] = __float2bfloat16(v);
        }
    }
  } else {
#pragma unroll
    for (int nt = 0; nt < 4; ++nt) {
      int col = n0 + nt * 16 + fm;
      float s = sc[col], bb = bi[col];
      float m = -INFINITY;
#pragma unroll
      for (int mt = 0; mt < 2; ++mt)
#pragma unroll
        for (int r = 0; r < 4; ++r) m = fmaxf(m, lrelu(acc[mt][nt][r] * s + bb));
      m = fmaxf(m, __shfl_xor(m, 16, 64));
      m = fmaxf(m, __shfl_xor(m, 32, 64));
      if (fq == 0) Red[wv][nt * 16 + fm] = m;
    }
    __syncthreads();
    if (tid < 64) {
      float m = fmaxf(fmaxf(Red[0][tid], Red[1][tid]), fmaxf(Red[2][tid], Red[3][tid]));
      atomicMax(&gmax[bidx * Ncols + n0 + tid], okey(m));
    }
  }
}

// ---------------- MFMA bf16 EdgeConv (layer 4): 320 edges x 64 cols / block ----------------
__global__ __launch_bounds__(256) void k_edgem(
    const __hip_bfloat16* __restrict__ F, int ldf, int coff, int K,
    const __hip_bfloat16* __restrict__ Wl,  // [N][K] bf16
    const float* __restrict__ sc, const float* __restrict__ bi,
    const float* __restrict__ T, int N,
    const int* __restrict__ idx,
    float* __restrict__ outf, __hip_bfloat16* __restrict__ outb) {
  __shared__ __align__(16) char smem[320 * 66 * 2];  // 42240 B, overlaid stage/Ys
  __hip_bfloat16* Al = (__hip_bfloat16*)smem;              // 320*40
  __hip_bfloat16* Bl = (__hip_bfloat16*)(smem + 25600);    // 64*40
  __hip_bfloat16* Ys = (__hip_bfloat16*)smem;              // 320*66 (post-loop)
  const int tid = threadIdx.x, lane = tid & 63, wv = tid >> 6;
  const int blk = blockIdx.x, n0 = blockIdx.y * 64;
  const int arow = tid >> 2, akc = (tid & 3) * 8;
  const int fm = lane & 15, fq = lane >> 4;
  const __hip_bfloat16* ap[5];
#pragma unroll
  for (int l = 0; l < 5; ++l) {
    int row = arow + l * 64;
    int e = blk * 320 + row;
    int p = e / 20;
    int j = idx[(size_t)p * 20 + (e - p * 20)];
    int src = ((p >> 12) << 12) + j;
    ap[l] = F + (size_t)src * ldf + coff + akc;
  }
  f32x4 acc[5][4];
#pragma unroll
  for (int l = 0; l < 5; ++l)
#pragma unroll
    for (int nt = 0; nt < 4; ++nt) acc[l][nt] = (f32x4){0.f, 0.f, 0.f, 0.f};
  for (int c0 = 0; c0 < K; c0 += 32) {
#pragma unroll
    for (int l = 0; l < 5; ++l)
      *(float4*)&Al[(arow + l * 64) * 40 + akc] = *(const float4*)(ap[l] + c0);
    *(float4*)&Bl[arow * 40 + akc] = *(const float4*)(Wl + (size_t)(n0 + arow) * K + c0 + akc);
    __syncthreads();
    bf16x8 af[5], bfr[4];
#pragma unroll
    for (int l = 0; l < 5; ++l)
      af[l] = *(const bf16x8*)&Al[(wv * 80 + l * 16 + fm) * 40 + fq * 8];
#pragma unroll
    for (int nt = 0; nt < 4; ++nt)
      bfr[nt] = *(const bf16x8*)&Bl[(nt * 16 + fm) * 40 + fq * 8];
#pragma unroll
    for (int l = 0; l < 5; ++l)
#pragma unroll
      for (int nt = 0; nt < 4; ++nt)
        acc[l][nt] = __builtin_amdgcn_mfma_f32_16x16x32_bf16(af[l], bfr[nt], acc[l][nt], 0, 0, 0);
    __syncthreads();
  }
#pragma unroll
  for (int l = 0; l < 5; ++l)
#pragma unroll
    for (int nt = 0; nt < 4; ++nt)
#pragma unroll
      for (int r = 0; r < 4; ++r)
        Ys[(wv * 80 + l * 16 + fq * 4 + r) * 66 + nt * 16 + fm] = __float2bfloat16(acc[l][nt][r]);
  __syncthreads();
  const int col = tid & 63;
#pragma unroll
  for (int gi = 0; gi < 4; ++gi) {
    int grp = wv + gi * 4;
    float m = -INFINITY;
#pragma unroll
    for (int k = 0; k < 20; ++k)
      m = fmaxf(m, __bfloat162float(Ys[(grp * 20 + k) * 66 + col]));
    int p = blk * 16 + grp;
    int o = n0 + col;
    float v = lrelu((m + T[(size_t)p * N + o]) * sc[o] + bi[o]);
    outf[(size_t)p * 512 + o] = v;
    outb[(size_t)p * 512 + o] = __float2bfloat16(v);
  }
}

// ---------------- bias2: one wave per (b,o) ----------------
__global__ __launch_bounds__(256) void k_bias2(const unsigned* __restrict__ gk,
                                               const float* __restrict__ Ws1,
                                               float* __restrict__ b2g) {
  const int lane = threadIdx.x & 63;
  const int wid = (blockIdx.x * 256 + threadIdx.x) >> 6;  // 0..1023
  const int b = wid >> 9, o = wid & 511;
  const float* wr = Ws1 + (size_t)o * 1536 + 512;
  const unsigned* g = gk + b * 1024;
  float acc = 0.f;
#pragma unroll
  for (int c = lane; c < 1024; c += 64) acc = fmaf(dekey(g[c]), wr[c], acc);
#pragma unroll
  for (int off = 32; off; off >>= 1) acc += __shfl_xor(acc, off, 64);
  if (lane == 0) b2g[b * 512 + o] = acc;
}

// ---------------- final head: out = H(8192x256) . Ws3^T + bs3 (fp32) ----------------
__global__ __launch_bounds__(256) void k_out(const float* __restrict__ H,
                                             const float* __restrict__ Ws3,
                                             const float* __restrict__ bs3,
                                             float* __restrict__ out) {
  __shared__ float Ws[13][256];
  const int tid = threadIdx.x;
  for (int e = tid; e < 13 * 256; e += 256) Ws[e >> 8][e & 255] = Ws3[e];
  __syncthreads();
  const int rloc = tid >> 4, o = tid & 15;
  const int row = blockIdx.x * 16 + rloc;
  if (o < 13) {
    const float* h = H + (size_t)row * 256;
    float acc = 0.f;
    for (int c = 0; c < 256; ++c) acc = fmaf(h[c], Ws[o][c], acc);
    out[(size_t)row * 13 + o] = acc + bs3[o];
  }
}

extern "C" void kernel_launch(void* const* d_in, const int* in_sizes, int n_in,
                              void* d_out, int out_size, void* d_ws, size_t ws_size,
                              hipStream_t stream) {
  const float* X   = (const float*)d_in[0];
  const float* W1  = (const float*)d_in[1];
  const float* S1  = (const float*)d_in[2];
  const float* B1  = (const float*)d_in[3];
  const float* W2  = (const float*)d_in[4];
  const float* S2  = (const float*)d_in[5];
  const float* B2  = (const float*)d_in[6];
  const float* W3  = (const float*)d_in[7];
  const float* S3  = (const float*)d_in[8];
  const float* B3  = (const float*)d_in[9];
  const float* W4  = (const float*)d_in[10];
  const float* S4  = (const float*)d_in[11];
  const float* B4  = (const float*)d_in[12];
  const float* Wg  = (const float*)d_in[13];
  const float* Sg  = (const float*)d_in[14];
  const float* Bg  = (const float*)d_in[15];
  const float* Ws1 = (const float*)d_in[16];
  const float* Ss1 = (const float*)d_in[17];
  const float* Bs1 = (const float*)d_in[18];
  const float* Ws2 = (const float*)d_in[19];
  const float* Ss2 = (const float*)d_in[20];
  const float* Bs2 = (const float*)d_in[21];
  const float* Ws3 = (const float*)d_in[22];
  const float* Bs3 = (const float*)d_in[23];

  char* ws = (char*)d_ws;
  float*           xxb   = (float*)(ws + 0);            // 32 KB
  int*             idxb  = (int*)(ws + 32768);          // 640 KB
  unsigned*        gk    = (unsigned*)(ws + 688128);    // 8 KB
  float*           b2g   = (float*)(ws + 696320);       // 4 KB
  __hip_bfloat16*  Wgb   = (__hip_bfloat16*)(ws + 1048576);  // 1 MB
  __hip_bfloat16*  Ws1b  = (__hip_bfloat16*)(ws + 2097152);  // 512 KB
  __hip_bfloat16*  Ws2b  = (__hip_bfloat16*)(ws + 2621440);  // 256 KB
  __hip_bfloat16*  Wlb4  = (__hip_bfloat16*)(ws + 2883584);  // 64 KB
  __hip_bfloat16*  Wdb4  = (__hip_bfloat16*)(ws + 2949120);  // 64 KB
  __hip_bfloat16*  xcatb = (__hip_bfloat16*)(ws + 3145728);  // 8 MB
  float*           xcat  = (float*)(ws + 11534336);          // 16 MB
  char*            region = ws + 28311552;                   // dist / Tbuf+h1b
  unsigned*        dist  = (unsigned*)(region);
  float*           Tbuf  = (float*)(region);
  __hip_bfloat16*  h1b   = (__hip_bfloat16*)(region + 8388608);

  // dist buffer variants: both batches (128MB) > one batch (64MB) > chunked (16MB)
  const bool big2 = (ws_size >= (size_t)28311552 + (128u << 20));
  const bool big1 = (ws_size >= (size_t)28311552 + (64u << 20));

  hipMemsetAsync(gk, 0, 2 * 1024 * sizeof(unsigned), stream);

  // weight bf16 packs (L4 + head only; L1-L3 weights stay fp32)
  k_conv<<<dim3(256, 2), dim3(64), 0, stream>>>(W4, 256, 0, 0, 128, Wlb4);
  k_conv<<<dim3(256, 2), dim3(64), 0, stream>>>(W4, 256, 128, 1, 128, Wdb4);
  k_conv<<<dim3(1024, 8), dim3(64), 0, stream>>>(Wg, 512, 0, 0, 512, Wgb);
  k_conv<<<dim3(512, 8), dim3(64), 0, stream>>>(Ws1, 1536, 0, 0, 512, Ws1b);
  k_conv<<<dim3(256, 8), dim3(64), 0, stream>>>(Ws2, 512, 0, 0, 512, Ws2b);

  // kNN for one layer (fills idxb); selection bit-identical in all paths
  auto run_knn = [&](const float* F, int ldf, int C) {
    k_xx<<<dim3(2048), dim3(256), 0, stream>>>(F, ldf, C, xxb);
    if (big2) {
      k_dist<<<dim3(528, 1, 2), dim3(256), 0, stream>>>(F, ldf, C, xxb, dist, -1, 0, 1);
      k_topk<<<dim3(4096, 2), dim3(256), 0, stream>>>(dist, idxb, -1, 0);
    } else if (big1) {
      for (int b = 0; b < 2; ++b) {
        k_dist<<<dim3(32, 32), dim3(256), 0, stream>>>(F, ldf, C, xxb, dist, b, 0, 0);
        k_topk<<<dim3(4096), dim3(256), 0, stream>>>(dist, idxb, b, 0);
      }
    } else {
      for (int b = 0; b < 2; ++b)
        for (int c = 0; c < 4; ++c) {
          k_dist<<<dim3(8, 32), dim3(256), 0, stream>>>(F, ldf, C, xxb, dist, b, c * 1024, 0);
          k_topk<<<dim3(1024), dim3(256), 0, stream>>>(dist, idxb, b, c * 1024);
        }
    }
  };

  // ---- Layer 1 (C=3 -> 64, fp32 exact) ----
  run_knn(X, 3, 3);
  k_edge1<<<dim3(2048), dim3(256), 0, stream>>>(X, W1, S1, B1, idxb, xcat, xcatb);

  // ---- Layer 2 (64 -> 64), fp32 (feeds kNN — must stay exact, R9 proved it) ----
  run_knn(xcat, 512, 64);
  k_pwT<<<dim3(128, 1), dim3(256), 0, stream>>>(xcat, 512, 64, W2, 128, 64, Tbuf, 64);
  k_edge<<<dim3(2048, 1), dim3(256), 0, stream>>>(xcat, 512, 64, W2, S2, B2,
      idxb, Tbuf, 64, xcat + 64, xcatb + 64);

  // ---- Layer 3 (64 -> 128), fp32 (feeds kNN) ----
  run_knn(xcat + 64, 512, 64);
  k_pwT<<<dim3(128, 2), dim3(256), 0, stream>>>(xcat + 64, 512, 64, W3, 128, 64, Tbuf, 128);
  k_edge<<<dim3(2048, 2), dim3(256), 0, stream>>>(xcat + 64, 512, 64, W3, S3, B3,
      idxb, Tbuf, 128, xcat + 128, xcatb + 128);

  // ---- Layer 4 (128 -> 256), bf16 MFMA (x4 feeds nothing discrete) ----
  run_knn(xcat + 128, 512, 128);
  k_mm<0><<<dim3(64, 4), dim3(256), 0, stream>>>(xcatb + 128, 512, 128, Wdb4,
      nullptr, nullptr, nullptr, 256, Tbuf, 256, nullptr, 0, nullptr);
  k_edgem<<<dim3(512, 4), dim3(256), 0, stream>>>(xcatb, 512, 128, 128, Wlb4,
      S4, B4, Tbuf, 256, idxb, xcat + 256, xcatb + 256);

  // ---- head (all bf16 MFMA) ----
  k_mm<2><<<dim3(64, 16), dim3(256), 0, stream>>>(xcatb, 512, 512, Wgb,
      Sg, Bg, nullptr, 1024, nullptr, 0, nullptr, 0, gk);
  k_bias2<<<dim3(256), dim3(256), 0, stream>>>(gk, Ws1, b2g);
  k_mm<1><<<dim3(64, 8), dim3(256), 0, stream>>>(xcatb, 512, 512, Ws1b,
      Ss1, Bs1, b2g, 512, nullptr, 0, h1b, 512, nullptr);
  k_mm<1><<<dim3(64, 4), dim3(256), 0, stream>>>(h1b, 512, 512, Ws2b,
      Ss2, Bs2, nullptr, 256, Tbuf, 256, nullptr, 0, nullptr);
  k_out<<<dim3(512), dim3(256), 0, stream>>>(Tbuf, Ws3, Bs3, (float*)d_out);
}

// Round 18
// 683.471 us; speedup vs baseline: 1.5698x; 1.3199x over previous
//
#include <hip/hip_runtime.h>
#include <hip/hip_bf16.h>

// DGCNN_Seg forward. B=2, N=4096, K=20. fp32 in/out.
// Round 18: k_topk v7 — ONE wave per row (64 keys/lane in VGPRs) and
// ballot+ffs instead of the lo min-tree. Shfl(LDS-pipe) ops per row drop
// ~960 -> ~150 (R17 proved k_topk is shfl-throughput bound). Selection =
// (okey, j) lexicographic, bit-identical. Rest = R17 (902us).

#define DEVI static __device__ __forceinline__
typedef __attribute__((ext_vector_type(8))) short bf16x8;   // 8 bf16 = 4 VGPR
typedef __attribute__((ext_vector_type(4))) float f32x4;    // MFMA acc
typedef unsigned long long ull;

DEVI float lrelu(float y) { return y > 0.f ? y : 0.2f * y; }
DEVI unsigned okey(float f) {
  unsigned u = __float_as_uint(f);
  return (f < 0.f) ? ~u : (u | 0x80000000u);
}
DEVI float dekey(unsigned k) {
  return __uint_as_float((k & 0x80000000u) ? (k & 0x7fffffffu) : ~k);
}

// ---------------- weight fp32 -> bf16 pack ----------------
__global__ __launch_bounds__(64) void k_conv(const float* __restrict__ src, int lds, int off,
                                             int sub, int Kc, __hip_bfloat16* __restrict__ dst) {
  int o = blockIdx.x, c = blockIdx.y * 64 + threadIdx.x;
  float v = src[(size_t)o * lds + off + c];
  if (sub) v -= src[(size_t)o * lds + c];
  dst[(size_t)o * Kc + c] = __float2bfloat16(v);
}

// ---------------- row squared-norms: one wave per row ----------------
__global__ __launch_bounds__(256) void k_xx(const float* __restrict__ F, int ldf, int C,
                                            float* __restrict__ xx) {
  int lane = threadIdx.x & 63;
  int row = blockIdx.x * 4 + (threadIdx.x >> 6);
  const float* f = F + (size_t)row * ldf;
  float s = 0.f;
  for (int c = lane; c < C; c += 64) { float v = f[c]; s += v * v; }
#pragma unroll
  for (int off = 32; off; off >>= 1) s += __shfl_xor(s, off, 64);
  if (lane == 0) xx[row] = s;
}

// ---------------- pairwise distances v5: 128x128 tile, 8x8/thread ----------------
__global__ __launch_bounds__(256) void k_dist(const float* __restrict__ F, int ldf, int C,
                                              const float* __restrict__ xx,
                                              unsigned* __restrict__ D, int bfix, int ibase,
                                              int sym) {
  __shared__ __align__(16) float As[16][132];
  __shared__ __align__(16) float Bs[16][132];
  const int tid = threadIdx.x;
  const int tx = tid & 15, ty = tid >> 4;
  int bi, bj;
  if (sym) {
    int t = blockIdx.x, r = 32;
    bi = 0;
    while (t >= r) { t -= r; ++bi; r = 32 - bi; }
    bj = bi + t;
  } else {
    bi = blockIdx.x;
    bj = blockIdx.y;
  }
  const int b = (bfix < 0) ? (int)blockIdx.z : bfix;
  unsigned* Db = (bfix < 0) ? (D + (size_t)b * 4096 * 4096) : D;
  const int i0 = ibase + bi * 128, j0 = bj * 128;
  const float* Fb = F + (size_t)b * 4096 * ldf;
  const float* xxb = xx + b * 4096;
  const int srow = tid >> 1, sq = (tid & 1) * 8;  // stage: 128 rows x 16 cols
  float acc[8][8] = {};
  for (int c0 = 0; c0 < C; c0 += 16) {
    if (C - c0 >= 16) {
      float4 a0 = *(const float4*)(Fb + (size_t)(i0 + srow) * ldf + c0 + sq);
      float4 a1 = *(const float4*)(Fb + (size_t)(i0 + srow) * ldf + c0 + sq + 4);
      As[sq + 0][srow] = a0.x; As[sq + 1][srow] = a0.y; As[sq + 2][srow] = a0.z; As[sq + 3][srow] = a0.w;
      As[sq + 4][srow] = a1.x; As[sq + 5][srow] = a1.y; As[sq + 6][srow] = a1.z; As[sq + 7][srow] = a1.w;
      float4 b0 = *(const float4*)(Fb + (size_t)(j0 + srow) * ldf + c0 + sq);
      float4 b1 = *(const float4*)(Fb + (size_t)(j0 + srow) * ldf + c0 + sq + 4);
      Bs[sq + 0][srow] = b0.x; Bs[sq + 1][srow] = b0.y; Bs[sq + 2][srow] = b0.z; Bs[sq + 3][srow] = b0.w;
      Bs[sq + 4][srow] = b1.x; Bs[sq + 5][srow] = b1.y; Bs[sq + 6][srow] = b1.z; Bs[sq + 7][srow] = b1.w;
    } else {
#pragma unroll
      for (int e = 0; e < 8; ++e) {
        int c = c0 + sq + e;
        As[sq + e][srow] = (c < C) ? Fb[(size_t)(i0 + srow) * ldf + c] : 0.f;
        Bs[sq + e][srow] = (c < C) ? Fb[(size_t)(j0 + srow) * ldf + c] : 0.f;
      }
    }
    __syncthreads();
#pragma unroll
    for (int kk = 0; kk < 16; ++kk) {
      const float4 al = *(const float4*)&As[kk][ty * 8];
      const float4 ah = *(const float4*)&As[kk][ty * 8 + 4];
      const float4 bl = *(const float4*)&Bs[kk][tx * 8];
      const float4 bh = *(const float4*)&Bs[kk][tx * 8 + 4];
      const float av[8] = {al.x, al.y, al.z, al.w, ah.x, ah.y, ah.z, ah.w};
      const float bv[8] = {bl.x, bl.y, bl.z, bl.w, bh.x, bh.y, bh.z, bh.w};
#pragma unroll
      for (int ii = 0; ii < 8; ++ii)
#pragma unroll
        for (int jj = 0; jj < 8; ++jj)
          acc[ii][jj] = fmaf(av[ii], bv[jj], acc[ii][jj]);
    }
    __syncthreads();
  }
  // normal block store
#pragma unroll
  for (int ii = 0; ii < 8; ++ii) {
    int i = i0 + ty * 8 + ii;
    float xi = xxb[i];
    uint4 o1, o2;
    o1.x = okey(xi + xxb[j0 + tx * 8 + 0] - 2.f * acc[ii][0]);
    o1.y = okey(xi + xxb[j0 + tx * 8 + 1] - 2.f * acc[ii][1]);
    o1.z = okey(xi + xxb[j0 + tx * 8 + 2] - 2.f * acc[ii][2]);
    o1.w = okey(xi + xxb[j0 + tx * 8 + 3] - 2.f * acc[ii][3]);
    o2.x = okey(xi + xxb[j0 + tx * 8 + 4] - 2.f * acc[ii][4]);
    o2.y = okey(xi + xxb[j0 + tx * 8 + 5] - 2.f * acc[ii][5]);
    o2.z = okey(xi + xxb[j0 + tx * 8 + 6] - 2.f * acc[ii][6]);
    o2.w = okey(xi + xxb[j0 + tx * 8 + 7] - 2.f * acc[ii][7]);
    *(uint4*)&Db[(size_t)(i - ibase) * 4096 + j0 + tx * 8] = o1;
    *(uint4*)&Db[(size_t)(i - ibase) * 4096 + j0 + tx * 8 + 4] = o2;
  }
  // mirror block store (sym, off-diagonal): direct register->global transposed.
  if (sym && bi < bj) {
#pragma unroll
    for (int jj = 0; jj < 8; ++jj) {
      const float xj = xxb[j0 + tx * 8 + jj];
      uint4 m1, m2;
      m1.x = okey(xxb[i0 + ty * 8 + 0] + xj - 2.f * acc[0][jj]);
      m1.y = okey(xxb[i0 + ty * 8 + 1] + xj - 2.f * acc[1][jj]);
      m1.z = okey(xxb[i0 + ty * 8 + 2] + xj - 2.f * acc[2][jj]);
      m1.w = okey(xxb[i0 + ty * 8 + 3] + xj - 2.f * acc[3][jj]);
      m2.x = okey(xxb[i0 + ty * 8 + 4] + xj - 2.f * acc[4][jj]);
      m2.y = okey(xxb[i0 + ty * 8 + 5] + xj - 2.f * acc[5][jj]);
      m2.z = okey(xxb[i0 + ty * 8 + 6] + xj - 2.f * acc[6][jj]);
      m2.w = okey(xxb[i0 + ty * 8 + 7] + xj - 2.f * acc[7][jj]);
      unsigned* dst = &Db[(size_t)(j0 + tx * 8 + jj) * 4096 + i0 + ty * 8];
      *(uint4*)(dst + 0) = m1;
      *(uint4*)(dst + 4) = m2;
    }
  }
}

// ---------------- top-20 v7: ONE WAVE per row ----------------
// Each lane holds 64 contiguous keys (16x uint4) in VGPRs; per-lane top-3
// tournament window. Extraction: 20 rounds of one u32 hi min-tree (6 shfl) +
// ballot/ffs for the popping lane (lane-major pos => lowest lane = smallest j)
// + 1 broadcast shfl. Rare refill scans the 64 regs via 64-bit consumed mask.
// Pop order = (okey, j) lexicographic -> bit-identical to R13-R17.
__global__ __launch_bounds__(256) void k_topk(const unsigned* __restrict__ Dk,
                                              int* __restrict__ idx, int bfix, int ibase) {
  const int tid = threadIdx.x, lane = tid & 63, wv = tid >> 6;
  const int ir_ = blockIdx.x * 4 + wv;
  const int b = (bfix < 0) ? (int)blockIdx.y : bfix;
  const unsigned* drow = Dk + ((bfix < 0) ? (size_t)b * 4096 * 4096 : 0) + (size_t)ir_ * 4096;
  unsigned key[64];
  {
    const uint4* dp = (const uint4*)(drow + lane * 64);
#pragma unroll
    for (int q = 0; q < 16; ++q) {
      uint4 k4 = dp[q];
      key[4 * q + 0] = k4.x; key[4 * q + 1] = k4.y;
      key[4 * q + 2] = k4.z; key[4 * q + 3] = k4.w;
    }
  }
  // per-lane top-3 tournament (strict < with ascending it -> ascending (key,j))
  unsigned m1k = 0xFFFFFFFFu, m2k = 0xFFFFFFFFu, m3k = 0xFFFFFFFFu;
  int m1p = 0, m2p = 0, m3p = 0;
#pragma unroll
  for (int it = 0; it < 64; ++it) {
    unsigned v = key[it];
    bool b1 = v < m1k, b2 = v < m2k, b3 = v < m3k;
    m3k = b2 ? m2k : (b3 ? v : m3k);
    m3p = b2 ? m2p : (b3 ? it : m3p);
    m2k = b1 ? m1k : (b2 ? v : m2k);
    m2p = b1 ? m1p : (b2 ? it : m2p);
    m1k = b1 ? v : m1k;
    m1p = b1 ? it : m1p;
  }
  ull consumed = (1ull << m1p) | (1ull << m2p) | (1ull << m3p);
  unsigned ck = m1k;
  int cp = m1p;
  unsigned n1k = m2k; int n1p = m2p;
  unsigned n2k = m3k; int n2p = m3p;
  int* op = idx + ((size_t)b * 4096 + ibase + ir_) * 20;
  for (int r = 0; r < 20; ++r) {
    unsigned mh = ck;
#pragma unroll
    for (int off = 32; off; off >>= 1) {
      unsigned o = __shfl_xor(mh, off, 64);
      mh = o < mh ? o : mh;
    }
    ull bal = __ballot(ck == mh);
    int sl = (int)(__ffsll((unsigned long long)bal) - 1);
    int mp = __shfl(cp, sl, 64);  // popping lane's in-lane position
    if (lane == 0) op[r] = sl * 64 + mp;
    bool pop = (lane == sl);
    ck = pop ? n1k : ck;  cp = pop ? n1p : cp;
    n1k = pop ? n2k : n1k; n1p = pop ? n2p : n1p;
    n2k = pop ? 0xFFFFFFFFu : n2k;
    if (ck == 0xFFFFFFFFu) {  // rare: this lane popped >=3 times; refill from regs
      unsigned bk = 0xFFFFFFFFu; int bp = 0;
#pragma unroll
      for (int t = 0; t < 64; ++t) {
        bool ok = ((consumed >> t) & 1ull) == 0ull;
        unsigned v = ok ? key[t] : 0xFFFFFFFFu;
        bool c = v < bk;
        bk = c ? v : bk;
        bp = c ? t : bp;
      }
      consumed |= (1ull << bp);
      ck = bk;
      cp = bp;
    }
  }
}

// ---------------- EdgeConv layer 1 (fp32, Cin=3): one wave per point ----------------
__global__ __launch_bounds__(256) void k_edge1(const float* __restrict__ xf,
                                               const float* __restrict__ W1,
                                               const float* __restrict__ s1,
                                               const float* __restrict__ b1,
                                               const int* __restrict__ idx,
                                               float* __restrict__ xcat,
                                               __hip_bfloat16* __restrict__ xcatb) {
  const int lane = threadIdx.x & 63;
  const int p = blockIdx.x * 4 + (threadIdx.x >> 6);
  const int bb = p >> 12;
  float wl[3], wr[3];
#pragma unroll
  for (int c = 0; c < 3; ++c) {
    wl[c] = W1[lane * 6 + c];
    wr[c] = W1[lane * 6 + 3 + c];
  }
  const float s = s1[lane], bi = b1[lane];
  const float* xc = xf + (size_t)p * 3;
  const float x0 = xc[0], x1 = xc[1], x2 = xc[2];
  const float t = x0 * (wr[0] - wl[0]) + x1 * (wr[1] - wl[1]) + x2 * (wr[2] - wl[2]);
  const int* ir = idx + (size_t)p * 20;
  float best = -INFINITY;
  for (int k = 0; k < 20; ++k) {
    int j = ir[k];
    const float* xn = xf + ((size_t)(bb << 12) + j) * 3;
    float y = t + xn[0] * wl[0] + xn[1] * wl[1] + xn[2] * wl[2];
    y = lrelu(y * s + bi);
    best = fmaxf(best, y);
  }
  xcat[(size_t)p * 512 + lane] = best;
  xcatb[(size_t)p * 512 + lane] = __float2bfloat16(best);
}

// ---------------- fp32 pointwise GEMM, raw store (T for layers 2-3) ----------------
__global__ __launch_bounds__(256) void k_pwT(const float* __restrict__ A, int lda, int K,
                                             const float* __restrict__ W, int ldw, int wsub,
                                             float* __restrict__ out, int ldo) {
  __shared__ __align__(16) float As[16][68];
  __shared__ __align__(16) float Bs[16][68];
  const int tid = threadIdx.x;
  const int tx = tid & 15, ty = tid >> 4;
  const int i0 = blockIdx.x * 64, o0 = blockIdx.y * 64;
  const int row = tid >> 2, q = (tid & 3) * 4;
  float acc[4][4] = {};
  for (int c0 = 0; c0 < K; c0 += 16) {
    float4 a = *(const float4*)(A + (size_t)(i0 + row) * lda + c0 + q);
    As[q + 0][row] = a.x; As[q + 1][row] = a.y; As[q + 2][row] = a.z; As[q + 3][row] = a.w;
    const float* wp = W + (size_t)(o0 + row) * ldw + c0 + q;
#pragma unroll
    for (int e = 0; e < 4; ++e) Bs[q + e][row] = wp[wsub + e] - wp[e];
    __syncthreads();
#pragma unroll
    for (int kk = 0; kk < 16; ++kk) {
      const float4 a4 = *(const float4*)&As[kk][ty * 4];
      const float4 b4 = *(const float4*)&Bs[kk][tx * 4];
      const float av[4] = {a4.x, a4.y, a4.z, a4.w};
      const float bv[4] = {b4.x, b4.y, b4.z, b4.w};
#pragma unroll
      for (int ii = 0; ii < 4; ++ii)
#pragma unroll
        for (int jj = 0; jj < 4; ++jj)
          acc[ii][jj] = fmaf(av[ii], bv[jj], acc[ii][jj]);
    }
    __syncthreads();
  }
#pragma unroll
  for (int ii = 0; ii < 4; ++ii)
#pragma unroll
    for (int jj = 0; jj < 4; ++jj)
      out[(size_t)(i0 + ty * 4 + ii) * ldo + o0 + tx * 4 + jj] = acc[ii][jj];
}

// ---------------- fp32 EdgeConv GEMM (layers 2-3; feeds kNN, stays exact) ----------------
__global__ __launch_bounds__(256) void k_edge(const float* __restrict__ F, int ldf, int Cin,
                                              const float* __restrict__ W,
                                              const float* __restrict__ sc,
                                              const float* __restrict__ bi,
                                              const int* __restrict__ idx,
                                              const float* __restrict__ T, int ldt,
                                              float* __restrict__ out,
                                              __hip_bfloat16* __restrict__ outb) {
  __shared__ float As[16][81];
  __shared__ __align__(16) float Bs[16][68];
  __shared__ float Ys[80][65];
  const int tid = threadIdx.x;
  const int tx = tid & 15, ty = tid >> 4;
  const int r0 = blockIdx.x * 80;
  const int o0 = blockIdx.y * 64;
  const int ldw = 2 * Cin;
  int grow[5], gcol[5];
#pragma unroll
  for (int l = 0; l < 5; ++l) {
    int e = tid + l * 256;
    int rr = e >> 4;
    gcol[l] = e & 15;
    int gr = r0 + rr;
    int p = gr / 20;
    int j = idx[(size_t)p * 20 + (gr % 20)];
    grow[l] = ((p >> 12) << 12) + j;
  }
  float acc[5][4] = {};
  const int wrow = tid >> 2, wq = (tid & 3) * 4;
  for (int c0 = 0; c0 < Cin; c0 += 16) {
#pragma unroll
    for (int l = 0; l < 5; ++l) {
      int e = tid + l * 256;
      As[gcol[l]][e >> 4] = F[(size_t)grow[l] * ldf + c0 + gcol[l]];
    }
    {
      const float* wp = W + (size_t)(o0 + wrow) * ldw + c0 + wq;
#pragma unroll
      for (int e = 0; e < 4; ++e) Bs[wq + e][wrow] = wp[e];
    }
    __syncthreads();
#pragma unroll
    for (int kk = 0; kk < 16; ++kk) {
      float a[5];
#pragma unroll
      for (int l = 0; l < 5; ++l) a[l] = As[kk][ty + l * 16];
      const float4 b4 = *(const float4*)&Bs[kk][tx * 4];
      const float bv[4] = {b4.x, b4.y, b4.z, b4.w};
#pragma unroll
      for (int l = 0; l < 5; ++l)
#pragma unroll
        for (int jj = 0; jj < 4; ++jj)
          acc[l][jj] = fmaf(a[l], bv[jj], acc[l][jj]);
    }
    __syncthreads();
  }
#pragma unroll
  for (int l = 0; l < 5; ++l) {
    int r = ty + l * 16;
    int p = (r0 + r) / 20;
#pragma unroll
    for (int jj = 0; jj < 4; ++jj) {
      int o = o0 + tx * 4 + jj;
      float y = (acc[l][jj] + T[(size_t)p * ldt + o]) * sc[o] + bi[o];
      Ys[r][tx * 4 + jj] = lrelu(y);
    }
  }
  __syncthreads();
  const int grp = tid >> 6, col = tid & 63;
  float m = -INFINITY;
#pragma unroll
  for (int k = 0; k < 20; ++k) m = fmaxf(m, Ys[grp * 20 + k][col]);
  const int p = blockIdx.x * 4 + grp;
  out[(size_t)p * 512 + o0 + col] = m;
  outb[(size_t)p * 512 + o0 + col] = __float2bfloat16(m);
}

// ---------------- MFMA bf16 GEMM: block 128(M)x64(N), 4 waves x (32x64) ----------------
template <int EPI>
__global__ __launch_bounds__(256) void k_mm(
    const __hip_bfloat16* __restrict__ A, int lda, int K,
    const __hip_bfloat16* __restrict__ B,  // [N][K] bf16
    const float* __restrict__ sc, const float* __restrict__ bi,
    const float* __restrict__ extra, int Ncols,
    float* __restrict__ outf, int ldof,
    __hip_bfloat16* __restrict__ outb, int ldob,
    unsigned* __restrict__ gmax) {
  __shared__ __align__(16) __hip_bfloat16 Al[128 * 40];
  __shared__ __align__(16) __hip_bfloat16 Bl[64 * 40];
  __shared__ float Red[4][64];
  const int tid = threadIdx.x, lane = tid & 63, wv = tid >> 6;
  const int m0 = blockIdx.x * 128, n0 = blockIdx.y * 64;
  const int arow = tid >> 2, akc = (tid & 3) * 8;
  const int fm = lane & 15, fq = lane >> 4;
  f32x4 acc[2][4];
#pragma unroll
  for (int mt = 0; mt < 2; ++mt)
#pragma unroll
    for (int nt = 0; nt < 4; ++nt) acc[mt][nt] = (f32x4){0.f, 0.f, 0.f, 0.f};
  for (int c0 = 0; c0 < K; c0 += 32) {
#pragma unroll
    for (int l = 0; l < 2; ++l) {
      int r = arow + l * 64;
      *(float4*)&Al[r * 40 + akc] = *(const float4*)(A + (size_t)(m0 + r) * lda + c0 + akc);
    }
    *(float4*)&Bl[arow * 40 + akc] = *(const float4*)(B + (size_t)(n0 + arow) * K + c0 + akc);
    __syncthreads();
    bf16x8 af[2], bfr[4];
#pragma unroll
    for (int mt = 0; mt < 2; ++mt)
      af[mt] = *(const bf16x8*)&Al[(wv * 32 + mt * 16 + fm) * 40 + fq * 8];
#pragma unroll
    for (int nt = 0; nt < 4; ++nt)
      bfr[nt] = *(const bf16x8*)&Bl[(nt * 16 + fm) * 40 + fq * 8];
#pragma unroll
    for (int mt = 0; mt < 2; ++mt)
#pragma unroll
      for (int nt = 0; nt < 4; ++nt)
        acc[mt][nt] = __builtin_amdgcn_mfma_f32_16x16x32_bf16(af[mt], bfr[nt], acc[mt][nt], 0, 0, 0);
    __syncthreads();
  }
  const int bidx = m0 >> 12;
  if (EPI == 0) {
#pragma unroll
    for (int mt = 0; mt < 2; ++mt)
#pragma unroll
      for (int nt = 0; nt < 4; ++nt)
#pragma unroll
        for (int r = 0; r < 4; ++r)
          outf[(size_t)(m0 + wv * 32 + mt * 16 + fq * 4 + r) * ldof + n0 + nt * 16 + fm] =
              acc[mt][nt][r];
  } else if (EPI == 1) {
#pragma unroll
    for (int nt = 0; nt < 4; ++nt) {
      int col = n0 + nt * 16 + fm;
      float s = sc[col], bb = bi[col];
      float ex = extra ? extra[bidx * Ncols + col] : 0.f;
#pragma unroll
      for (int mt = 0; mt < 2; ++mt)
#pragma unroll
        for (int r = 0; r < 4; ++r) {
          float v = lrelu((acc[mt][nt][r] + ex) * s + bb);
          size_t rr = (size_t)(m0 + wv * 32 + mt * 16 + fq * 4 + r);
          if (outf) outf[rr * ldof + col] = v;
          if (outb) outb[rr * ldob + col] = __float2bfloat16(v);
        }
    }
  } else {
#pragma unroll
    for (int nt = 0; nt < 4; ++nt) {
      int col = n0 + nt * 16 + fm;
      float s = sc[col], bb = bi[col];
      float m = -INFINITY;
#pragma unroll
      for (int mt = 0; mt < 2; ++mt)
#pragma unroll
        for (int r = 0; r < 4; ++r) m = fmaxf(m, lrelu(acc[mt][nt][r] * s + bb));
      m = fmaxf(m, __shfl_xor(m, 16, 64));
      m = fmaxf(m, __shfl_xor(m, 32, 64));
      if (fq == 0) Red[wv][nt * 16 + fm] = m;
    }
    __syncthreads();
    if (tid < 64) {
      float m = fmaxf(fmaxf(Red[0][tid], Red[1][tid]), fmaxf(Red[2][tid], Red[3][tid]));
      atomicMax(&gmax[bidx * Ncols + n0 + tid], okey(m));
    }
  }
}

// ---------------- MFMA bf16 EdgeConv (layer 4): 320 edges x 64 cols / block ----------------
__global__ __launch_bounds__(256) void k_edgem(
    const __hip_bfloat16* __restrict__ F, int ldf, int coff, int K,
    const __hip_bfloat16* __restrict__ Wl,  // [N][K] bf16
    const float* __restrict__ sc, const float* __restrict__ bi,
    const float* __restrict__ T, int N,
    const int* __restrict__ idx,
    float* __restrict__ outf, __hip_bfloat16* __restrict__ outb) {
  __shared__ __align__(16) char smem[320 * 66 * 2];  // 42240 B, overlaid stage/Ys
  __hip_bfloat16* Al = (__hip_bfloat16*)smem;              // 320*40
  __hip_bfloat16* Bl = (__hip_bfloat16*)(smem + 25600);    // 64*40
  __hip_bfloat16* Ys = (__hip_bfloat16*)smem;              // 320*66 (post-loop)
  const int tid = threadIdx.x, lane = tid & 63, wv = tid >> 6;
  const int blk = blockIdx.x, n0 = blockIdx.y * 64;
  const int arow = tid >> 2, akc = (tid & 3) * 8;
  const int fm = lane & 15, fq = lane >> 4;
  const __hip_bfloat16* ap[5];
#pragma unroll
  for (int l = 0; l < 5; ++l) {
    int row = arow + l * 64;
    int e = blk * 320 + row;
    int p = e / 20;
    int j = idx[(size_t)p * 20 + (e - p * 20)];
    int src = ((p >> 12) << 12) + j;
    ap[l] = F + (size_t)src * ldf + coff + akc;
  }
  f32x4 acc[5][4];
#pragma unroll
  for (int l = 0; l < 5; ++l)
#pragma unroll
    for (int nt = 0; nt < 4; ++nt) acc[l][nt] = (f32x4){0.f, 0.f, 0.f, 0.f};
  for (int c0 = 0; c0 < K; c0 += 32) {
#pragma unroll
    for (int l = 0; l < 5; ++l)
      *(float4*)&Al[(arow + l * 64) * 40 + akc] = *(const float4*)(ap[l] + c0);
    *(float4*)&Bl[arow * 40 + akc] = *(const float4*)(Wl + (size_t)(n0 + arow) * K + c0 + akc);
    __syncthreads();
    bf16x8 af[5], bfr[4];
#pragma unroll
    for (int l = 0; l < 5; ++l)
      af[l] = *(const bf16x8*)&Al[(wv * 80 + l * 16 + fm) * 40 + fq * 8];
#pragma unroll
    for (int nt = 0; nt < 4; ++nt)
      bfr[nt] = *(const bf16x8*)&Bl[(nt * 16 + fm) * 40 + fq * 8];
#pragma unroll
    for (int l = 0; l < 5; ++l)
#pragma unroll
      for (int nt = 0; nt < 4; ++nt)
        acc[l][nt] = __builtin_amdgcn_mfma_f32_16x16x32_bf16(af[l], bfr[nt], acc[l][nt], 0, 0, 0);
    __syncthreads();
  }
#pragma unroll
  for (int l = 0; l < 5; ++l)
#pragma unroll
    for (int nt = 0; nt < 4; ++nt)
#pragma unroll
      for (int r = 0; r < 4; ++r)
        Ys[(wv * 80 + l * 16 + fq * 4 + r) * 66 + nt * 16 + fm] = __float2bfloat16(acc[l][nt][r]);
  __syncthreads();
  const int col = tid & 63;
#pragma unroll
  for (int gi = 0; gi < 4; ++gi) {
    int grp = wv + gi * 4;
    float m = -INFINITY;
#pragma unroll
    for (int k = 0; k < 20; ++k)
      m = fmaxf(m, __bfloat162float(Ys[(grp * 20 + k) * 66 + col]));
    int p = blk * 16 + grp;
    int o = n0 + col;
    float v = lrelu((m + T[(size_t)p * N + o]) * sc[o] + bi[o]);
    outf[(size_t)p * 512 + o] = v;
    outb[(size_t)p * 512 + o] = __float2bfloat16(v);
  }
}

// ---------------- bias2: one wave per (b,o) ----------------
__global__ __launch_bounds__(256) void k_bias2(const unsigned* __restrict__ gk,
                                               const float* __restrict__ Ws1,
                                               float* __restrict__ b2g) {
  const int lane = threadIdx.x & 63;
  const int wid = (blockIdx.x * 256 + threadIdx.x) >> 6;  // 0..1023
  const int b = wid >> 9, o = wid & 511;
  const float* wr = Ws1 + (size_t)o * 1536 + 512;
  const unsigned* g = gk + b * 1024;
  float acc = 0.f;
#pragma unroll
  for (int c = lane; c < 1024; c += 64) acc = fmaf(dekey(g[c]), wr[c], acc);
#pragma unroll
  for (int off = 32; off; off >>= 1) acc += __shfl_xor(acc, off, 64);
  if (lane == 0) b2g[b * 512 + o] = acc;
}

// ---------------- final head: out = H(8192x256) . Ws3^T + bs3 (fp32) ----------------
__global__ __launch_bounds__(256) void k_out(const float* __restrict__ H,
                                             const float* __restrict__ Ws3,
                                             const float* __restrict__ bs3,
                                             float* __restrict__ out) {
  __shared__ float Ws[13][256];
  const int tid = threadIdx.x;
  for (int e = tid; e < 13 * 256; e += 256) Ws[e >> 8][e & 255] = Ws3[e];
  __syncthreads();
  const int rloc = tid >> 4, o = tid & 15;
  const int row = blockIdx.x * 16 + rloc;
  if (o < 13) {
    const float* h = H + (size_t)row * 256;
    float acc = 0.f;
    for (int c = 0; c < 256; ++c) acc = fmaf(h[c], Ws[o][c], acc);
    out[(size_t)row * 13 + o] = acc + bs3[o];
  }
}

extern "C" void kernel_launch(void* const* d_in, const int* in_sizes, int n_in,
                              void* d_out, int out_size, void* d_ws, size_t ws_size,
                              hipStream_t stream) {
  const float* X   = (const float*)d_in[0];
  const float* W1  = (const float*)d_in[1];
  const float* S1  = (const float*)d_in[2];
  const float* B1  = (const float*)d_in[3];
  const float* W2  = (const float*)d_in[4];
  const float* S2  = (const float*)d_in[5];
  const float* B2  = (const float*)d_in[6];
  const float* W3  = (const float*)d_in[7];
  const float* S3  = (const float*)d_in[8];
  const float* B3  = (const float*)d_in[9];
  const float* W4  = (const float*)d_in[10];
  const float* S4  = (const float*)d_in[11];
  const float* B4  = (const float*)d_in[12];
  const float* Wg  = (const float*)d_in[13];
  const float* Sg  = (const float*)d_in[14];
  const float* Bg  = (const float*)d_in[15];
  const float* Ws1 = (const float*)d_in[16];
  const float* Ss1 = (const float*)d_in[17];
  const float* Bs1 = (const float*)d_in[18];
  const float* Ws2 = (const float*)d_in[19];
  const float* Ss2 = (const float*)d_in[20];
  const float* Bs2 = (const float*)d_in[21];
  const float* Ws3 = (const float*)d_in[22];
  const float* Bs3 = (const float*)d_in[23];

  char* ws = (char*)d_ws;
  float*           xxb   = (float*)(ws + 0);            // 32 KB
  int*             idxb  = (int*)(ws + 32768);          // 640 KB
  unsigned*        gk    = (unsigned*)(ws + 688128);    // 8 KB
  float*           b2g   = (float*)(ws + 696320);       // 4 KB
  __hip_bfloat16*  Wgb   = (__hip_bfloat16*)(ws + 1048576);  // 1 MB
  __hip_bfloat16*  Ws1b  = (__hip_bfloat16*)(ws + 2097152);  // 512 KB
  __hip_bfloat16*  Ws2b  = (__hip_bfloat16*)(ws + 2621440);  // 256 KB
  __hip_bfloat16*  Wlb4  = (__hip_bfloat16*)(ws + 2883584);  // 64 KB
  __hip_bfloat16*  Wdb4  = (__hip_bfloat16*)(ws + 2949120);  // 64 KB
  __hip_bfloat16*  xcatb = (__hip_bfloat16*)(ws + 3145728);  // 8 MB
  float*           xcat  = (float*)(ws + 11534336);          // 16 MB
  char*            region = ws + 28311552;                   // dist / Tbuf+h1b
  unsigned*        dist  = (unsigned*)(region);
  float*           Tbuf  = (float*)(region);
  __hip_bfloat16*  h1b   = (__hip_bfloat16*)(region + 8388608);

  // dist buffer variants: both batches (128MB) > one batch (64MB) > chunked (16MB)
  const bool big2 = (ws_size >= (size_t)28311552 + (128u << 20));
  const bool big1 = (ws_size >= (size_t)28311552 + (64u << 20));

  hipMemsetAsync(gk, 0, 2 * 1024 * sizeof(unsigned), stream);

  // weight bf16 packs (L4 + head only; L1-L3 weights stay fp32)
  k_conv<<<dim3(256, 2), dim3(64), 0, stream>>>(W4, 256, 0, 0, 128, Wlb4);
  k_conv<<<dim3(256, 2), dim3(64), 0, stream>>>(W4, 256, 128, 1, 128, Wdb4);
  k_conv<<<dim3(1024, 8), dim3(64), 0, stream>>>(Wg, 512, 0, 0, 512, Wgb);
  k_conv<<<dim3(512, 8), dim3(64), 0, stream>>>(Ws1, 1536, 0, 0, 512, Ws1b);
  k_conv<<<dim3(256, 8), dim3(64), 0, stream>>>(Ws2, 512, 0, 0, 512, Ws2b);

  // kNN for one layer (fills idxb); selection bit-identical in all paths
  auto run_knn = [&](const float* F, int ldf, int C) {
    k_xx<<<dim3(2048), dim3(256), 0, stream>>>(F, ldf, C, xxb);
    if (big2) {
      k_dist<<<dim3(528, 1, 2), dim3(256), 0, stream>>>(F, ldf, C, xxb, dist, -1, 0, 1);
      k_topk<<<dim3(1024, 2), dim3(256), 0, stream>>>(dist, idxb, -1, 0);
    } else if (big1) {
      for (int b = 0; b < 2; ++b) {
        k_dist<<<dim3(32, 32), dim3(256), 0, stream>>>(F, ldf, C, xxb, dist, b, 0, 0);
        k_topk<<<dim3(1024), dim3(256), 0, stream>>>(dist, idxb, b, 0);
      }
    } else {
      for (int b = 0; b < 2; ++b)
        for (int c = 0; c < 4; ++c) {
          k_dist<<<dim3(8, 32), dim3(256), 0, stream>>>(F, ldf, C, xxb, dist, b, c * 1024, 0);
          k_topk<<<dim3(256), dim3(256), 0, stream>>>(dist, idxb, b, c * 1024);
        }
    }
  };

  // ---- Layer 1 (C=3 -> 64, fp32 exact) ----
  run_knn(X, 3, 3);
  k_edge1<<<dim3(2048), dim3(256), 0, stream>>>(X, W1, S1, B1, idxb, xcat, xcatb);

  // ---- Layer 2 (64 -> 64), fp32 (feeds kNN — must stay exact, R9 proved it) ----
  run_knn(xcat, 512, 64);
  k_pwT<<<dim3(128, 1), dim3(256), 0, stream>>>(xcat, 512, 64, W2, 128, 64, Tbuf, 64);
  k_edge<<<dim3(2048, 1), dim3(256), 0, stream>>>(xcat, 512, 64, W2, S2, B2,
      idxb, Tbuf, 64, xcat + 64, xcatb + 64);

  // ---- Layer 3 (64 -> 128), fp32 (feeds kNN) ----
  run_knn(xcat + 64, 512, 64);
  k_pwT<<<dim3(128, 2), dim3(256), 0, stream>>>(xcat + 64, 512, 64, W3, 128, 64, Tbuf, 128);
  k_edge<<<dim3(2048, 2), dim3(256), 0, stream>>>(xcat + 64, 512, 64, W3, S3, B3,
      idxb, Tbuf, 128, xcat + 128, xcatb + 128);

  // ---- Layer 4 (128 -> 256), bf16 MFMA (x4 feeds nothing discrete) ----
  run_knn(xcat + 128, 512, 128);
  k_mm<0><<<dim3(64, 4), dim3(256), 0, stream>>>(xcatb + 128, 512, 128, Wdb4,
      nullptr, nullptr, nullptr, 256, Tbuf, 256, nullptr, 0, nullptr);
  k_edgem<<<dim3(512, 4), dim3(256), 0, stream>>>(xcatb, 512, 128, 128, Wlb4,
      S4, B4, Tbuf, 256, idxb, xcat + 256, xcatb + 256);

  // ---- head (all bf16 MFMA) ----
  k_mm<2><<<dim3(64, 16), dim3(256), 0, stream>>>(xcatb, 512, 512, Wgb,
      Sg, Bg, nullptr, 1024, nullptr, 0, nullptr, 0, gk);
  k_bias2<<<dim3(256), dim3(256), 0, stream>>>(gk, Ws1, b2g);
  k_mm<1><<<dim3(64, 8), dim3(256), 0, stream>>>(xcatb, 512, 512, Ws1b,
      Ss1, Bs1, b2g, 512, nullptr, 0, h1b, 512, nullptr);
  k_mm<1><<<dim3(64, 4), dim3(256), 0, stream>>>(h1b, 512, 512, Ws2b,
      Ss2, Bs2, nullptr, 256, Tbuf, 256, nullptr, 0, nullptr);
  k_out<<<dim3(512), dim3(256), 0, stream>>>(Tbuf, Ws3, Bs3, (float*)d_out);
}

// Round 19
// 665.369 us; speedup vs baseline: 1.6125x; 1.0272x over previous
//
#include <hip/hip_runtime.h>
#include <hip/hip_bf16.h>

// DGCNN_Seg forward. B=2, N=4096, K=20. fp32 in/out.
// Round 19: symmetric k_dist on the 128x64 tile (8x4 acc = 32 VGPRs; R18's
// 8x8 sym tile had VGPR 88 -> 16% occupancy and lost the symmetry win).
// Triangular j-blocks >= 2*bi; diag pair computed fully, off-diag mirrored
// barrier-free from registers. Bit-identical. Rest = R18 (683us).

#define DEVI static __device__ __forceinline__
typedef __attribute__((ext_vector_type(8))) short bf16x8;   // 8 bf16 = 4 VGPR
typedef __attribute__((ext_vector_type(4))) float f32x4;    // MFMA acc
typedef unsigned long long ull;

DEVI float lrelu(float y) { return y > 0.f ? y : 0.2f * y; }
DEVI unsigned okey(float f) {
  unsigned u = __float_as_uint(f);
  return (f < 0.f) ? ~u : (u | 0x80000000u);
}
DEVI float dekey(unsigned k) {
  return __uint_as_float((k & 0x80000000u) ? (k & 0x7fffffffu) : ~k);
}

// ---------------- weight fp32 -> bf16 pack ----------------
__global__ __launch_bounds__(64) void k_conv(const float* __restrict__ src, int lds, int off,
                                             int sub, int Kc, __hip_bfloat16* __restrict__ dst) {
  int o = blockIdx.x, c = blockIdx.y * 64 + threadIdx.x;
  float v = src[(size_t)o * lds + off + c];
  if (sub) v -= src[(size_t)o * lds + c];
  dst[(size_t)o * Kc + c] = __float2bfloat16(v);
}

// ---------------- row squared-norms: one wave per row ----------------
__global__ __launch_bounds__(256) void k_xx(const float* __restrict__ F, int ldf, int C,
                                            float* __restrict__ xx) {
  int lane = threadIdx.x & 63;
  int row = blockIdx.x * 4 + (threadIdx.x >> 6);
  const float* f = F + (size_t)row * ldf;
  float s = 0.f;
  for (int c = lane; c < C; c += 64) { float v = f[c]; s += v * v; }
#pragma unroll
  for (int off = 32; off; off >>= 1) s += __shfl_xor(s, off, 64);
  if (lane == 0) xx[row] = s;
}

// ---------------- pairwise distances v6: 128(i)x64(j) tile, 8x4/thread ----------------
// sym=1: triangular decode (j-blocks >= 2*bi); bj>=2bi+2 tiles mirror directly
// from registers. Stores okey(d) u32. fmaf order identical -> bit-identical.
__global__ __launch_bounds__(256) void k_dist(const float* __restrict__ F, int ldf, int C,
                                              const float* __restrict__ xx,
                                              unsigned* __restrict__ D, int bfix, int ibase,
                                              int sym) {
  __shared__ __align__(16) float As[16][132];
  __shared__ __align__(16) float Bs[16][68];
  const int tid = threadIdx.x;
  const int tx = tid & 15, ty = tid >> 4;
  int bi, bj;
  if (sym) {
    int t = blockIdx.x;
    bi = 0;
    while (t >= 64 - 2 * bi) { t -= 64 - 2 * bi; ++bi; }
    bj = 2 * bi + t;
  } else {
    bi = blockIdx.x;
    bj = blockIdx.y;
  }
  const int b = (bfix < 0) ? (int)blockIdx.z : bfix;
  unsigned* Db = (bfix < 0) ? (D + (size_t)b * 4096 * 4096) : D;
  const int i0 = ibase + bi * 128, j0 = bj * 64;
  const float* Fb = F + (size_t)b * 4096 * ldf;
  const float* xxb = xx + b * 4096;
  const int arow = tid >> 1, q8 = (tid & 1) * 8;   // A stage: 128 rows x 16 cols
  const int brow = tid >> 2, q4 = (tid & 3) * 4;   // B stage: 64 rows x 16 cols
  float acc[8][4] = {};
  for (int c0 = 0; c0 < C; c0 += 16) {
    if (C - c0 >= 16) {
      float4 a0 = *(const float4*)(Fb + (size_t)(i0 + arow) * ldf + c0 + q8);
      float4 a1 = *(const float4*)(Fb + (size_t)(i0 + arow) * ldf + c0 + q8 + 4);
      As[q8 + 0][arow] = a0.x; As[q8 + 1][arow] = a0.y; As[q8 + 2][arow] = a0.z; As[q8 + 3][arow] = a0.w;
      As[q8 + 4][arow] = a1.x; As[q8 + 5][arow] = a1.y; As[q8 + 6][arow] = a1.z; As[q8 + 7][arow] = a1.w;
      float4 w = *(const float4*)(Fb + (size_t)(j0 + brow) * ldf + c0 + q4);
      Bs[q4 + 0][brow] = w.x; Bs[q4 + 1][brow] = w.y; Bs[q4 + 2][brow] = w.z; Bs[q4 + 3][brow] = w.w;
    } else {
#pragma unroll
      for (int e = 0; e < 8; ++e) {
        int c = c0 + q8 + e;
        As[q8 + e][arow] = (c < C) ? Fb[(size_t)(i0 + arow) * ldf + c] : 0.f;
      }
#pragma unroll
      for (int e = 0; e < 4; ++e) {
        int c = c0 + q4 + e;
        Bs[q4 + e][brow] = (c < C) ? Fb[(size_t)(j0 + brow) * ldf + c] : 0.f;
      }
    }
    __syncthreads();
#pragma unroll
    for (int kk = 0; kk < 16; ++kk) {
      const float4 a4l = *(const float4*)&As[kk][ty * 8];
      const float4 a4h = *(const float4*)&As[kk][ty * 8 + 4];
      const float4 b4 = *(const float4*)&Bs[kk][tx * 4];
      const float av[8] = {a4l.x, a4l.y, a4l.z, a4l.w, a4h.x, a4h.y, a4h.z, a4h.w};
      const float bv[4] = {b4.x, b4.y, b4.z, b4.w};
#pragma unroll
      for (int ii = 0; ii < 8; ++ii)
#pragma unroll
        for (int jj = 0; jj < 4; ++jj)
          acc[ii][jj] = fmaf(av[ii], bv[jj], acc[ii][jj]);
    }
    __syncthreads();
  }
  // normal block store (128 rows x 64 cols)
#pragma unroll
  for (int ii = 0; ii < 8; ++ii) {
    int i = i0 + ty * 8 + ii;
    float xi = xxb[i];
    uint4 o;
    o.x = okey(xi + xxb[j0 + tx * 4 + 0] - 2.f * acc[ii][0]);
    o.y = okey(xi + xxb[j0 + tx * 4 + 1] - 2.f * acc[ii][1]);
    o.z = okey(xi + xxb[j0 + tx * 4 + 2] - 2.f * acc[ii][2]);
    o.w = okey(xi + xxb[j0 + tx * 4 + 3] - 2.f * acc[ii][3]);
    *(uint4*)&Db[(size_t)(i - ibase) * 4096 + j0 + tx * 4] = o;
  }
  // mirror store (sym, strictly off-diagonal tiles only): 64 rows x 128 cols
  if (sym && bj >= 2 * bi + 2) {
#pragma unroll
    for (int jj = 0; jj < 4; ++jj) {
      const float xj = xxb[j0 + tx * 4 + jj];
      uint4 m1, m2;
      m1.x = okey(xxb[i0 + ty * 8 + 0] + xj - 2.f * acc[0][jj]);
      m1.y = okey(xxb[i0 + ty * 8 + 1] + xj - 2.f * acc[1][jj]);
      m1.z = okey(xxb[i0 + ty * 8 + 2] + xj - 2.f * acc[2][jj]);
      m1.w = okey(xxb[i0 + ty * 8 + 3] + xj - 2.f * acc[3][jj]);
      m2.x = okey(xxb[i0 + ty * 8 + 4] + xj - 2.f * acc[4][jj]);
      m2.y = okey(xxb[i0 + ty * 8 + 5] + xj - 2.f * acc[5][jj]);
      m2.z = okey(xxb[i0 + ty * 8 + 6] + xj - 2.f * acc[6][jj]);
      m2.w = okey(xxb[i0 + ty * 8 + 7] + xj - 2.f * acc[7][jj]);
      unsigned* dst = &Db[(size_t)(j0 + tx * 4 + jj) * 4096 + i0 + ty * 8];
      *(uint4*)(dst + 0) = m1;
      *(uint4*)(dst + 4) = m2;
    }
  }
}

// ---------------- top-20 v7: ONE WAVE per row ----------------
__global__ __launch_bounds__(256) void k_topk(const unsigned* __restrict__ Dk,
                                              int* __restrict__ idx, int bfix, int ibase) {
  const int tid = threadIdx.x, lane = tid & 63, wv = tid >> 6;
  const int ir_ = blockIdx.x * 4 + wv;
  const int b = (bfix < 0) ? (int)blockIdx.y : bfix;
  const unsigned* drow = Dk + ((bfix < 0) ? (size_t)b * 4096 * 4096 : 0) + (size_t)ir_ * 4096;
  unsigned key[64];
  {
    const uint4* dp = (const uint4*)(drow + lane * 64);
#pragma unroll
    for (int q = 0; q < 16; ++q) {
      uint4 k4 = dp[q];
      key[4 * q + 0] = k4.x; key[4 * q + 1] = k4.y;
      key[4 * q + 2] = k4.z; key[4 * q + 3] = k4.w;
    }
  }
  unsigned m1k = 0xFFFFFFFFu, m2k = 0xFFFFFFFFu, m3k = 0xFFFFFFFFu;
  int m1p = 0, m2p = 0, m3p = 0;
#pragma unroll
  for (int it = 0; it < 64; ++it) {
    unsigned v = key[it];
    bool b1 = v < m1k, b2 = v < m2k, b3 = v < m3k;
    m3k = b2 ? m2k : (b3 ? v : m3k);
    m3p = b2 ? m2p : (b3 ? it : m3p);
    m2k = b1 ? m1k : (b2 ? v : m2k);
    m2p = b1 ? m1p : (b2 ? it : m2p);
    m1k = b1 ? v : m1k;
    m1p = b1 ? it : m1p;
  }
  ull consumed = (1ull << m1p) | (1ull << m2p) | (1ull << m3p);
  unsigned ck = m1k;
  int cp = m1p;
  unsigned n1k = m2k; int n1p = m2p;
  unsigned n2k = m3k; int n2p = m3p;
  int* op = idx + ((size_t)b * 4096 + ibase + ir_) * 20;
  for (int r = 0; r < 20; ++r) {
    unsigned mh = ck;
#pragma unroll
    for (int off = 32; off; off >>= 1) {
      unsigned o = __shfl_xor(mh, off, 64);
      mh = o < mh ? o : mh;
    }
    ull bal = __ballot(ck == mh);
    int sl = (int)(__ffsll((unsigned long long)bal) - 1);
    int mp = __shfl(cp, sl, 64);  // popping lane's in-lane position
    if (lane == 0) op[r] = sl * 64 + mp;
    bool pop = (lane == sl);
    ck = pop ? n1k : ck;  cp = pop ? n1p : cp;
    n1k = pop ? n2k : n1k; n1p = pop ? n2p : n1p;
    n2k = pop ? 0xFFFFFFFFu : n2k;
    if (ck == 0xFFFFFFFFu) {  // rare: this lane popped >=3 times; refill from regs
      unsigned bk = 0xFFFFFFFFu; int bp = 0;
#pragma unroll
      for (int t = 0; t < 64; ++t) {
        bool ok = ((consumed >> t) & 1ull) == 0ull;
        unsigned v = ok ? key[t] : 0xFFFFFFFFu;
        bool c = v < bk;
        bk = c ? v : bk;
        bp = c ? t : bp;
      }
      consumed |= (1ull << bp);
      ck = bk;
      cp = bp;
    }
  }
}

// ---------------- EdgeConv layer 1 (fp32, Cin=3): one wave per point ----------------
__global__ __launch_bounds__(256) void k_edge1(const float* __restrict__ xf,
                                               const float* __restrict__ W1,
                                               const float* __restrict__ s1,
                                               const float* __restrict__ b1,
                                               const int* __restrict__ idx,
                                               float* __restrict__ xcat,
                                               __hip_bfloat16* __restrict__ xcatb) {
  const int lane = threadIdx.x & 63;
  const int p = blockIdx.x * 4 + (threadIdx.x >> 6);
  const int bb = p >> 12;
  float wl[3], wr[3];
#pragma unroll
  for (int c = 0; c < 3; ++c) {
    wl[c] = W1[lane * 6 + c];
    wr[c] = W1[lane * 6 + 3 + c];
  }
  const float s = s1[lane], bi = b1[lane];
  const float* xc = xf + (size_t)p * 3;
  const float x0 = xc[0], x1 = xc[1], x2 = xc[2];
  const float t = x0 * (wr[0] - wl[0]) + x1 * (wr[1] - wl[1]) + x2 * (wr[2] - wl[2]);
  const int* ir = idx + (size_t)p * 20;
  float best = -INFINITY;
  for (int k = 0; k < 20; ++k) {
    int j = ir[k];
    const float* xn = xf + ((size_t)(bb << 12) + j) * 3;
    float y = t + xn[0] * wl[0] + xn[1] * wl[1] + xn[2] * wl[2];
    y = lrelu(y * s + bi);
    best = fmaxf(best, y);
  }
  xcat[(size_t)p * 512 + lane] = best;
  xcatb[(size_t)p * 512 + lane] = __float2bfloat16(best);
}

// ---------------- fp32 pointwise GEMM, raw store (T for layers 2-3) ----------------
__global__ __launch_bounds__(256) void k_pwT(const float* __restrict__ A, int lda, int K,
                                             const float* __restrict__ W, int ldw, int wsub,
                                             float* __restrict__ out, int ldo) {
  __shared__ __align__(16) float As[16][68];
  __shared__ __align__(16) float Bs[16][68];
  const int tid = threadIdx.x;
  const int tx = tid & 15, ty = tid >> 4;
  const int i0 = blockIdx.x * 64, o0 = blockIdx.y * 64;
  const int row = tid >> 2, q = (tid & 3) * 4;
  float acc[4][4] = {};
  for (int c0 = 0; c0 < K; c0 += 16) {
    float4 a = *(const float4*)(A + (size_t)(i0 + row) * lda + c0 + q);
    As[q + 0][row] = a.x; As[q + 1][row] = a.y; As[q + 2][row] = a.z; As[q + 3][row] = a.w;
    const float* wp = W + (size_t)(o0 + row) * ldw + c0 + q;
#pragma unroll
    for (int e = 0; e < 4; ++e) Bs[q + e][row] = wp[wsub + e] - wp[e];
    __syncthreads();
#pragma unroll
    for (int kk = 0; kk < 16; ++kk) {
      const float4 a4 = *(const float4*)&As[kk][ty * 4];
      const float4 b4 = *(const float4*)&Bs[kk][tx * 4];
      const float av[4] = {a4.x, a4.y, a4.z, a4.w};
      const float bv[4] = {b4.x, b4.y, b4.z, b4.w};
#pragma unroll
      for (int ii = 0; ii < 4; ++ii)
#pragma unroll
        for (int jj = 0; jj < 4; ++jj)
          acc[ii][jj] = fmaf(av[ii], bv[jj], acc[ii][jj]);
    }
    __syncthreads();
  }
#pragma unroll
  for (int ii = 0; ii < 4; ++ii)
#pragma unroll
    for (int jj = 0; jj < 4; ++jj)
      out[(size_t)(i0 + ty * 4 + ii) * ldo + o0 + tx * 4 + jj] = acc[ii][jj];
}

// ---------------- fp32 EdgeConv GEMM (layers 2-3; feeds kNN, stays exact) ----------------
__global__ __launch_bounds__(256) void k_edge(const float* __restrict__ F, int ldf, int Cin,
                                              const float* __restrict__ W,
                                              const float* __restrict__ sc,
                                              const float* __restrict__ bi,
                                              const int* __restrict__ idx,
                                              const float* __restrict__ T, int ldt,
                                              float* __restrict__ out,
                                              __hip_bfloat16* __restrict__ outb) {
  __shared__ float As[16][81];
  __shared__ __align__(16) float Bs[16][68];
  __shared__ float Ys[80][65];
  const int tid = threadIdx.x;
  const int tx = tid & 15, ty = tid >> 4;
  const int r0 = blockIdx.x * 80;
  const int o0 = blockIdx.y * 64;
  const int ldw = 2 * Cin;
  int grow[5], gcol[5];
#pragma unroll
  for (int l = 0; l < 5; ++l) {
    int e = tid + l * 256;
    int rr = e >> 4;
    gcol[l] = e & 15;
    int gr = r0 + rr;
    int p = gr / 20;
    int j = idx[(size_t)p * 20 + (gr % 20)];
    grow[l] = ((p >> 12) << 12) + j;
  }
  float acc[5][4] = {};
  const int wrow = tid >> 2, wq = (tid & 3) * 4;
  for (int c0 = 0; c0 < Cin; c0 += 16) {
#pragma unroll
    for (int l = 0; l < 5; ++l) {
      int e = tid + l * 256;
      As[gcol[l]][e >> 4] = F[(size_t)grow[l] * ldf + c0 + gcol[l]];
    }
    {
      const float* wp = W + (size_t)(o0 + wrow) * ldw + c0 + wq;
#pragma unroll
      for (int e = 0; e < 4; ++e) Bs[wq + e][wrow] = wp[e];
    }
    __syncthreads();
#pragma unroll
    for (int kk = 0; kk < 16; ++kk) {
      float a[5];
#pragma unroll
      for (int l = 0; l < 5; ++l) a[l] = As[kk][ty + l * 16];
      const float4 b4 = *(const float4*)&Bs[kk][tx * 4];
      const float bv[4] = {b4.x, b4.y, b4.z, b4.w};
#pragma unroll
      for (int l = 0; l < 5; ++l)
#pragma unroll
        for (int jj = 0; jj < 4; ++jj)
          acc[l][jj] = fmaf(a[l], bv[jj], acc[l][jj]);
    }
    __syncthreads();
  }
#pragma unroll
  for (int l = 0; l < 5; ++l) {
    int r = ty + l * 16;
    int p = (r0 + r) / 20;
#pragma unroll
    for (int jj = 0; jj < 4; ++jj) {
      int o = o0 + tx * 4 + jj;
      float y = (acc[l][jj] + T[(size_t)p * ldt + o]) * sc[o] + bi[o];
      Ys[r][tx * 4 + jj] = lrelu(y);
    }
  }
  __syncthreads();
  const int grp = tid >> 6, col = tid & 63;
  float m = -INFINITY;
#pragma unroll
  for (int k = 0; k < 20; ++k) m = fmaxf(m, Ys[grp * 20 + k][col]);
  const int p = blockIdx.x * 4 + grp;
  out[(size_t)p * 512 + o0 + col] = m;
  outb[(size_t)p * 512 + o0 + col] = __float2bfloat16(m);
}

// ---------------- MFMA bf16 GEMM: block 128(M)x64(N), 4 waves x (32x64) ----------------
template <int EPI>
__global__ __launch_bounds__(256) void k_mm(
    const __hip_bfloat16* __restrict__ A, int lda, int K,
    const __hip_bfloat16* __restrict__ B,  // [N][K] bf16
    const float* __restrict__ sc, const float* __restrict__ bi,
    const float* __restrict__ extra, int Ncols,
    float* __restrict__ outf, int ldof,
    __hip_bfloat16* __restrict__ outb, int ldob,
    unsigned* __restrict__ gmax) {
  __shared__ __align__(16) __hip_bfloat16 Al[128 * 40];
  __shared__ __align__(16) __hip_bfloat16 Bl[64 * 40];
  __shared__ float Red[4][64];
  const int tid = threadIdx.x, lane = tid & 63, wv = tid >> 6;
  const int m0 = blockIdx.x * 128, n0 = blockIdx.y * 64;
  const int arow = tid >> 2, akc = (tid & 3) * 8;
  const int fm = lane & 15, fq = lane >> 4;
  f32x4 acc[2][4];
#pragma unroll
  for (int mt = 0; mt < 2; ++mt)
#pragma unroll
    for (int nt = 0; nt < 4; ++nt) acc[mt][nt] = (f32x4){0.f, 0.f, 0.f, 0.f};
  for (int c0 = 0; c0 < K; c0 += 32) {
#pragma unroll
    for (int l = 0; l < 2; ++l) {
      int r = arow + l * 64;
      *(float4*)&Al[r * 40 + akc] = *(const float4*)(A + (size_t)(m0 + r) * lda + c0 + akc);
    }
    *(float4*)&Bl[arow * 40 + akc] = *(const float4*)(B + (size_t)(n0 + arow) * K + c0 + akc);
    __syncthreads();
    bf16x8 af[2], bfr[4];
#pragma unroll
    for (int mt = 0; mt < 2; ++mt)
      af[mt] = *(const bf16x8*)&Al[(wv * 32 + mt * 16 + fm) * 40 + fq * 8];
#pragma unroll
    for (int nt = 0; nt < 4; ++nt)
      bfr[nt] = *(const bf16x8*)&Bl[(nt * 16 + fm) * 40 + fq * 8];
#pragma unroll
    for (int mt = 0; mt < 2; ++mt)
#pragma unroll
      for (int nt = 0; nt < 4; ++nt)
        acc[mt][nt] = __builtin_amdgcn_mfma_f32_16x16x32_bf16(af[mt], bfr[nt], acc[mt][nt], 0, 0, 0);
    __syncthreads();
  }
  const int bidx = m0 >> 12;
  if (EPI == 0) {
#pragma unroll
    for (int mt = 0; mt < 2; ++mt)
#pragma unroll
      for (int nt = 0; nt < 4; ++nt)
#pragma unroll
        for (int r = 0; r < 4; ++r)
          outf[(size_t)(m0 + wv * 32 + mt * 16 + fq * 4 + r) * ldof + n0 + nt * 16 + fm] =
              acc[mt][nt][r];
  } else if (EPI == 1) {
#pragma unroll
    for (int nt = 0; nt < 4; ++nt) {
      int col = n0 + nt * 16 + fm;
      float s = sc[col], bb = bi[col];
      float ex = extra ? extra[bidx * Ncols + col] : 0.f;
#pragma unroll
      for (int mt = 0; mt < 2; ++mt)
#pragma unroll
        for (int r = 0; r < 4; ++r) {
          float v = lrelu((acc[mt][nt][r] + ex) * s + bb);
          size_t rr = (size_t)(m0 + wv * 32 + mt * 16 + fq * 4 + r);
          if (outf) outf[rr * ldof + col] = v;
          if (outb) outb[rr * ldob + col] = __float2bfloat16(v);
        }
    }
  } else {
#pragma unroll
    for (int nt = 0; nt < 4; ++nt) {
      int col = n0 + nt * 16 + fm;
      float s = sc[col], bb = bi[col];
      float m = -INFINITY;
#pragma unroll
      for (int mt = 0; mt < 2; ++mt)
#pragma unroll
        for (int r = 0; r < 4; ++r) m = fmaxf(m, lrelu(acc[mt][nt][r] * s + bb));
      m = fmaxf(m, __shfl_xor(m, 16, 64));
      m = fmaxf(m, __shfl_xor(m, 32, 64));
      if (fq == 0) Red[wv][nt * 16 + fm] = m;
    }
    __syncthreads();
    if (tid < 64) {
      float m = fmaxf(fmaxf(Red[0][tid], Red[1][tid]), fmaxf(Red[2][tid], Red[3][tid]));
      atomicMax(&gmax[bidx * Ncols + n0 + tid], okey(m));
    }
  }
}

// ---------------- MFMA bf16 EdgeConv (layer 4): 320 edges x 64 cols / block ----------------
__global__ __launch_bounds__(256) void k_edgem(
    const __hip_bfloat16* __restrict__ F, int ldf, int coff, int K,
    const __hip_bfloat16* __restrict__ Wl,  // [N][K] bf16
    const float* __restrict__ sc, const float* __restrict__ bi,
    const float* __restrict__ T, int N,
    const int* __restrict__ idx,
    float* __restrict__ outf, __hip_bfloat16* __restrict__ outb) {
  __shared__ __align__(16) char smem[320 * 66 * 2];  // 42240 B, overlaid stage/Ys
  __hip_bfloat16* Al = (__hip_bfloat16*)smem;              // 320*40
  __hip_bfloat16* Bl = (__hip_bfloat16*)(smem + 25600);    // 64*40
  __hip_bfloat16* Ys = (__hip_bfloat16*)smem;              // 320*66 (post-loop)
  const int tid = threadIdx.x, lane = tid & 63, wv = tid >> 6;
  const int blk = blockIdx.x, n0 = blockIdx.y * 64;
  const int arow = tid >> 2, akc = (tid & 3) * 8;
  const int fm = lane & 15, fq = lane >> 4;
  const __hip_bfloat16* ap[5];
#pragma unroll
  for (int l = 0; l < 5; ++l) {
    int row = arow + l * 64;
    int e = blk * 320 + row;
    int p = e / 20;
    int j = idx[(size_t)p * 20 + (e - p * 20)];
    int src = ((p >> 12) << 12) + j;
    ap[l] = F + (size_t)src * ldf + coff + akc;
  }
  f32x4 acc[5][4];
#pragma unroll
  for (int l = 0; l < 5; ++l)
#pragma unroll
    for (int nt = 0; nt < 4; ++nt) acc[l][nt] = (f32x4){0.f, 0.f, 0.f, 0.f};
  for (int c0 = 0; c0 < K; c0 += 32) {
#pragma unroll
    for (int l = 0; l < 5; ++l)
      *(float4*)&Al[(arow + l * 64) * 40 + akc] = *(const float4*)(ap[l] + c0);
    *(float4*)&Bl[arow * 40 + akc] = *(const float4*)(Wl + (size_t)(n0 + arow) * K + c0 + akc);
    __syncthreads();
    bf16x8 af[5], bfr[4];
#pragma unroll
    for (int l = 0; l < 5; ++l)
      af[l] = *(const bf16x8*)&Al[(wv * 80 + l * 16 + fm) * 40 + fq * 8];
#pragma unroll
    for (int nt = 0; nt < 4; ++nt)
      bfr[nt] = *(const bf16x8*)&Bl[(nt * 16 + fm) * 40 + fq * 8];
#pragma unroll
    for (int l = 0; l < 5; ++l)
#pragma unroll
      for (int nt = 0; nt < 4; ++nt)
        acc[l][nt] = __builtin_amdgcn_mfma_f32_16x16x32_bf16(af[l], bfr[nt], acc[l][nt], 0, 0, 0);
    __syncthreads();
  }
#pragma unroll
  for (int l = 0; l < 5; ++l)
#pragma unroll
    for (int nt = 0; nt < 4; ++nt)
#pragma unroll
      for (int r = 0; r < 4; ++r)
        Ys[(wv * 80 + l * 16 + fq * 4 + r) * 66 + nt * 16 + fm] = __float2bfloat16(acc[l][nt][r]);
  __syncthreads();
  const int col = tid & 63;
#pragma unroll
  for (int gi = 0; gi < 4; ++gi) {
    int grp = wv + gi * 4;
    float m = -INFINITY;
#pragma unroll
    for (int k = 0; k < 20; ++k)
      m = fmaxf(m, __bfloat162float(Ys[(grp * 20 + k) * 66 + col]));
    int p = blk * 16 + grp;
    int o = n0 + col;
    float v = lrelu((m + T[(size_t)p * N + o]) * sc[o] + bi[o]);
    outf[(size_t)p * 512 + o] = v;
    outb[(size_t)p * 512 + o] = __float2bfloat16(v);
  }
}

// ---------------- bias2: one wave per (b,o) ----------------
__global__ __launch_bounds__(256) void k_bias2(const unsigned* __restrict__ gk,
                                               const float* __restrict__ Ws1,
                                               float* __restrict__ b2g) {
  const int lane = threadIdx.x & 63;
  const int wid = (blockIdx.x * 256 + threadIdx.x) >> 6;  // 0..1023
  const int b = wid >> 9, o = wid & 511;
  const float* wr = Ws1 + (size_t)o * 1536 + 512;
  const unsigned* g = gk + b * 1024;
  float acc = 0.f;
#pragma unroll
  for (int c = lane; c < 1024; c += 64) acc = fmaf(dekey(g[c]), wr[c], acc);
#pragma unroll
  for (int off = 32; off; off >>= 1) acc += __shfl_xor(acc, off, 64);
  if (lane == 0) b2g[b * 512 + o] = acc;
}

// ---------------- final head: out = H(8192x256) . Ws3^T + bs3 (fp32) ----------------
__global__ __launch_bounds__(256) void k_out(const float* __restrict__ H,
                                             const float* __restrict__ Ws3,
                                             const float* __restrict__ bs3,
                                             float* __restrict__ out) {
  __shared__ float Ws[13][256];
  const int tid = threadIdx.x;
  for (int e = tid; e < 13 * 256; e += 256) Ws[e >> 8][e & 255] = Ws3[e];
  __syncthreads();
  const int rloc = tid >> 4, o = tid & 15;
  const int row = blockIdx.x * 16 + rloc;
  if (o < 13) {
    const float* h = H + (size_t)row * 256;
    float acc = 0.f;
    for (int c = 0; c < 256; ++c) acc = fmaf(h[c], Ws[o][c], acc);
    out[(size_t)row * 13 + o] = acc + bs3[o];
  }
}

extern "C" void kernel_launch(void* const* d_in, const int* in_sizes, int n_in,
                              void* d_out, int out_size, void* d_ws, size_t ws_size,
                              hipStream_t stream) {
  const float* X   = (const float*)d_in[0];
  const float* W1  = (const float*)d_in[1];
  const float* S1  = (const float*)d_in[2];
  const float* B1  = (const float*)d_in[3];
  const float* W2  = (const float*)d_in[4];
  const float* S2  = (const float*)d_in[5];
  const float* B2  = (const float*)d_in[6];
  const float* W3  = (const float*)d_in[7];
  const float* S3  = (const float*)d_in[8];
  const float* B3  = (const float*)d_in[9];
  const float* W4  = (const float*)d_in[10];
  const float* S4  = (const float*)d_in[11];
  const float* B4  = (const float*)d_in[12];
  const float* Wg  = (const float*)d_in[13];
  const float* Sg  = (const float*)d_in[14];
  const float* Bg  = (const float*)d_in[15];
  const float* Ws1 = (const float*)d_in[16];
  const float* Ss1 = (const float*)d_in[17];
  const float* Bs1 = (const float*)d_in[18];
  const float* Ws2 = (const float*)d_in[19];
  const float* Ss2 = (const float*)d_in[20];
  const float* Bs2 = (const float*)d_in[21];
  const float* Ws3 = (const float*)d_in[22];
  const float* Bs3 = (const float*)d_in[23];

  char* ws = (char*)d_ws;
  float*           xxb   = (float*)(ws + 0);            // 32 KB
  int*             idxb  = (int*)(ws + 32768);          // 640 KB
  unsigned*        gk    = (unsigned*)(ws + 688128);    // 8 KB
  float*           b2g   = (float*)(ws + 696320);       // 4 KB
  __hip_bfloat16*  Wgb   = (__hip_bfloat16*)(ws + 1048576);  // 1 MB
  __hip_bfloat16*  Ws1b  = (__hip_bfloat16*)(ws + 2097152);  // 512 KB
  __hip_bfloat16*  Ws2b  = (__hip_bfloat16*)(ws + 2621440);  // 256 KB
  __hip_bfloat16*  Wlb4  = (__hip_bfloat16*)(ws + 2883584);  // 64 KB
  __hip_bfloat16*  Wdb4  = (__hip_bfloat16*)(ws + 2949120);  // 64 KB
  __hip_bfloat16*  xcatb = (__hip_bfloat16*)(ws + 3145728);  // 8 MB
  float*           xcat  = (float*)(ws + 11534336);          // 16 MB
  char*            region = ws + 28311552;                   // dist / Tbuf+h1b
  unsigned*        dist  = (unsigned*)(region);
  float*           Tbuf  = (float*)(region);
  __hip_bfloat16*  h1b   = (__hip_bfloat16*)(region + 8388608);

  // dist buffer variants: both batches (128MB) > one batch (64MB) > chunked (16MB)
  const bool big2 = (ws_size >= (size_t)28311552 + (128u << 20));
  const bool big1 = (ws_size >= (size_t)28311552 + (64u << 20));

  hipMemsetAsync(gk, 0, 2 * 1024 * sizeof(unsigned), stream);

  // weight bf16 packs (L4 + head only; L1-L3 weights stay fp32)
  k_conv<<<dim3(256, 2), dim3(64), 0, stream>>>(W4, 256, 0, 0, 128, Wlb4);
  k_conv<<<dim3(256, 2), dim3(64), 0, stream>>>(W4, 256, 128, 1, 128, Wdb4);
  k_conv<<<dim3(1024, 8), dim3(64), 0, stream>>>(Wg, 512, 0, 0, 512, Wgb);
  k_conv<<<dim3(512, 8), dim3(64), 0, stream>>>(Ws1, 1536, 0, 0, 512, Ws1b);
  k_conv<<<dim3(256, 8), dim3(64), 0, stream>>>(Ws2, 512, 0, 0, 512, Ws2b);

  // kNN for one layer (fills idxb); selection bit-identical in all paths
  auto run_knn = [&](const float* F, int ldf, int C) {
    k_xx<<<dim3(2048), dim3(256), 0, stream>>>(F, ldf, C, xxb);
    if (big2) {
      k_dist<<<dim3(1056, 1, 2), dim3(256), 0, stream>>>(F, ldf, C, xxb, dist, -1, 0, 1);
      k_topk<<<dim3(1024, 2), dim3(256), 0, stream>>>(dist, idxb, -1, 0);
    } else if (big1) {
      for (int b = 0; b < 2; ++b) {
        k_dist<<<dim3(32, 64), dim3(256), 0, stream>>>(F, ldf, C, xxb, dist, b, 0, 0);
        k_topk<<<dim3(1024), dim3(256), 0, stream>>>(dist, idxb, b, 0);
      }
    } else {
      for (int b = 0; b < 2; ++b)
        for (int c = 0; c < 4; ++c) {
          k_dist<<<dim3(8, 64), dim3(256), 0, stream>>>(F, ldf, C, xxb, dist, b, c * 1024, 0);
          k_topk<<<dim3(256), dim3(256), 0, stream>>>(dist, idxb, b, c * 1024);
        }
    }
  };

  // ---- Layer 1 (C=3 -> 64, fp32 exact) ----
  run_knn(X, 3, 3);
  k_edge1<<<dim3(2048), dim3(256), 0, stream>>>(X, W1, S1, B1, idxb, xcat, xcatb);

  // ---- Layer 2 (64 -> 64), fp32 (feeds kNN — must stay exact, R9 proved it) ----
  run_knn(xcat, 512, 64);
  k_pwT<<<dim3(128, 1), dim3(256), 0, stream>>>(xcat, 512, 64, W2, 128, 64, Tbuf, 64);
  k_edge<<<dim3(2048, 1), dim3(256), 0, stream>>>(xcat, 512, 64, W2, S2, B2,
      idxb, Tbuf, 64, xcat + 64, xcatb + 64);

  // ---- Layer 3 (64 -> 128), fp32 (feeds kNN) ----
  run_knn(xcat + 64, 512, 64);
  k_pwT<<<dim3(128, 2), dim3(256), 0, stream>>>(xcat + 64, 512, 64, W3, 128, 64, Tbuf, 128);
  k_edge<<<dim3(2048, 2), dim3(256), 0, stream>>>(xcat + 64, 512, 64, W3, S3, B3,
      idxb, Tbuf, 128, xcat + 128, xcatb + 128);

  // ---- Layer 4 (128 -> 256), bf16 MFMA (x4 feeds nothing discrete) ----
  run_knn(xcat + 128, 512, 128);
  k_mm<0><<<dim3(64, 4), dim3(256), 0, stream>>>(xcatb + 128, 512, 128, Wdb4,
      nullptr, nullptr, nullptr, 256, Tbuf, 256, nullptr, 0, nullptr);
  k_edgem<<<dim3(512, 4), dim3(256), 0, stream>>>(xcatb, 512, 128, 128, Wlb4,
      S4, B4, Tbuf, 256, idxb, xcat + 256, xcatb + 256);

  // ---- head (all bf16 MFMA) ----
  k_mm<2><<<dim3(64, 16), dim3(256), 0, stream>>>(xcatb, 512, 512, Wgb,
      Sg, Bg, nullptr, 1024, nullptr, 0, nullptr, 0, gk);
  k_bias2<<<dim3(256), dim3(256), 0, stream>>>(gk, Ws1, b2g);
  k_mm<1><<<dim3(64, 8), dim3(256), 0, stream>>>(xcatb, 512, 512, Ws1b,
      Ss1, Bs1, b2g, 512, nullptr, 0, h1b, 512, nullptr);
  k_mm<1><<<dim3(64, 4), dim3(256), 0, stream>>>(h1b, 512, 512, Ws2b,
      Ss2, Bs2, nullptr, 256, Tbuf, 256, nullptr, 0, nullptr);
  k_out<<<dim3(512), dim3(256), 0, stream>>>(Tbuf, Ws3, Bs3, (float*)d_out);
}